// Round 3
// baseline (781.971 us; speedup 1.0000x reference)
//
#include <hip/hip_runtime.h>

typedef _Float16 f16;
typedef _Float16 f16x8 __attribute__((ext_vector_type(8)));
typedef _Float16 f16x4 __attribute__((ext_vector_type(4)));
typedef float f32x4 __attribute__((ext_vector_type(4)));

#define MFMA16(A,B,C) __builtin_amdgcn_mfma_f32_16x16x32_f16(A,B,C,0,0,0)
#define INV2048 4.8828125e-4f
#define HN (16ll*2048*96)
#define UVN 589824   // 768*768
// z in log2 domain: zl = log2(e)*768*accS + log2(e)*768/2048*accX
#define ZC1 1107.98979f
#define ZC2 0.54101064f

__device__ __forceinline__ void split_f16(float x, f16& h, f16& l) {
    h = (f16)x;
    l = (f16)((x - (float)h) * 2048.0f);   // lo pre-scaled by 2^11 (avoids fp16 denorm loss)
}

// ============================================================
// K0: split qz, U, V (fp32) into fp16 hi/lo pairs.
// ============================================================
__global__ __launch_bounds__(256) void k0_split(const float* __restrict__ qz,
                                                const float* __restrict__ U,
                                                const float* __restrict__ V,
                                                f16* __restrict__ qzh, f16* __restrict__ qzl,
                                                f16* __restrict__ Uh, f16* __restrict__ Ul,
                                                f16* __restrict__ Vh, f16* __restrict__ Vl) {
    const int i4 = blockIdx.x * 256 + threadIdx.x;   // float4 index
    {
        float4 x = *(const float4*)(qz + (size_t)i4 * 4);
        f16 h0, l0, h1, l1, h2, l2, h3, l3;
        split_f16(x.x, h0, l0); split_f16(x.y, h1, l1);
        split_f16(x.z, h2, l2); split_f16(x.w, h3, l3);
        f16x4 hv = {h0, h1, h2, h3};
        f16x4 lv = {l0, l1, l2, l3};
        *(f16x4*)(qzh + (size_t)i4 * 4) = hv;
        *(f16x4*)(qzl + (size_t)i4 * 4) = lv;
    }
    if (i4 < UVN / 4) {
        float4 x = *(const float4*)(U + (size_t)i4 * 4);
        f16 h0, l0, h1, l1, h2, l2, h3, l3;
        split_f16(x.x, h0, l0); split_f16(x.y, h1, l1);
        split_f16(x.z, h2, l2); split_f16(x.w, h3, l3);
        f16x4 hv = {h0, h1, h2, h3};
        f16x4 lv = {l0, l1, l2, l3};
        *(f16x4*)(Uh + (size_t)i4 * 4) = hv;
        *(f16x4*)(Ul + (size_t)i4 * 4) = lv;
        float4 y = *(const float4*)(V + (size_t)i4 * 4);
        split_f16(y.x, h0, l0); split_f16(y.y, h1, l1);
        split_f16(y.z, h2, l2); split_f16(y.w, h3, l3);
        f16x4 hv2 = {h0, h1, h2, h3};
        f16x4 lv2 = {l0, l1, l2, l3};
        *(f16x4*)(Vh + (size_t)i4 * 4) = hv2;
        *(f16x4*)(Vl + (size_t)i4 * 4) = lv2;
    }
}

// ============================================================
// K1: dual GEMM qz@U^T, qz@V^T via fp16 MFMA 3-product emulation
// + RoPE. Reg-prefetch of next K-chunk overlaps the MFMA phase.
// ============================================================
__global__ __launch_bounds__(256, 2) void k1_proj(const f16* __restrict__ qzh,
                                                  const f16* __restrict__ qzl,
                                                  const f16* __restrict__ Uh,
                                                  const f16* __restrict__ Ul,
                                                  const f16* __restrict__ Vh,
                                                  const f16* __restrict__ Vl,
                                                  const float* __restrict__ cosb,
                                                  const float* __restrict__ sinb,
                                                  f16* __restrict__ uhp, f16* __restrict__ ulp,
                                                  f16* __restrict__ vhp, f16* __restrict__ vlp,
                                                  f16* __restrict__ vT, f16* __restrict__ oT) {
    __shared__ __align__(16) f16 smem[36864];            // 73728 B -> 2 blocks/CU
    f16* sAh  = smem;                                    // [64][72]
    f16* sAl  = smem + 4608;
    f16* sBuh = smem + 9216;                             // [96][72]
    f16* sBul = smem + 9216 + 6912;
    f16* sBvh = smem + 9216 + 2 * 6912;
    f16* sBvl = smem + 9216 + 3 * 6912;

    const int tid = threadIdx.x;
    const int w = tid >> 6, lane = tid & 63;
    const int quad = lane >> 4, l15 = lane & 15;
    const int wr = w >> 1, wc = w & 1;                   // 2x2 wave grid
    const int bs0 = blockIdx.x * 64;
    const int c = blockIdx.y;

    const f16* Ug_h = Uh + (size_t)c * 96 * 768;
    const f16* Ug_l = Ul + (size_t)c * 96 * 768;
    const f16* Vg_h = Vh + (size_t)c * 96 * 768;
    const f16* Vg_l = Vl + (size_t)c * 96 * 768;

    f32x4 aUS[2][3] = {}, aUX[2][3] = {};
    f32x4 aVS[2][3] = {}, aVX[2][3] = {};

    float4 rAh[2], rAl[2], rUh[3], rUl[3], rVh[3], rVl[3];
    auto loadAll = [&](int k0) {
#pragma unroll
        for (int m = 0; m < 2; ++m) {
            int f = tid + 256 * m, row = f >> 3, cg8 = (f & 7) * 8;
            const size_t go = (size_t)(bs0 + row) * 768 + k0 + cg8;
            rAh[m] = *(const float4*)(qzh + go);
            rAl[m] = *(const float4*)(qzl + go);
        }
#pragma unroll
        for (int m = 0; m < 3; ++m) {
            int f = tid + 256 * m, row = f >> 3, cg8 = (f & 7) * 8;
            const size_t go = (size_t)row * 768 + k0 + cg8;
            rUh[m] = *(const float4*)(Ug_h + go);
            rUl[m] = *(const float4*)(Ug_l + go);
            rVh[m] = *(const float4*)(Vg_h + go);
            rVl[m] = *(const float4*)(Vg_l + go);
        }
    };
    auto storeAll = [&]() {
#pragma unroll
        for (int m = 0; m < 2; ++m) {
            int f = tid + 256 * m, row = f >> 3, cg8 = (f & 7) * 8;
            const int lo = row * 72 + cg8;
            *(float4*)&sAh[lo] = rAh[m];
            *(float4*)&sAl[lo] = rAl[m];
        }
#pragma unroll
        for (int m = 0; m < 3; ++m) {
            int f = tid + 256 * m, row = f >> 3, cg8 = (f & 7) * 8;
            const int lo = row * 72 + cg8;
            *(float4*)&sBuh[lo] = rUh[m];
            *(float4*)&sBul[lo] = rUl[m];
            *(float4*)&sBvh[lo] = rVh[m];
            *(float4*)&sBvl[lo] = rVl[m];
        }
    };

    loadAll(0);
    for (int k0 = 0; k0 < 768; k0 += 64) {
        __syncthreads();                     // prior MFMA-phase LDS reads done
        storeAll();
        __syncthreads();
        if (k0 + 64 < 768) loadAll(k0 + 64); // overlaps MFMA phase below
#pragma unroll
        for (int cc = 0; cc < 2; ++cc) {
            f16x8 ah[2], al[2];
#pragma unroll
            for (int mt = 0; mt < 2; ++mt) {
                const int ar = (32 * wr + 16 * mt + l15) * 72 + cc * 32 + quad * 8;
                ah[mt] = *(const f16x8*)&sAh[ar];
                al[mt] = *(const f16x8*)&sAl[ar];
            }
#pragma unroll
            for (int nt = 0; nt < 3; ++nt) {
                const int br = (48 * wc + 16 * nt + l15) * 72 + cc * 32 + quad * 8;
                f16x8 buh = *(const f16x8*)&sBuh[br];
                f16x8 bul = *(const f16x8*)&sBul[br];
                f16x8 bvh = *(const f16x8*)&sBvh[br];
                f16x8 bvl = *(const f16x8*)&sBvl[br];
#pragma unroll
                for (int mt = 0; mt < 2; ++mt) {
                    aUS[mt][nt] = MFMA16(ah[mt], buh, aUS[mt][nt]);
                    aUX[mt][nt] = MFMA16(ah[mt], bul, aUX[mt][nt]);
                    aUX[mt][nt] = MFMA16(al[mt], buh, aUX[mt][nt]);
                    aVS[mt][nt] = MFMA16(ah[mt], bvh, aVS[mt][nt]);
                    aVX[mt][nt] = MFMA16(ah[mt], bvl, aVX[mt][nt]);
                    aVX[mt][nt] = MFMA16(al[mt], bvh, aVX[mt][nt]);
                }
            }
        }
    }

    // ---- epilogue: combine to fp32 in LDS, then the exact old epilogue ----
    __syncthreads();
    float* LU = (float*)smem;          // [64][100] = 25.6 KB
    float* LV = LU + 6400;
#pragma unroll
    for (int mt = 0; mt < 2; ++mt)
#pragma unroll
        for (int nt = 0; nt < 3; ++nt)
#pragma unroll
            for (int r = 0; r < 4; ++r) {
                const int sl = 32 * wr + 16 * mt + 4 * quad + r;
                const int col = 48 * wc + 16 * nt + l15;
                LU[sl * 100 + col] = aUS[mt][nt][r] + aUX[mt][nt][r] * INV2048;
                LV[sl * 100 + col] = aVS[mt][nt][r] + aVX[mt][nt][r] * INV2048;
            }
    __syncthreads();

    const int b = bs0 >> 11;
    const int s0 = bs0 & 2047;
    const int head = b * 8 + c;
    const size_t nb = (size_t)head * 2048 * 96;
    const size_t tb = (size_t)head * 96 * 2048;
    const int ty = tid >> 4, tx = tid & 15;

#pragma unroll
    for (int jj = 0; jj < 3; ++jj) {
        int r = tx + 16 * jj;
        f16 vt1[4], vt2[4], ot1[4], ot2[4];
#pragma unroll
        for (int ii = 0; ii < 4; ++ii) {
            int sl = 4 * ty + ii;
            int s = s0 + sl;
            int cbi = (b * 2048 + s) * 96 + r;
            float cc = cosb[cbi], ss = sinb[cbi];
            size_t rowb = nb + (size_t)s * 96;
            float u1 = LU[sl * 100 + r], u2 = LU[sl * 100 + r + 48];
            float v1 = LV[sl * 100 + r], v2 = LV[sl * 100 + r + 48];
            float ur1 = u1 * cc - u2 * ss, ur2 = u2 * cc + u1 * ss;
            float uo1 = u1 * cc + u2 * ss, uo2 = u2 * cc - u1 * ss;
            float vr1 = v1 * cc - v2 * ss, vr2 = v2 * cc + v1 * ss;
            f16 h, l;
            split_f16(ur1, h, l); uhp[rowb + r] = h;      ulp[rowb + r] = l;
            split_f16(ur2, h, l); uhp[rowb + r + 48] = h; ulp[rowb + r + 48] = l;
            split_f16(vr1, h, l); vhp[rowb + r] = h;      vlp[rowb + r] = l;      vt1[ii] = h;
            split_f16(vr2, h, l); vhp[rowb + r + 48] = h; vlp[rowb + r + 48] = l; vt2[ii] = h;
            ot1[ii] = (f16)uo1; ot2[ii] = (f16)uo2;
        }
        f16x4 pv1 = {vt1[0], vt1[1], vt1[2], vt1[3]};
        f16x4 pv2 = {vt2[0], vt2[1], vt2[2], vt2[3]};
        f16x4 po1 = {ot1[0], ot1[1], ot1[2], ot1[3]};
        f16x4 po2 = {ot2[0], ot2[1], ot2[2], ot2[3]};
        *(f16x4*)&vT[tb + (size_t)r * 2048 + s0 + 4 * ty] = pv1;
        *(f16x4*)&vT[tb + (size_t)(r + 48) * 2048 + s0 + 4 * ty] = pv2;
        *(f16x4*)&oT[tb + (size_t)r * 2048 + s0 + 4 * ty] = po1;
        *(f16x4*)&oT[tb + (size_t)(r + 48) * 2048 + s0 + 4 * ty] = po2;
    }
}

// ============================================================
// K2: MFMA row stats. Double-buffered Bh/Bl -> 1 barrier per k-tile,
// next-next tile prefetched into regs. Per-lane online (m,l); one
// 16-lane merge at the end + cross-wave LDS merge. log2 domain.
// ============================================================
__global__ __launch_bounds__(256, 2) void k2_stats(const f16* __restrict__ uhp,
                                                   const f16* __restrict__ ulp,
                                                   const f16* __restrict__ vhp,
                                                   const f16* __restrict__ vlp,
                                                   float* __restrict__ Mo,
                                                   float* __restrict__ Lo) {
    __shared__ f16 Bh[2][64 * 104];
    __shared__ f16 Bl[2][64 * 104];
    __shared__ float Mbuf[4][64], Lbuf[4][64];
    const int tid = threadIdx.x, w = tid >> 6, lane = tid & 63;
    const int quad = lane >> 4, l15 = lane & 15;
    const int q0 = blockIdx.x * 64, head = blockIdx.y;
    const f16* Ah_g = uhp + (size_t)head * 2048 * 96;
    const f16* Al_g = ulp + (size_t)head * 2048 * 96;
    const f16* Bh_g = vhp + (size_t)head * 2048 * 96;
    const f16* Bl_g = vlp + (size_t)head * 2048 * 96;

    f16x8 Afh[4][3], Afl[4][3];
#pragma unroll
    for (int mt = 0; mt < 4; ++mt)
#pragma unroll
        for (int cc = 0; cc < 3; ++cc) {
            size_t off = (size_t)(q0 + 16 * mt + l15) * 96 + cc * 32 + quad * 8;
            Afh[mt][cc] = *(const f16x8*)(Ah_g + off);
            Afl[mt][cc] = *(const f16x8*)(Al_g + off);
        }

    int srow[3], scol[3];
#pragma unroll
    for (int m = 0; m < 3; ++m) {
        int f = tid + 256 * m;
        srow[m] = f / 12; scol[m] = (f % 12) * 8;
    }
    float4 rh[3], rl[3];
    auto loadB = [&](int k0) {
#pragma unroll
        for (int m = 0; m < 3; ++m) {
            rh[m] = *(const float4*)(Bh_g + (size_t)(k0 + srow[m]) * 96 + scol[m]);
            rl[m] = *(const float4*)(Bl_g + (size_t)(k0 + srow[m]) * 96 + scol[m]);
        }
    };
    auto storeB = [&](int bsel) {
#pragma unroll
        for (int m = 0; m < 3; ++m) {
            *(float4*)&Bh[bsel][srow[m] * 104 + scol[m]] = rh[m];
            *(float4*)&Bl[bsel][srow[m] * 104 + scol[m]] = rl[m];
        }
    };

    float m_run[4][4], l_run[4][4];
#pragma unroll
    for (int mt = 0; mt < 4; ++mt)
#pragma unroll
        for (int r = 0; r < 4; ++r) { m_run[mt][r] = -3.0e38f; l_run[mt][r] = 0.f; }

    loadB(0); storeB(0); loadB(64);
    __syncthreads();

    for (int t = 0; t < 32; ++t) {
        const int cur = t & 1;
        if (t < 31) storeB(cur ^ 1);          // tile t+1 (regs from last iter)
        if (t < 30) loadB((t + 2) * 64);      // tile t+2 in flight
        f32x4 accS[4] = {}, accX[4] = {};
#pragma unroll
        for (int cc = 0; cc < 3; ++cc) {
            f16x8 bh = *(const f16x8*)&Bh[cur][(w * 16 + l15) * 104 + cc * 32 + quad * 8];
            f16x8 bl = *(const f16x8*)&Bl[cur][(w * 16 + l15) * 104 + cc * 32 + quad * 8];
#pragma unroll
            for (int mt = 0; mt < 4; ++mt) {
                accS[mt] = MFMA16(Afh[mt][cc], bh, accS[mt]);
                accX[mt] = MFMA16(Afh[mt][cc], bl, accX[mt]);
                accX[mt] = MFMA16(Afl[mt][cc], bh, accX[mt]);
            }
        }
        // per-lane online update only
#pragma unroll
        for (int mt = 0; mt < 4; ++mt)
#pragma unroll
            for (int r = 0; r < 4; ++r) {
                float zl = fmaf(ZC1, accS[mt][r], ZC2 * accX[mt][r]);
                float nm = fmaxf(m_run[mt][r], zl);
                l_run[mt][r] = fmaf(l_run[mt][r], exp2f(m_run[mt][r] - nm),
                                    exp2f(zl - nm));
                m_run[mt][r] = nm;
            }
        __syncthreads();
    }
    // merge the 16 per-lane column-partitions
#pragma unroll
    for (int mt = 0; mt < 4; ++mt)
#pragma unroll
        for (int r = 0; r < 4; ++r) {
            float m = m_run[mt][r], l = l_run[mt][r];
#pragma unroll
            for (int d = 1; d < 16; d <<= 1) {
                float mo = __shfl_xor(m, d), lo = __shfl_xor(l, d);
                float nm = fmaxf(m, mo);
                l = fmaf(l, exp2f(m - nm), lo * exp2f(mo - nm));
                m = nm;
            }
            m_run[mt][r] = m; l_run[mt][r] = l;
        }
    if (l15 == 0) {
#pragma unroll
        for (int mt = 0; mt < 4; ++mt)
#pragma unroll
            for (int r = 0; r < 4; ++r) {
                Mbuf[w][16 * mt + 4 * quad + r] = m_run[mt][r];
                Lbuf[w][16 * mt + 4 * quad + r] = l_run[mt][r];
            }
    }
    __syncthreads();
    if (tid < 64) {
        float M = -3.0e38f;
#pragma unroll
        for (int ww = 0; ww < 4; ++ww) M = fmaxf(M, Mbuf[ww][tid]);
        float L = 0.f;
#pragma unroll
        for (int ww = 0; ww < 4; ++ww) L += Lbuf[ww][tid] * exp2f(Mbuf[ww][tid] - M);
        Mo[head * 2048 + q0 + tid] = M;      // log2-domain max
        Lo[head * 2048 + q0 + tid] = L;
    }
}

// ============================================================
// K3a: S=ur.vr^T (x3 fp16 emulation, z bitwise == k2), P=exp2(zl-M[q]),
// out=P@vr, scale 1/L[q], rope_o -> w1. Double-buffered Bh/Bl ->
// 2 barriers/tile; staging loads prefetched; P XOR-swizzled.
// ============================================================
__global__ __launch_bounds__(256, 2) void k3a(const f16* __restrict__ uhp,
                                              const f16* __restrict__ ulp,
                                              const f16* __restrict__ vhp,
                                              const f16* __restrict__ vlp,
                                              const f16* __restrict__ vT,
                                              const float* __restrict__ Mo,
                                              const float* __restrict__ Lo,
                                              const float* __restrict__ cosb,
                                              const float* __restrict__ sinb,
                                              f16* __restrict__ w1) {
    __shared__ f16 Bh[2][64 * 104];
    __shared__ f16 Bl[2][64 * 104];
    __shared__ f16 Vt[96 * 72];
    __shared__ f16 P[64 * 72];
    const int tid = threadIdx.x, w = tid >> 6, lane = tid & 63;
    const int quad = lane >> 4, l15 = lane & 15;
    const int q0 = blockIdx.x * 64, head = blockIdx.y;
    const f16* Ah_g = uhp + (size_t)head * 2048 * 96;
    const f16* Al_g = ulp + (size_t)head * 2048 * 96;
    const f16* Bh_g = vhp + (size_t)head * 2048 * 96;
    const f16* Bl_g = vlp + (size_t)head * 2048 * 96;
    const f16* Vt_g = vT + (size_t)head * 96 * 2048;

    f16x8 Afh[4][3], Afl[4][3];
#pragma unroll
    for (int mt = 0; mt < 4; ++mt)
#pragma unroll
        for (int cc = 0; cc < 3; ++cc) {
            size_t off = (size_t)(q0 + 16 * mt + l15) * 96 + cc * 32 + quad * 8;
            Afh[mt][cc] = *(const f16x8*)(Ah_g + off);
            Afl[mt][cc] = *(const f16x8*)(Al_g + off);
        }
    float negM[4][4];
#pragma unroll
    for (int mt = 0; mt < 4; ++mt)
#pragma unroll
        for (int r = 0; r < 4; ++r)
            negM[mt][r] = -Mo[head * 2048 + q0 + 16 * mt + 4 * quad + r];
    float invL[4];
#pragma unroll
    for (int r = 0; r < 4; ++r)
        invL[r] = 1.0f / Lo[head * 2048 + q0 + w * 16 + quad * 4 + r];

    int srow[3], scol[3], vrow[3], vcol[3];
#pragma unroll
    for (int m = 0; m < 3; ++m) {
        int f = tid + 256 * m;
        srow[m] = f / 12; scol[m] = (f % 12) * 8;
        vrow[m] = f >> 3; vcol[m] = (f & 7) * 8;
    }
    float4 rh[3], rl[3], rv[3];
    auto loadB = [&](int k0) {
#pragma unroll
        for (int m = 0; m < 3; ++m) {
            rh[m] = *(const float4*)(Bh_g + (size_t)(k0 + srow[m]) * 96 + scol[m]);
            rl[m] = *(const float4*)(Bl_g + (size_t)(k0 + srow[m]) * 96 + scol[m]);
        }
    };
    auto storeB = [&](int bsel) {
#pragma unroll
        for (int m = 0; m < 3; ++m) {
            *(float4*)&Bh[bsel][srow[m] * 104 + scol[m]] = rh[m];
            *(float4*)&Bl[bsel][srow[m] * 104 + scol[m]] = rl[m];
        }
    };
    auto loadV = [&](int k0) {
#pragma unroll
        for (int m = 0; m < 3; ++m)
            rv[m] = *(const float4*)(Vt_g + (size_t)vrow[m] * 2048 + k0 + vcol[m]);
    };
    auto storeV = [&]() {
#pragma unroll
        for (int m = 0; m < 3; ++m)
            *(float4*)&Vt[vrow[m] * 72 + vcol[m]] = rv[m];
    };

    f32x4 accO[6] = {};

    loadB(0); storeB(0);
    loadV(0); loadB(64);
    __syncthreads();                       // buf0 visible

    for (int t = 0; t < 32; ++t) {
        const int cur = t & 1;
        const int k0 = t * 64;
        storeV();                          // tile t (covered by sync_B)
        if (t < 31) storeB(cur ^ 1);       // tile t+1 (covered by sync_B+C)
        if (t < 31) loadV(k0 + 64);
        if (t < 30) loadB(k0 + 128);

        f32x4 accS[4] = {}, accX[4] = {};
#pragma unroll
        for (int cc = 0; cc < 3; ++cc) {
            f16x8 bh = *(const f16x8*)&Bh[cur][(w * 16 + l15) * 104 + cc * 32 + quad * 8];
            f16x8 bl = *(const f16x8*)&Bl[cur][(w * 16 + l15) * 104 + cc * 32 + quad * 8];
#pragma unroll
            for (int mt = 0; mt < 4; ++mt) {
                accS[mt] = MFMA16(Afh[mt][cc], bh, accS[mt]);
                accX[mt] = MFMA16(Afh[mt][cc], bl, accX[mt]);
                accX[mt] = MFMA16(Afl[mt][cc], bh, accX[mt]);
            }
        }
#pragma unroll
        for (int mt = 0; mt < 4; ++mt)
#pragma unroll
            for (int r = 0; r < 4; ++r) {
                float zl = fmaf(ZC1, accS[mt][r], ZC2 * accX[mt][r]);
                // XOR-swizzle column by row-bit3 to break quad-pair bank aliasing
                P[(16 * mt + 4 * quad + r) * 72 +
                  ((w * 16 + l15) ^ ((quad >> 1) << 4))] =
                    (f16)exp2f(zl + negM[mt][r]);
            }
        __syncthreads();                   // sync_B: P + Vt visible
#pragma unroll
        for (int kc = 0; kc < 2; ++kc) {
            f16x8 ap = *(const f16x8*)&P[(w * 16 + l15) * 72 +
                                         ((kc * 32 + quad * 8) ^ (((l15 >> 3) & 1) << 4))];
#pragma unroll
            for (int nt = 0; nt < 6; ++nt) {
                f16x8 bv = *(const f16x8*)&Vt[(nt * 16 + l15) * 72 + kc * 32 + quad * 8];
                accO[nt] = MFMA16(ap, bv, accO[nt]);
            }
        }
        __syncthreads();                   // sync_C: PV reads done
    }
    const int b = head >> 3, c = head & 7;
#pragma unroll
    for (int r = 0; r < 4; ++r) {
        int q = q0 + w * 16 + quad * 4 + r;
        int cbi = (b * 2048 + q) * 96;
        f16* wrow = w1 + (size_t)(b * 2048 + q) * 768 + c * 96;
#pragma unroll
        for (int nt = 0; nt < 3; ++nt) {
            int rr = nt * 16 + l15;
            float cc = cosb[cbi + rr], ss = sinb[cbi + rr];
            float a = accO[nt][r] * invL[r];
            float b2 = accO[nt + 3][r] * invL[r];
            wrow[rr] = (f16)(a * cc + b2 * ss);
            wrow[rr + 48] = (f16)(b2 * cc - a * ss);
        }
    }
}

// ============================================================
// K3b: S2[q][k]=vr_q.ur_k (bitwise == k2's z transposed),
// P2=exp2(zl-M[k])/L[k], out=P2@uo, rope -> w2. Same pipeline as k3a.
// ============================================================
__global__ __launch_bounds__(256, 2) void k3b(const f16* __restrict__ uhp,
                                              const f16* __restrict__ ulp,
                                              const f16* __restrict__ vhp,
                                              const f16* __restrict__ vlp,
                                              const f16* __restrict__ oT,
                                              const float* __restrict__ Mo,
                                              const float* __restrict__ Lo,
                                              const float* __restrict__ cosb,
                                              const float* __restrict__ sinb,
                                              f16* __restrict__ w2) {
    __shared__ f16 Bh[2][64 * 104];
    __shared__ f16 Bl[2][64 * 104];
    __shared__ f16 Ot[96 * 72];
    __shared__ f16 P[64 * 72];
    const int tid = threadIdx.x, w = tid >> 6, lane = tid & 63;
    const int quad = lane >> 4, l15 = lane & 15;
    const int q0 = blockIdx.x * 64, head = blockIdx.y;
    const f16* Ah_g = vhp + (size_t)head * 2048 * 96;   // A = vr
    const f16* Al_g = vlp + (size_t)head * 2048 * 96;
    const f16* Bh_g = uhp + (size_t)head * 2048 * 96;   // B = ur
    const f16* Bl_g = ulp + (size_t)head * 2048 * 96;
    const f16* Ot_g = oT + (size_t)head * 96 * 2048;

    f16x8 Afh[4][3], Afl[4][3];
#pragma unroll
    for (int mt = 0; mt < 4; ++mt)
#pragma unroll
        for (int cc = 0; cc < 3; ++cc) {
            size_t off = (size_t)(q0 + 16 * mt + l15) * 96 + cc * 32 + quad * 8;
            Afh[mt][cc] = *(const f16x8*)(Ah_g + off);
            Afl[mt][cc] = *(const f16x8*)(Al_g + off);
        }

    int srow[3], scol[3], vrow[3], vcol[3];
#pragma unroll
    for (int m = 0; m < 3; ++m) {
        int f = tid + 256 * m;
        srow[m] = f / 12; scol[m] = (f % 12) * 8;
        vrow[m] = f >> 3; vcol[m] = (f & 7) * 8;
    }
    float4 rh[3], rl[3], rv[3];
    auto loadB = [&](int k0) {
#pragma unroll
        for (int m = 0; m < 3; ++m) {
            rh[m] = *(const float4*)(Bh_g + (size_t)(k0 + srow[m]) * 96 + scol[m]);
            rl[m] = *(const float4*)(Bl_g + (size_t)(k0 + srow[m]) * 96 + scol[m]);
        }
    };
    auto storeB = [&](int bsel) {
#pragma unroll
        for (int m = 0; m < 3; ++m) {
            *(float4*)&Bh[bsel][srow[m] * 104 + scol[m]] = rh[m];
            *(float4*)&Bl[bsel][srow[m] * 104 + scol[m]] = rl[m];
        }
    };
    auto loadO = [&](int k0) {
#pragma unroll
        for (int m = 0; m < 3; ++m)
            rv[m] = *(const float4*)(Ot_g + (size_t)vrow[m] * 2048 + k0 + vcol[m]);
    };
    auto storeO = [&]() {
#pragma unroll
        for (int m = 0; m < 3; ++m)
            *(float4*)&Ot[vrow[m] * 72 + vcol[m]] = rv[m];
    };

    f32x4 accO[6] = {};

    loadB(0); storeB(0);
    loadO(0); loadB(64);
    __syncthreads();

    for (int t = 0; t < 32; ++t) {
        const int cur = t & 1;
        const int k0 = t * 64;
        float negMk = -Mo[head * 2048 + k0 + w * 16 + l15];
        float invLk = 1.0f / Lo[head * 2048 + k0 + w * 16 + l15];
        storeO();
        if (t < 31) storeB(cur ^ 1);
        if (t < 31) loadO(k0 + 64);
        if (t < 30) loadB(k0 + 128);

        f32x4 accS[4] = {}, accX[4] = {};
#pragma unroll
        for (int cc = 0; cc < 3; ++cc) {
            f16x8 bh = *(const f16x8*)&Bh[cur][(w * 16 + l15) * 104 + cc * 32 + quad * 8];
            f16x8 bl = *(const f16x8*)&Bl[cur][(w * 16 + l15) * 104 + cc * 32 + quad * 8];
#pragma unroll
            for (int mt = 0; mt < 4; ++mt) {
                accS[mt] = MFMA16(Afh[mt][cc], bh, accS[mt]);
                // preserve k2's cross-product order: (u_hi*v_lo) first, then (u_lo*v_hi)
                accX[mt] = MFMA16(Afl[mt][cc], bh, accX[mt]);   // v_lo * u_hi
                accX[mt] = MFMA16(Afh[mt][cc], bl, accX[mt]);   // v_hi * u_lo
            }
        }
#pragma unroll
        for (int mt = 0; mt < 4; ++mt)
#pragma unroll
            for (int r = 0; r < 4; ++r) {
                float zl = fmaf(ZC1, accS[mt][r], ZC2 * accX[mt][r]);
                P[(16 * mt + 4 * quad + r) * 72 +
                  ((w * 16 + l15) ^ ((quad >> 1) << 4))] =
                    (f16)(exp2f(zl + negMk) * invLk);
            }
        __syncthreads();
#pragma unroll
        for (int kc = 0; kc < 2; ++kc) {
            f16x8 ap = *(const f16x8*)&P[(w * 16 + l15) * 72 +
                                         ((kc * 32 + quad * 8) ^ (((l15 >> 3) & 1) << 4))];
#pragma unroll
            for (int nt = 0; nt < 6; ++nt) {
                f16x8 bo = *(const f16x8*)&Ot[(nt * 16 + l15) * 72 + kc * 32 + quad * 8];
                accO[nt] = MFMA16(ap, bo, accO[nt]);
            }
        }
        __syncthreads();
    }
    const int b = head >> 3, c = head & 7;
#pragma unroll
    for (int r = 0; r < 4; ++r) {
        int q = q0 + w * 16 + quad * 4 + r;
        int cbi = (b * 2048 + q) * 96;
        f16* wrow = w2 + (size_t)(b * 2048 + q) * 768 + c * 96;
#pragma unroll
        for (int nt = 0; nt < 3; ++nt) {
            int rr = nt * 16 + l15;
            float cc = cosb[cbi + rr], ss = sinb[cbi + rr];
            float a = accO[nt][r];
            float b2 = accO[nt + 3][r];
            wrow[rr] = (f16)(a * cc - b2 * ss);
            wrow[rr + 48] = (f16)(b2 * cc + a * ss);
        }
    }
}

// ============================================================
// K4: G = w1@U + w2@V (fp16 MFMA). grid (32 s-blocks, 12 d-blocks),
// block 256 (4 waves), tile 128s x 64d, wave strip 32s.
// ============================================================
__global__ __launch_bounds__(256, 2) void k4_final(const f16* __restrict__ w1,
                                                   const f16* __restrict__ w2,
                                                   const float* __restrict__ U,
                                                   const float* __restrict__ V,
                                                   float* __restrict__ outp) {
    __shared__ f16 A1[128 * 56];
    __shared__ f16 A2[128 * 56];
    __shared__ f16 B1[64 * 56];
    __shared__ f16 B2[64 * 56];
    const int tid = threadIdx.x, w = tid >> 6, lane = tid & 63;
    const int quad = lane >> 4, l15 = lane & 15;
    const int bs0 = blockIdx.x * 128;
    const int d0 = blockIdx.y * 64;
    f32x4 acc[2][4] = {};

    for (int ec = 0; ec < 24; ++ec) {
        int e0 = ec * 32;
        __syncthreads();
#pragma unroll
        for (int m = 0; m < 2; ++m) {
            int f = tid + 256 * m;
            int row = f >> 2, q = f & 3;
            *(float4*)&A1[row * 56 + q * 8] =
                *(const float4*)(w1 + (size_t)(bs0 + row) * 768 + e0 + q * 8);
            *(float4*)&A2[row * 56 + q * 8] =
                *(const float4*)(w2 + (size_t)(bs0 + row) * 768 + e0 + q * 8);
        }
#pragma unroll
        for (int m2 = 0; m2 < 2; ++m2) {
            int e_r = (tid >> 4) + 16 * m2;
            int dc = tid & 15;
            float4 fu = *(const float4*)(U + (size_t)(e0 + e_r) * 768 + d0 + dc * 4);
            float4 fv = *(const float4*)(V + (size_t)(e0 + e_r) * 768 + d0 + dc * 4);
            B1[(dc * 4 + 0) * 56 + e_r] = (f16)fu.x;
            B1[(dc * 4 + 1) * 56 + e_r] = (f16)fu.y;
            B1[(dc * 4 + 2) * 56 + e_r] = (f16)fu.z;
            B1[(dc * 4 + 3) * 56 + e_r] = (f16)fu.w;
            B2[(dc * 4 + 0) * 56 + e_r] = (f16)fv.x;
            B2[(dc * 4 + 1) * 56 + e_r] = (f16)fv.y;
            B2[(dc * 4 + 2) * 56 + e_r] = (f16)fv.z;
            B2[(dc * 4 + 3) * 56 + e_r] = (f16)fv.w;
        }
        __syncthreads();
        f16x8 a1f[2], a2f[2];
#pragma unroll
        for (int mt = 0; mt < 2; ++mt) {
            a1f[mt] = *(const f16x8*)&A1[(32 * w + 16 * mt + l15) * 56 + quad * 8];
            a2f[mt] = *(const f16x8*)&A2[(32 * w + 16 * mt + l15) * 56 + quad * 8];
        }
#pragma unroll
        for (int nt = 0; nt < 4; ++nt) {
            f16x8 b1f = *(const f16x8*)&B1[(nt * 16 + l15) * 56 + quad * 8];
            f16x8 b2f = *(const f16x8*)&B2[(nt * 16 + l15) * 56 + quad * 8];
#pragma unroll
            for (int mt = 0; mt < 2; ++mt) {
                acc[mt][nt] = MFMA16(a1f[mt], b1f, acc[mt][nt]);
                acc[mt][nt] = MFMA16(a2f[mt], b2f, acc[mt][nt]);
            }
        }
    }
#pragma unroll
    for (int mt = 0; mt < 2; ++mt)
#pragma unroll
        for (int nt = 0; nt < 4; ++nt)
#pragma unroll
            for (int r = 0; r < 4; ++r) {
                int s = bs0 + 32 * w + 16 * mt + 4 * quad + r;
                int d = d0 + 16 * nt + l15;
                outp[(size_t)s * 768 + d] = acc[mt][nt][r];
            }
}

extern "C" void kernel_launch(void* const* d_in, const int* in_sizes, int n_in,
                              void* d_out, int out_size, void* d_ws, size_t ws_size,
                              hipStream_t stream) {
    const float* qz   = (const float*)d_in[0];
    const float* cosb = (const float*)d_in[1];
    const float* sinb = (const float*)d_in[2];
    const float* U    = (const float*)d_in[3];
    const float* V    = (const float*)d_in[4];
    float* outp = (float*)d_out;

    f16* ws16 = (f16*)d_ws;
    f16* uhp = ws16;
    f16* ulp = ws16 + HN;
    f16* vhp = ws16 + 2 * HN;
    f16* vlp = ws16 + 3 * HN;
    f16* vT  = ws16 + 4 * HN;
    f16* oT  = ws16 + 5 * HN;
    f16* w1  = ws16 + 6 * HN;
    f16* w2  = ws16 + 7 * HN;
    float* Mo = (float*)(ws16 + 8 * HN);
    float* Lo = Mo + 16 * 2048;

    // qz hi/lo splits live in the w1/w2 slots (dead until k3a/k3b write them).
    f16* qzh = w1;
    f16* qzl = w2;
    // U/V hi/lo splits live in d_out scratch (overwritten by k4 at the end).
    f16* outw = (f16*)d_out;
    f16* Uh = outw;
    f16* Ul = outw + UVN;
    f16* Vh = outw + 2 * UVN;
    f16* Vl = outw + 3 * UVN;

    k0_split<<<dim3(3072), 256, 0, stream>>>(qz, U, V, qzh, qzl, Uh, Ul, Vh, Vl);
    k1_proj<<<dim3(64, 8), 256, 0, stream>>>(qzh, qzl, Uh, Ul, Vh, Vl, cosb, sinb,
                                             uhp, ulp, vhp, vlp, vT, oT);
    k2_stats<<<dim3(32, 16), 256, 0, stream>>>(uhp, ulp, vhp, vlp, Mo, Lo);
    k3a<<<dim3(32, 16), 256, 0, stream>>>(uhp, ulp, vhp, vlp, vT, Mo, Lo, cosb, sinb, w1);
    k3b<<<dim3(32, 16), 256, 0, stream>>>(uhp, ulp, vhp, vlp, oT, Mo, Lo, cosb, sinb, w2);
    k4_final<<<dim3(32, 12), 256, 0, stream>>>(w1, w2, U, V, outp);
}

// Round 4
// 399.943 us; speedup vs baseline: 1.9552x; 1.9552x over previous
//
#include <hip/hip_runtime.h>

typedef _Float16 f16;
typedef _Float16 f16x8 __attribute__((ext_vector_type(8)));
typedef _Float16 f16x4 __attribute__((ext_vector_type(4)));
typedef float f32x4 __attribute__((ext_vector_type(4)));

#define MFMA16(A,B,C) __builtin_amdgcn_mfma_f32_16x16x32_f16(A,B,C,0,0,0)
#define INV2048 4.8828125e-4f
#define HN (16ll*2048*96)
#define UVN 589824   // 768*768
// z in log2 domain: zl = log2(e)*768*accS + log2(e)*768/2048*accX
#define ZC1 1107.98979f
#define ZC2 0.54101064f

__device__ __forceinline__ void split_f16(float x, f16& h, f16& l) {
    h = (f16)x;
    l = (f16)((x - (float)h) * 2048.0f);   // lo pre-scaled by 2^11 (avoids fp16 denorm loss)
}

// async global->LDS, 16B per lane; source AND dest linear (wave-uniform base + lane*16)
__device__ __forceinline__ void gload16(const f16* g, f16* l) {
    __builtin_amdgcn_global_load_lds(
        (const __attribute__((address_space(1))) unsigned int*)g,
        (__attribute__((address_space(3))) unsigned int*)l, 16, 0, 0);
}

// ============================================================
// K0: split qz, U, V (fp32) into fp16 hi/lo pairs.
// ============================================================
__global__ __launch_bounds__(256) void k0_split(const float* __restrict__ qz,
                                                const float* __restrict__ U,
                                                const float* __restrict__ V,
                                                f16* __restrict__ qzh, f16* __restrict__ qzl,
                                                f16* __restrict__ Uh, f16* __restrict__ Ul,
                                                f16* __restrict__ Vh, f16* __restrict__ Vl) {
    const int i4 = blockIdx.x * 256 + threadIdx.x;   // float4 index
    {
        float4 x = *(const float4*)(qz + (size_t)i4 * 4);
        f16 h0, l0, h1, l1, h2, l2, h3, l3;
        split_f16(x.x, h0, l0); split_f16(x.y, h1, l1);
        split_f16(x.z, h2, l2); split_f16(x.w, h3, l3);
        f16x4 hv = {h0, h1, h2, h3};
        f16x4 lv = {l0, l1, l2, l3};
        *(f16x4*)(qzh + (size_t)i4 * 4) = hv;
        *(f16x4*)(qzl + (size_t)i4 * 4) = lv;
    }
    if (i4 < UVN / 4) {
        float4 x = *(const float4*)(U + (size_t)i4 * 4);
        f16 h0, l0, h1, l1, h2, l2, h3, l3;
        split_f16(x.x, h0, l0); split_f16(x.y, h1, l1);
        split_f16(x.z, h2, l2); split_f16(x.w, h3, l3);
        f16x4 hv = {h0, h1, h2, h3};
        f16x4 lv = {l0, l1, l2, l3};
        *(f16x4*)(Uh + (size_t)i4 * 4) = hv;
        *(f16x4*)(Ul + (size_t)i4 * 4) = lv;
        float4 y = *(const float4*)(V + (size_t)i4 * 4);
        split_f16(y.x, h0, l0); split_f16(y.y, h1, l1);
        split_f16(y.z, h2, l2); split_f16(y.w, h3, l3);
        f16x4 hv2 = {h0, h1, h2, h3};
        f16x4 lv2 = {l0, l1, l2, l3};
        *(f16x4*)(Vh + (size_t)i4 * 4) = hv2;
        *(f16x4*)(Vl + (size_t)i4 * 4) = lv2;
    }
}

// ============================================================
// K1: dual GEMM qz@U^T, qz@V^T via fp16 MFMA 3-product emulation
// + RoPE (round-2 proven version, direct staging).
// ============================================================
__global__ __launch_bounds__(256, 2) void k1_proj(const f16* __restrict__ qzh,
                                                  const f16* __restrict__ qzl,
                                                  const f16* __restrict__ Uh,
                                                  const f16* __restrict__ Ul,
                                                  const f16* __restrict__ Vh,
                                                  const f16* __restrict__ Vl,
                                                  const float* __restrict__ cosb,
                                                  const float* __restrict__ sinb,
                                                  f16* __restrict__ uhp, f16* __restrict__ ulp,
                                                  f16* __restrict__ vhp, f16* __restrict__ vlp,
                                                  f16* __restrict__ vT, f16* __restrict__ oT) {
    __shared__ __align__(16) f16 smem[36864];            // 73728 B -> 2 blocks/CU
    f16* sAh  = smem;                                    // [64][72]
    f16* sAl  = smem + 4608;
    f16* sBuh = smem + 9216;                             // [96][72]
    f16* sBul = smem + 9216 + 6912;
    f16* sBvh = smem + 9216 + 2 * 6912;
    f16* sBvl = smem + 9216 + 3 * 6912;

    const int tid = threadIdx.x;
    const int w = tid >> 6, lane = tid & 63;
    const int quad = lane >> 4, l15 = lane & 15;
    const int wr = w >> 1, wc = w & 1;                   // 2x2 wave grid
    const int bs0 = blockIdx.x * 64;
    const int c = blockIdx.y;

    const f16* Ug_h = Uh + (size_t)c * 96 * 768;
    const f16* Ug_l = Ul + (size_t)c * 96 * 768;
    const f16* Vg_h = Vh + (size_t)c * 96 * 768;
    const f16* Vg_l = Vl + (size_t)c * 96 * 768;

    f32x4 aUS[2][3] = {}, aUX[2][3] = {};
    f32x4 aVS[2][3] = {}, aVX[2][3] = {};

    for (int k0 = 0; k0 < 768; k0 += 32) {
        __syncthreads();
        {
            int f = tid;
            int i = f >> 2, ec = f & 3;
            const size_t go = (size_t)(bs0 + i) * 768 + k0 + 8 * ec;
            const int lo = i * 72 + 8 * ec + ((k0 & 32) ? 32 : 0);
            (void)lo;
        }
        // stage A (qz hi/lo): 64 rows x 32 cols  (one 32-chunk per pass)
        {
            int f = tid;
            int row = f >> 2, cg = f & 3;
            const size_t go = (size_t)(bs0 + row) * 768 + k0 + cg * 8;
            const int lo = row * 72 + cg * 8;
            *(float4*)&sAh[lo] = *(const float4*)(qzh + go);
            *(float4*)&sAl[lo] = *(const float4*)(qzl + go);
        }
        // stage B (U,V hi/lo): 96 rows x 32 cols each
#pragma unroll
        for (int m = 0; m < 2; ++m) {
            int f = tid + 256 * m;
            if (f < 384) {
                int row = f >> 2, cg = f & 3;
                const size_t go = (size_t)row * 768 + k0 + cg * 8;
                const int lo = row * 72 + cg * 8;
                *(float4*)&sBuh[lo] = *(const float4*)(Ug_h + go);
                *(float4*)&sBul[lo] = *(const float4*)(Ug_l + go);
                *(float4*)&sBvh[lo] = *(const float4*)(Vg_h + go);
                *(float4*)&sBvl[lo] = *(const float4*)(Vg_l + go);
            }
        }
        __syncthreads();
        {
            f16x8 ah[2], al[2];
#pragma unroll
            for (int mt = 0; mt < 2; ++mt) {
                const int ar = (32 * wr + 16 * mt + l15) * 72 + quad * 8;
                ah[mt] = *(const f16x8*)&sAh[ar];
                al[mt] = *(const f16x8*)&sAl[ar];
            }
#pragma unroll
            for (int nt = 0; nt < 3; ++nt) {
                const int br = (48 * wc + 16 * nt + l15) * 72 + quad * 8;
                f16x8 buh = *(const f16x8*)&sBuh[br];
                f16x8 bul = *(const f16x8*)&sBul[br];
                f16x8 bvh = *(const f16x8*)&sBvh[br];
                f16x8 bvl = *(const f16x8*)&sBvl[br];
#pragma unroll
                for (int mt = 0; mt < 2; ++mt) {
                    aUS[mt][nt] = MFMA16(ah[mt], buh, aUS[mt][nt]);
                    aUX[mt][nt] = MFMA16(ah[mt], bul, aUX[mt][nt]);
                    aUX[mt][nt] = MFMA16(al[mt], buh, aUX[mt][nt]);
                    aVS[mt][nt] = MFMA16(ah[mt], bvh, aVS[mt][nt]);
                    aVX[mt][nt] = MFMA16(ah[mt], bvl, aVX[mt][nt]);
                    aVX[mt][nt] = MFMA16(al[mt], bvh, aVX[mt][nt]);
                }
            }
        }
    }

    // ---- epilogue: combine to fp32 in LDS, then the exact old epilogue ----
    __syncthreads();
    float* LU = (float*)smem;          // [64][100] = 25.6 KB
    float* LV = LU + 6400;
#pragma unroll
    for (int mt = 0; mt < 2; ++mt)
#pragma unroll
        for (int nt = 0; nt < 3; ++nt)
#pragma unroll
            for (int r = 0; r < 4; ++r) {
                const int sl = 32 * wr + 16 * mt + 4 * quad + r;
                const int col = 48 * wc + 16 * nt + l15;
                LU[sl * 100 + col] = aUS[mt][nt][r] + aUX[mt][nt][r] * INV2048;
                LV[sl * 100 + col] = aVS[mt][nt][r] + aVX[mt][nt][r] * INV2048;
            }
    __syncthreads();

    const int b = bs0 >> 11;
    const int s0 = bs0 & 2047;
    const int head = b * 8 + c;
    const size_t nb = (size_t)head * 2048 * 96;
    const size_t tb = (size_t)head * 96 * 2048;
    const int ty = tid >> 4, tx = tid & 15;

#pragma unroll
    for (int jj = 0; jj < 3; ++jj) {
        int r = tx + 16 * jj;
        f16 vt1[4], vt2[4], ot1[4], ot2[4];
#pragma unroll
        for (int ii = 0; ii < 4; ++ii) {
            int sl = 4 * ty + ii;
            int s = s0 + sl;
            int cbi = (b * 2048 + s) * 96 + r;
            float cc = cosb[cbi], ss = sinb[cbi];
            size_t rowb = nb + (size_t)s * 96;
            float u1 = LU[sl * 100 + r], u2 = LU[sl * 100 + r + 48];
            float v1 = LV[sl * 100 + r], v2 = LV[sl * 100 + r + 48];
            float ur1 = u1 * cc - u2 * ss, ur2 = u2 * cc + u1 * ss;
            float uo1 = u1 * cc + u2 * ss, uo2 = u2 * cc - u1 * ss;
            float vr1 = v1 * cc - v2 * ss, vr2 = v2 * cc + v1 * ss;
            f16 h, l;
            split_f16(ur1, h, l); uhp[rowb + r] = h;      ulp[rowb + r] = l;
            split_f16(ur2, h, l); uhp[rowb + r + 48] = h; ulp[rowb + r + 48] = l;
            split_f16(vr1, h, l); vhp[rowb + r] = h;      vlp[rowb + r] = l;      vt1[ii] = h;
            split_f16(vr2, h, l); vhp[rowb + r + 48] = h; vlp[rowb + r + 48] = l; vt2[ii] = h;
            ot1[ii] = (f16)uo1; ot2[ii] = (f16)uo2;
        }
        f16x4 pv1 = {vt1[0], vt1[1], vt1[2], vt1[3]};
        f16x4 pv2 = {vt2[0], vt2[1], vt2[2], vt2[3]};
        f16x4 po1 = {ot1[0], ot1[1], ot1[2], ot1[3]};
        f16x4 po2 = {ot2[0], ot2[1], ot2[2], ot2[3]};
        *(f16x4*)&vT[tb + (size_t)r * 2048 + s0 + 4 * ty] = pv1;
        *(f16x4*)&vT[tb + (size_t)(r + 48) * 2048 + s0 + 4 * ty] = pv2;
        *(f16x4*)&oT[tb + (size_t)r * 2048 + s0 + 4 * ty] = po1;
        *(f16x4*)&oT[tb + (size_t)(r + 48) * 2048 + s0 + 4 * ty] = po2;
    }
}

// ============================================================
// K2: MFMA row stats. Double-buffered Bh/Bl via global_load_lds
// (linear src+dst, unpadded [64][96]); 1 barrier per k-tile.
// Per-lane online (m,l); one 16-lane merge + cross-wave merge.
// ============================================================
__global__ __launch_bounds__(256, 2) void k2_stats(const f16* __restrict__ uhp,
                                                   const f16* __restrict__ ulp,
                                                   const f16* __restrict__ vhp,
                                                   const f16* __restrict__ vlp,
                                                   float* __restrict__ Mo,
                                                   float* __restrict__ Lo) {
    __shared__ f16 Bh[2][64 * 96];
    __shared__ f16 Bl[2][64 * 96];
    __shared__ float Mbuf[4][64], Lbuf[4][64];
    const int tid = threadIdx.x, w = tid >> 6, lane = tid & 63;
    const int quad = lane >> 4, l15 = lane & 15;
    const int q0 = blockIdx.x * 64, head = blockIdx.y;
    const f16* Ah_g = uhp + (size_t)head * 2048 * 96;
    const f16* Al_g = ulp + (size_t)head * 2048 * 96;
    const f16* Bh_g = vhp + (size_t)head * 2048 * 96;
    const f16* Bl_g = vlp + (size_t)head * 2048 * 96;

    f16x8 Afh[4][3], Afl[4][3];
#pragma unroll
    for (int mt = 0; mt < 4; ++mt)
#pragma unroll
        for (int cc = 0; cc < 3; ++cc) {
            size_t off = (size_t)(q0 + 16 * mt + l15) * 96 + cc * 32 + quad * 8;
            Afh[mt][cc] = *(const f16x8*)(Ah_g + off);
            Afl[mt][cc] = *(const f16x8*)(Al_g + off);
        }

    const int o0 = tid * 8;               // f16 offset of this thread's 16B chunk

    float m_run[4][4], l_run[4][4];
#pragma unroll
    for (int mt = 0; mt < 4; ++mt)
#pragma unroll
        for (int r = 0; r < 4; ++r) { m_run[mt][r] = -3.0e38f; l_run[mt][r] = 0.f; }

    // prologue: tile 0 into buf 0 (async) then barrier (drains vmcnt)
#pragma unroll
    for (int m = 0; m < 3; ++m) {
        gload16(Bh_g + o0 + 2048 * m, &Bh[0][o0 + 2048 * m]);
        gload16(Bl_g + o0 + 2048 * m, &Bl[0][o0 + 2048 * m]);
    }
    __syncthreads();

    for (int t = 0; t < 32; ++t) {
        const int cur = t & 1;
        if (t < 31) {
            const f16* bs = Bh_g + (size_t)(t + 1) * 6144;
            const f16* ls = Bl_g + (size_t)(t + 1) * 6144;
#pragma unroll
            for (int m = 0; m < 3; ++m) {
                gload16(bs + o0 + 2048 * m, &Bh[cur ^ 1][o0 + 2048 * m]);
                gload16(ls + o0 + 2048 * m, &Bl[cur ^ 1][o0 + 2048 * m]);
            }
        }
        f32x4 accS[4] = {}, accX[4] = {};
#pragma unroll
        for (int cc = 0; cc < 3; ++cc) {
            f16x8 bh = *(const f16x8*)&Bh[cur][(w * 16 + l15) * 96 + cc * 32 + quad * 8];
            f16x8 bl = *(const f16x8*)&Bl[cur][(w * 16 + l15) * 96 + cc * 32 + quad * 8];
#pragma unroll
            for (int mt = 0; mt < 4; ++mt) {
                accS[mt] = MFMA16(Afh[mt][cc], bh, accS[mt]);
                accX[mt] = MFMA16(Afh[mt][cc], bl, accX[mt]);
                accX[mt] = MFMA16(Afl[mt][cc], bh, accX[mt]);
            }
        }
        // per-lane online update only (hides the in-flight gloads)
#pragma unroll
        for (int mt = 0; mt < 4; ++mt)
#pragma unroll
            for (int r = 0; r < 4; ++r) {
                float zl = fmaf(ZC1, accS[mt][r], ZC2 * accX[mt][r]);
                float nm = fmaxf(m_run[mt][r], zl);
                l_run[mt][r] = fmaf(l_run[mt][r], exp2f(m_run[mt][r] - nm),
                                    exp2f(zl - nm));
                m_run[mt][r] = nm;
            }
        __syncthreads();   // next buf ready (vmcnt drained) + all reads of cur done
    }
    // merge the 16 per-lane column-partitions
#pragma unroll
    for (int mt = 0; mt < 4; ++mt)
#pragma unroll
        for (int r = 0; r < 4; ++r) {
            float m = m_run[mt][r], l = l_run[mt][r];
#pragma unroll
            for (int d = 1; d < 16; d <<= 1) {
                float mo = __shfl_xor(m, d), lo = __shfl_xor(l, d);
                float nm = fmaxf(m, mo);
                l = fmaf(l, exp2f(m - nm), lo * exp2f(mo - nm));
                m = nm;
            }
            m_run[mt][r] = m; l_run[mt][r] = l;
        }
    if (l15 == 0) {
#pragma unroll
        for (int mt = 0; mt < 4; ++mt)
#pragma unroll
            for (int r = 0; r < 4; ++r) {
                Mbuf[w][16 * mt + 4 * quad + r] = m_run[mt][r];
                Lbuf[w][16 * mt + 4 * quad + r] = l_run[mt][r];
            }
    }
    __syncthreads();
    if (tid < 64) {
        float M = -3.0e38f;
#pragma unroll
        for (int ww = 0; ww < 4; ++ww) M = fmaxf(M, Mbuf[ww][tid]);
        float L = 0.f;
#pragma unroll
        for (int ww = 0; ww < 4; ++ww) L += Lbuf[ww][tid] * exp2f(Mbuf[ww][tid] - M);
        Mo[head * 2048 + q0 + tid] = M;      // log2-domain max
        Lo[head * 2048 + q0 + tid] = L;
    }
}

// ============================================================
// K3a: S=ur.vr^T (x3 fp16 emulation, z bitwise == k2), P=exp2(zl-M[q]),
// out=P@vr, /L[q], rope_o -> w1. Bh/Bl double-buffered via
// global_load_lds (async, overlaps S-MFMA); Vt reg-staged with
// named regs (load mid-iter, store after tail barrier). 2 barriers/tile.
// ============================================================
__global__ __launch_bounds__(256, 2) void k3a(const f16* __restrict__ uhp,
                                              const f16* __restrict__ ulp,
                                              const f16* __restrict__ vhp,
                                              const f16* __restrict__ vlp,
                                              const f16* __restrict__ vT,
                                              const float* __restrict__ Mo,
                                              const float* __restrict__ Lo,
                                              const float* __restrict__ cosb,
                                              const float* __restrict__ sinb,
                                              f16* __restrict__ w1) {
    __shared__ f16 Bh[2][64 * 96];
    __shared__ f16 Bl[2][64 * 96];
    __shared__ f16 Vt[96 * 72];
    __shared__ f16 P[64 * 72];
    const int tid = threadIdx.x, w = tid >> 6, lane = tid & 63;
    const int quad = lane >> 4, l15 = lane & 15;
    const int q0 = blockIdx.x * 64, head = blockIdx.y;
    const f16* Ah_g = uhp + (size_t)head * 2048 * 96;
    const f16* Al_g = ulp + (size_t)head * 2048 * 96;
    const f16* Bh_g = vhp + (size_t)head * 2048 * 96;
    const f16* Bl_g = vlp + (size_t)head * 2048 * 96;
    const f16* Vt_g = vT + (size_t)head * 96 * 2048;

    f16x8 Afh[4][3], Afl[4][3];
#pragma unroll
    for (int mt = 0; mt < 4; ++mt)
#pragma unroll
        for (int cc = 0; cc < 3; ++cc) {
            size_t off = (size_t)(q0 + 16 * mt + l15) * 96 + cc * 32 + quad * 8;
            Afh[mt][cc] = *(const f16x8*)(Ah_g + off);
            Afl[mt][cc] = *(const f16x8*)(Al_g + off);
        }
    float negM[4][4];
#pragma unroll
    for (int mt = 0; mt < 4; ++mt)
#pragma unroll
        for (int r = 0; r < 4; ++r)
            negM[mt][r] = -Mo[head * 2048 + q0 + 16 * mt + 4 * quad + r];
    float invL[4];
#pragma unroll
    for (int r = 0; r < 4; ++r)
        invL[r] = 1.0f / Lo[head * 2048 + q0 + w * 16 + quad * 4 + r];

    const int o0 = tid * 8;                 // Bh/Bl linear chunk (f16 units)
    const int vr = tid >> 3;                // Vt rows vr, vr+32, vr+64
    const int vc = (tid & 7) * 8;
    float4 rv0, rv1, rv2;

    // prologue: tile0 Bh/Bl async; Vt tile0 regs
#pragma unroll
    for (int m = 0; m < 3; ++m) {
        gload16(Bh_g + o0 + 2048 * m, &Bh[0][o0 + 2048 * m]);
        gload16(Bl_g + o0 + 2048 * m, &Bl[0][o0 + 2048 * m]);
    }
    rv0 = *(const float4*)(Vt_g + (size_t)vr * 2048 + vc);
    rv1 = *(const float4*)(Vt_g + (size_t)(vr + 32) * 2048 + vc);
    rv2 = *(const float4*)(Vt_g + (size_t)(vr + 64) * 2048 + vc);
    __syncthreads();                        // buf0 ready
    *(float4*)&Vt[vr * 72 + vc] = rv0;      // visible at first P-barrier
    *(float4*)&Vt[(vr + 32) * 72 + vc] = rv1;
    *(float4*)&Vt[(vr + 64) * 72 + vc] = rv2;

    f32x4 accO[6] = {};

    for (int t = 0; t < 32; ++t) {
        const int cur = t & 1;
        if (t < 31) {                       // async: overlaps S-MFMA below
            const f16* bs = Bh_g + (size_t)(t + 1) * 6144;
            const f16* ls = Bl_g + (size_t)(t + 1) * 6144;
#pragma unroll
            for (int m = 0; m < 3; ++m) {
                gload16(bs + o0 + 2048 * m, &Bh[cur ^ 1][o0 + 2048 * m]);
                gload16(ls + o0 + 2048 * m, &Bl[cur ^ 1][o0 + 2048 * m]);
            }
        }
        f32x4 accS[4] = {}, accX[4] = {};
#pragma unroll
        for (int cc = 0; cc < 3; ++cc) {
            f16x8 bh = *(const f16x8*)&Bh[cur][(w * 16 + l15) * 96 + cc * 32 + quad * 8];
            f16x8 bl = *(const f16x8*)&Bl[cur][(w * 16 + l15) * 96 + cc * 32 + quad * 8];
#pragma unroll
            for (int mt = 0; mt < 4; ++mt) {
                accS[mt] = MFMA16(Afh[mt][cc], bh, accS[mt]);
                accX[mt] = MFMA16(Afh[mt][cc], bl, accX[mt]);
                accX[mt] = MFMA16(Afl[mt][cc], bh, accX[mt]);
            }
        }
        if (t < 31) {                       // Vt(t+1) -> regs (hidden under P+PV)
            const int kn = (t + 1) * 64;
            rv0 = *(const float4*)(Vt_g + (size_t)vr * 2048 + kn + vc);
            rv1 = *(const float4*)(Vt_g + (size_t)(vr + 32) * 2048 + kn + vc);
            rv2 = *(const float4*)(Vt_g + (size_t)(vr + 64) * 2048 + kn + vc);
        }
#pragma unroll
        for (int mt = 0; mt < 4; ++mt)
#pragma unroll
            for (int r = 0; r < 4; ++r) {
                float zl = fmaf(ZC1, accS[mt][r], ZC2 * accX[mt][r]);
                P[(16 * mt + 4 * quad + r) * 72 + w * 16 + l15] =
                    (f16)exp2f(zl + negM[mt][r]);
            }
        __syncthreads();                    // P + Vt(t) visible; gloads drained
#pragma unroll
        for (int kc = 0; kc < 2; ++kc) {
            f16x8 ap = *(const f16x8*)&P[(w * 16 + l15) * 72 + kc * 32 + quad * 8];
#pragma unroll
            for (int nt = 0; nt < 6; ++nt) {
                f16x8 bv = *(const f16x8*)&Vt[(nt * 16 + l15) * 72 + kc * 32 + quad * 8];
                accO[nt] = MFMA16(ap, bv, accO[nt]);
            }
        }
        __syncthreads();                    // PV reads done -> safe to overwrite
        if (t < 31) {
            *(float4*)&Vt[vr * 72 + vc] = rv0;
            *(float4*)&Vt[(vr + 32) * 72 + vc] = rv1;
            *(float4*)&Vt[(vr + 64) * 72 + vc] = rv2;
        }
    }
    const int b = head >> 3, c = head & 7;
#pragma unroll
    for (int r = 0; r < 4; ++r) {
        int q = q0 + w * 16 + quad * 4 + r;
        int cbi = (b * 2048 + q) * 96;
        f16* wrow = w1 + (size_t)(b * 2048 + q) * 768 + c * 96;
#pragma unroll
        for (int nt = 0; nt < 3; ++nt) {
            int rr = nt * 16 + l15;
            float cc = cosb[cbi + rr], ss = sinb[cbi + rr];
            float a = accO[nt][r] * invL[r];
            float b2 = accO[nt + 3][r] * invL[r];
            wrow[rr] = (f16)(a * cc + b2 * ss);
            wrow[rr + 48] = (f16)(b2 * cc - a * ss);
        }
    }
}

// ============================================================
// K3b: S2[q][k]=vr_q.ur_k (bitwise == k2's z transposed),
// P2=exp2(zl-M[k])/L[k], out=P2@uo, rope -> w2. Same pipeline as k3a.
// ============================================================
__global__ __launch_bounds__(256, 2) void k3b(const f16* __restrict__ uhp,
                                              const f16* __restrict__ ulp,
                                              const f16* __restrict__ vhp,
                                              const f16* __restrict__ vlp,
                                              const f16* __restrict__ oT,
                                              const float* __restrict__ Mo,
                                              const float* __restrict__ Lo,
                                              const float* __restrict__ cosb,
                                              const float* __restrict__ sinb,
                                              f16* __restrict__ w2) {
    __shared__ f16 Bh[2][64 * 96];
    __shared__ f16 Bl[2][64 * 96];
    __shared__ f16 Ot[96 * 72];
    __shared__ f16 P[64 * 72];
    const int tid = threadIdx.x, w = tid >> 6, lane = tid & 63;
    const int quad = lane >> 4, l15 = lane & 15;
    const int q0 = blockIdx.x * 64, head = blockIdx.y;
    const f16* Ah_g = vhp + (size_t)head * 2048 * 96;   // A = vr
    const f16* Al_g = vlp + (size_t)head * 2048 * 96;
    const f16* Bh_g = uhp + (size_t)head * 2048 * 96;   // B = ur
    const f16* Bl_g = ulp + (size_t)head * 2048 * 96;
    const f16* Ot_g = oT + (size_t)head * 96 * 2048;

    f16x8 Afh[4][3], Afl[4][3];
#pragma unroll
    for (int mt = 0; mt < 4; ++mt)
#pragma unroll
        for (int cc = 0; cc < 3; ++cc) {
            size_t off = (size_t)(q0 + 16 * mt + l15) * 96 + cc * 32 + quad * 8;
            Afh[mt][cc] = *(const f16x8*)(Ah_g + off);
            Afl[mt][cc] = *(const f16x8*)(Al_g + off);
        }

    const int o0 = tid * 8;
    const int vr = tid >> 3;
    const int vc = (tid & 7) * 8;
    float4 rv0, rv1, rv2;

#pragma unroll
    for (int m = 0; m < 3; ++m) {
        gload16(Bh_g + o0 + 2048 * m, &Bh[0][o0 + 2048 * m]);
        gload16(Bl_g + o0 + 2048 * m, &Bl[0][o0 + 2048 * m]);
    }
    rv0 = *(const float4*)(Ot_g + (size_t)vr * 2048 + vc);
    rv1 = *(const float4*)(Ot_g + (size_t)(vr + 32) * 2048 + vc);
    rv2 = *(const float4*)(Ot_g + (size_t)(vr + 64) * 2048 + vc);
    __syncthreads();
    *(float4*)&Ot[vr * 72 + vc] = rv0;
    *(float4*)&Ot[(vr + 32) * 72 + vc] = rv1;
    *(float4*)&Ot[(vr + 64) * 72 + vc] = rv2;

    f32x4 accO[6] = {};

    for (int t = 0; t < 32; ++t) {
        const int cur = t & 1;
        const int k0 = t * 64;
        float negMk = -Mo[head * 2048 + k0 + w * 16 + l15];
        float invLk = 1.0f / Lo[head * 2048 + k0 + w * 16 + l15];
        if (t < 31) {
            const f16* bs = Bh_g + (size_t)(t + 1) * 6144;
            const f16* ls = Bl_g + (size_t)(t + 1) * 6144;
#pragma unroll
            for (int m = 0; m < 3; ++m) {
                gload16(bs + o0 + 2048 * m, &Bh[cur ^ 1][o0 + 2048 * m]);
                gload16(ls + o0 + 2048 * m, &Bl[cur ^ 1][o0 + 2048 * m]);
            }
        }
        f32x4 accS[4] = {}, accX[4] = {};
#pragma unroll
        for (int cc = 0; cc < 3; ++cc) {
            f16x8 bh = *(const f16x8*)&Bh[cur][(w * 16 + l15) * 96 + cc * 32 + quad * 8];
            f16x8 bl = *(const f16x8*)&Bl[cur][(w * 16 + l15) * 96 + cc * 32 + quad * 8];
#pragma unroll
            for (int mt = 0; mt < 4; ++mt) {
                accS[mt] = MFMA16(Afh[mt][cc], bh, accS[mt]);
                // preserve k2's cross-product order: (u_hi*v_lo) first, then (u_lo*v_hi)
                accX[mt] = MFMA16(Afl[mt][cc], bh, accX[mt]);   // v_lo * u_hi
                accX[mt] = MFMA16(Afh[mt][cc], bl, accX[mt]);   // v_hi * u_lo
            }
        }
        if (t < 31) {
            const int kn = (t + 1) * 64;
            rv0 = *(const float4*)(Ot_g + (size_t)vr * 2048 + kn + vc);
            rv1 = *(const float4*)(Ot_g + (size_t)(vr + 32) * 2048 + kn + vc);
            rv2 = *(const float4*)(Ot_g + (size_t)(vr + 64) * 2048 + kn + vc);
        }
#pragma unroll
        for (int mt = 0; mt < 4; ++mt)
#pragma unroll
            for (int r = 0; r < 4; ++r) {
                float zl = fmaf(ZC1, accS[mt][r], ZC2 * accX[mt][r]);
                P[(16 * mt + 4 * quad + r) * 72 + w * 16 + l15] =
                    (f16)(exp2f(zl + negMk) * invLk);
            }
        __syncthreads();
#pragma unroll
        for (int kc = 0; kc < 2; ++kc) {
            f16x8 ap = *(const f16x8*)&P[(w * 16 + l15) * 72 + kc * 32 + quad * 8];
#pragma unroll
            for (int nt = 0; nt < 6; ++nt) {
                f16x8 bo = *(const f16x8*)&Ot[(nt * 16 + l15) * 72 + kc * 32 + quad * 8];
                accO[nt] = MFMA16(ap, bo, accO[nt]);
            }
        }
        __syncthreads();
        if (t < 31) {
            *(float4*)&Ot[vr * 72 + vc] = rv0;
            *(float4*)&Ot[(vr + 32) * 72 + vc] = rv1;
            *(float4*)&Ot[(vr + 64) * 72 + vc] = rv2;
        }
    }
    const int b = head >> 3, c = head & 7;
#pragma unroll
    for (int r = 0; r < 4; ++r) {
        int q = q0 + w * 16 + quad * 4 + r;
        int cbi = (b * 2048 + q) * 96;
        f16* wrow = w2 + (size_t)(b * 2048 + q) * 768 + c * 96;
#pragma unroll
        for (int nt = 0; nt < 3; ++nt) {
            int rr = nt * 16 + l15;
            float cc = cosb[cbi + rr], ss = sinb[cbi + rr];
            float a = accO[nt][r];
            float b2 = accO[nt + 3][r];
            wrow[rr] = (f16)(a * cc - b2 * ss);
            wrow[rr + 48] = (f16)(b2 * cc + a * ss);
        }
    }
}

// ============================================================
// K4: G = w1@U + w2@V (fp16 MFMA). grid (32 s-blocks, 12 d-blocks),
// block 256 (4 waves), tile 128s x 64d, wave strip 32s.
// ============================================================
__global__ __launch_bounds__(256, 2) void k4_final(const f16* __restrict__ w1,
                                                   const f16* __restrict__ w2,
                                                   const float* __restrict__ U,
                                                   const float* __restrict__ V,
                                                   float* __restrict__ outp) {
    __shared__ f16 A1[128 * 56];
    __shared__ f16 A2[128 * 56];
    __shared__ f16 B1[64 * 56];
    __shared__ f16 B2[64 * 56];
    const int tid = threadIdx.x, w = tid >> 6, lane = tid & 63;
    const int quad = lane >> 4, l15 = lane & 15;
    const int bs0 = blockIdx.x * 128;
    const int d0 = blockIdx.y * 64;
    f32x4 acc[2][4] = {};

    for (int ec = 0; ec < 24; ++ec) {
        int e0 = ec * 32;
        __syncthreads();
#pragma unroll
        for (int m = 0; m < 2; ++m) {
            int f = tid + 256 * m;
            int row = f >> 2, q = f & 3;
            *(float4*)&A1[row * 56 + q * 8] =
                *(const float4*)(w1 + (size_t)(bs0 + row) * 768 + e0 + q * 8);
            *(float4*)&A2[row * 56 + q * 8] =
                *(const float4*)(w2 + (size_t)(bs0 + row) * 768 + e0 + q * 8);
        }
#pragma unroll
        for (int m2 = 0; m2 < 2; ++m2) {
            int e_r = (tid >> 4) + 16 * m2;
            int dc = tid & 15;
            float4 fu = *(const float4*)(U + (size_t)(e0 + e_r) * 768 + d0 + dc * 4);
            float4 fv = *(const float4*)(V + (size_t)(e0 + e_r) * 768 + d0 + dc * 4);
            B1[(dc * 4 + 0) * 56 + e_r] = (f16)fu.x;
            B1[(dc * 4 + 1) * 56 + e_r] = (f16)fu.y;
            B1[(dc * 4 + 2) * 56 + e_r] = (f16)fu.z;
            B1[(dc * 4 + 3) * 56 + e_r] = (f16)fu.w;
            B2[(dc * 4 + 0) * 56 + e_r] = (f16)fv.x;
            B2[(dc * 4 + 1) * 56 + e_r] = (f16)fv.y;
            B2[(dc * 4 + 2) * 56 + e_r] = (f16)fv.z;
            B2[(dc * 4 + 3) * 56 + e_r] = (f16)fv.w;
        }
        __syncthreads();
        f16x8 a1f[2], a2f[2];
#pragma unroll
        for (int mt = 0; mt < 2; ++mt) {
            a1f[mt] = *(const f16x8*)&A1[(32 * w + 16 * mt + l15) * 56 + quad * 8];
            a2f[mt] = *(const f16x8*)&A2[(32 * w + 16 * mt + l15) * 56 + quad * 8];
        }
#pragma unroll
        for (int nt = 0; nt < 4; ++nt) {
            f16x8 b1f = *(const f16x8*)&B1[(nt * 16 + l15) * 56 + quad * 8];
            f16x8 b2f = *(const f16x8*)&B2[(nt * 16 + l15) * 56 + quad * 8];
#pragma unroll
            for (int mt = 0; mt < 2; ++mt) {
                acc[mt][nt] = MFMA16(a1f[mt], b1f, acc[mt][nt]);
                acc[mt][nt] = MFMA16(a2f[mt], b2f, acc[mt][nt]);
            }
        }
    }
#pragma unroll
    for (int mt = 0; mt < 2; ++mt)
#pragma unroll
        for (int nt = 0; nt < 4; ++nt)
#pragma unroll
            for (int r = 0; r < 4; ++r) {
                int s = bs0 + 32 * w + 16 * mt + 4 * quad + r;
                int d = d0 + 16 * nt + l15;
                outp[(size_t)s * 768 + d] = acc[mt][nt][r];
            }
}

extern "C" void kernel_launch(void* const* d_in, const int* in_sizes, int n_in,
                              void* d_out, int out_size, void* d_ws, size_t ws_size,
                              hipStream_t stream) {
    const float* qz   = (const float*)d_in[0];
    const float* cosb = (const float*)d_in[1];
    const float* sinb = (const float*)d_in[2];
    const float* U    = (const float*)d_in[3];
    const float* V    = (const float*)d_in[4];
    float* outp = (float*)d_out;

    f16* ws16 = (f16*)d_ws;
    f16* uhp = ws16;
    f16* ulp = ws16 + HN;
    f16* vhp = ws16 + 2 * HN;
    f16* vlp = ws16 + 3 * HN;
    f16* vT  = ws16 + 4 * HN;
    f16* oT  = ws16 + 5 * HN;
    f16* w1  = ws16 + 6 * HN;
    f16* w2  = ws16 + 7 * HN;
    float* Mo = (float*)(ws16 + 8 * HN);
    float* Lo = Mo + 16 * 2048;

    // qz hi/lo splits live in the w1/w2 slots (dead until k3a/k3b write them).
    f16* qzh = w1;
    f16* qzl = w2;
    // U/V hi/lo splits live in d_out scratch (overwritten by k4 at the end).
    f16* outw = (f16*)d_out;
    f16* Uh = outw;
    f16* Ul = outw + UVN;
    f16* Vh = outw + 2 * UVN;
    f16* Vl = outw + 3 * UVN;

    k0_split<<<dim3(3072), 256, 0, stream>>>(qz, U, V, qzh, qzl, Uh, Ul, Vh, Vl);
    k1_proj<<<dim3(64, 8), 256, 0, stream>>>(qzh, qzl, Uh, Ul, Vh, Vl, cosb, sinb,
                                             uhp, ulp, vhp, vlp, vT, oT);
    k2_stats<<<dim3(32, 16), 256, 0, stream>>>(uhp, ulp, vhp, vlp, Mo, Lo);
    k3a<<<dim3(32, 16), 256, 0, stream>>>(uhp, ulp, vhp, vlp, vT, Mo, Lo, cosb, sinb, w1);
    k3b<<<dim3(32, 16), 256, 0, stream>>>(uhp, ulp, vhp, vlp, oT, Mo, Lo, cosb, sinb, w2);
    k4_final<<<dim3(32, 12), 256, 0, stream>>>(w1, w2, U, V, outp);
}

// Round 5
// 339.847 us; speedup vs baseline: 2.3009x; 1.1768x over previous
//
#include <hip/hip_runtime.h>

typedef _Float16 f16;
typedef _Float16 f16x8 __attribute__((ext_vector_type(8)));
typedef _Float16 f16x4 __attribute__((ext_vector_type(4)));
typedef float f32x4 __attribute__((ext_vector_type(4)));

#define MFMA16(A,B,C) __builtin_amdgcn_mfma_f32_16x16x32_f16(A,B,C,0,0,0)
#define INV2048 4.8828125e-4f
#define HN (16ll*2048*96)
#define UVN 589824   // 768*768
// z in log2 domain: zl = log2(e)*768*accS + log2(e)*768/2048*accX
#define ZC1 1107.98979f
#define ZC2 0.54101064f

__device__ __forceinline__ void split_f16(float x, f16& h, f16& l) {
    h = (f16)x;
    l = (f16)((x - (float)h) * 2048.0f);   // lo pre-scaled by 2^11 (avoids fp16 denorm loss)
}

// ============================================================
// K0: split qz, U, V (fp32) into fp16 hi/lo pairs.
// ============================================================
__global__ __launch_bounds__(256) void k0_split(const float* __restrict__ qz,
                                                const float* __restrict__ U,
                                                const float* __restrict__ V,
                                                f16* __restrict__ qzh, f16* __restrict__ qzl,
                                                f16* __restrict__ Uh, f16* __restrict__ Ul,
                                                f16* __restrict__ Vh, f16* __restrict__ Vl) {
    const int i4 = blockIdx.x * 256 + threadIdx.x;   // float4 index
    {
        float4 x = *(const float4*)(qz + (size_t)i4 * 4);
        f16 h0, l0, h1, l1, h2, l2, h3, l3;
        split_f16(x.x, h0, l0); split_f16(x.y, h1, l1);
        split_f16(x.z, h2, l2); split_f16(x.w, h3, l3);
        f16x4 hv = {h0, h1, h2, h3};
        f16x4 lv = {l0, l1, l2, l3};
        *(f16x4*)(qzh + (size_t)i4 * 4) = hv;
        *(f16x4*)(qzl + (size_t)i4 * 4) = lv;
    }
    if (i4 < UVN / 4) {
        float4 x = *(const float4*)(U + (size_t)i4 * 4);
        f16 h0, l0, h1, l1, h2, l2, h3, l3;
        split_f16(x.x, h0, l0); split_f16(x.y, h1, l1);
        split_f16(x.z, h2, l2); split_f16(x.w, h3, l3);
        f16x4 hv = {h0, h1, h2, h3};
        f16x4 lv = {l0, l1, l2, l3};
        *(f16x4*)(Uh + (size_t)i4 * 4) = hv;
        *(f16x4*)(Ul + (size_t)i4 * 4) = lv;
        float4 y = *(const float4*)(V + (size_t)i4 * 4);
        split_f16(y.x, h0, l0); split_f16(y.y, h1, l1);
        split_f16(y.z, h2, l2); split_f16(y.w, h3, l3);
        f16x4 hv2 = {h0, h1, h2, h3};
        f16x4 lv2 = {l0, l1, l2, l3};
        *(f16x4*)(Vh + (size_t)i4 * 4) = hv2;
        *(f16x4*)(Vl + (size_t)i4 * 4) = lv2;
    }
}

// ============================================================
// K1: dual GEMM qz@U^T, qz@V^T via fp16 MFMA 3-product emulation
// (hi*hi, hi*lo, lo*hi; lo pre-scaled 2^11) + RoPE; round-2 proven
// version. Block 256 = 4 waves (2x2), tile 64s x 96r, K-chunk 64.
// ============================================================
__global__ __launch_bounds__(256, 2) void k1_proj(const f16* __restrict__ qzh,
                                                  const f16* __restrict__ qzl,
                                                  const f16* __restrict__ Uh,
                                                  const f16* __restrict__ Ul,
                                                  const f16* __restrict__ Vh,
                                                  const f16* __restrict__ Vl,
                                                  const float* __restrict__ cosb,
                                                  const float* __restrict__ sinb,
                                                  f16* __restrict__ uhp, f16* __restrict__ ulp,
                                                  f16* __restrict__ vhp, f16* __restrict__ vlp,
                                                  f16* __restrict__ vT, f16* __restrict__ oT) {
    __shared__ __align__(16) f16 smem[36864];            // 73728 B -> 2 blocks/CU
    f16* sAh  = smem;                                    // [64][72]
    f16* sAl  = smem + 4608;
    f16* sBuh = smem + 9216;                             // [96][72]
    f16* sBul = smem + 9216 + 6912;
    f16* sBvh = smem + 9216 + 2 * 6912;
    f16* sBvl = smem + 9216 + 3 * 6912;

    const int tid = threadIdx.x;
    const int w = tid >> 6, lane = tid & 63;
    const int quad = lane >> 4, l15 = lane & 15;
    const int wr = w >> 1, wc = w & 1;                   // 2x2 wave grid
    const int bs0 = blockIdx.x * 64;
    const int c = blockIdx.y;

    const f16* Ug_h = Uh + (size_t)c * 96 * 768;
    const f16* Ug_l = Ul + (size_t)c * 96 * 768;
    const f16* Vg_h = Vh + (size_t)c * 96 * 768;
    const f16* Vg_l = Vl + (size_t)c * 96 * 768;

    f32x4 aUS[2][3] = {}, aUX[2][3] = {};
    f32x4 aVS[2][3] = {}, aVX[2][3] = {};

    for (int k0 = 0; k0 < 768; k0 += 64) {
        __syncthreads();
        // stage A (qz hi/lo): 64 rows x 64 cols
#pragma unroll
        for (int m = 0; m < 2; ++m) {
            int f = tid + 256 * m, row = f >> 3, cg = f & 7;
            const size_t go = (size_t)(bs0 + row) * 768 + k0 + cg * 8;
            const int lo = row * 72 + cg * 8;
            *(float4*)&sAh[lo] = *(const float4*)(qzh + go);
            *(float4*)&sAl[lo] = *(const float4*)(qzl + go);
        }
        // stage B (U,V hi/lo): 96 rows x 64 cols each
#pragma unroll
        for (int m = 0; m < 3; ++m) {
            int f = tid + 256 * m, row = f >> 3, cg = f & 7;
            const size_t go = (size_t)row * 768 + k0 + cg * 8;
            const int lo = row * 72 + cg * 8;
            *(float4*)&sBuh[lo] = *(const float4*)(Ug_h + go);
            *(float4*)&sBul[lo] = *(const float4*)(Ug_l + go);
            *(float4*)&sBvh[lo] = *(const float4*)(Vg_h + go);
            *(float4*)&sBvl[lo] = *(const float4*)(Vg_l + go);
        }
        __syncthreads();
#pragma unroll
        for (int cc = 0; cc < 2; ++cc) {
            f16x8 ah[2], al[2];
#pragma unroll
            for (int mt = 0; mt < 2; ++mt) {
                const int ar = (32 * wr + 16 * mt + l15) * 72 + cc * 32 + quad * 8;
                ah[mt] = *(const f16x8*)&sAh[ar];
                al[mt] = *(const f16x8*)&sAl[ar];
            }
#pragma unroll
            for (int nt = 0; nt < 3; ++nt) {
                const int br = (48 * wc + 16 * nt + l15) * 72 + cc * 32 + quad * 8;
                f16x8 buh = *(const f16x8*)&sBuh[br];
                f16x8 bul = *(const f16x8*)&sBul[br];
                f16x8 bvh = *(const f16x8*)&sBvh[br];
                f16x8 bvl = *(const f16x8*)&sBvl[br];
#pragma unroll
                for (int mt = 0; mt < 2; ++mt) {
                    aUS[mt][nt] = MFMA16(ah[mt], buh, aUS[mt][nt]);
                    aUX[mt][nt] = MFMA16(ah[mt], bul, aUX[mt][nt]);
                    aUX[mt][nt] = MFMA16(al[mt], buh, aUX[mt][nt]);
                    aVS[mt][nt] = MFMA16(ah[mt], bvh, aVS[mt][nt]);
                    aVX[mt][nt] = MFMA16(ah[mt], bvl, aVX[mt][nt]);
                    aVX[mt][nt] = MFMA16(al[mt], bvh, aVX[mt][nt]);
                }
            }
        }
    }

    // ---- epilogue: combine to fp32 in LDS (RoPE pairs r / r+48 span both
    // wave-columns), then run the exact old epilogue from LDS. ----
    __syncthreads();
    float* LU = (float*)smem;          // [64][100] = 25.6 KB
    float* LV = LU + 6400;             // fits in the 73.7 KB staging buffer
#pragma unroll
    for (int mt = 0; mt < 2; ++mt)
#pragma unroll
        for (int nt = 0; nt < 3; ++nt)
#pragma unroll
            for (int r = 0; r < 4; ++r) {
                const int sl = 32 * wr + 16 * mt + 4 * quad + r;
                const int col = 48 * wc + 16 * nt + l15;
                LU[sl * 100 + col] = aUS[mt][nt][r] + aUX[mt][nt][r] * INV2048;
                LV[sl * 100 + col] = aVS[mt][nt][r] + aVX[mt][nt][r] * INV2048;
            }
    __syncthreads();

    const int b = bs0 >> 11;
    const int s0 = bs0 & 2047;
    const int head = b * 8 + c;
    const size_t nb = (size_t)head * 2048 * 96;
    const size_t tb = (size_t)head * 96 * 2048;
    const int ty = tid >> 4, tx = tid & 15;

#pragma unroll
    for (int jj = 0; jj < 3; ++jj) {
        int r = tx + 16 * jj;
        f16 vt1[4], vt2[4], ot1[4], ot2[4];
#pragma unroll
        for (int ii = 0; ii < 4; ++ii) {
            int sl = 4 * ty + ii;
            int s = s0 + sl;
            int cbi = (b * 2048 + s) * 96 + r;
            float cc = cosb[cbi], ss = sinb[cbi];
            size_t rowb = nb + (size_t)s * 96;
            float u1 = LU[sl * 100 + r], u2 = LU[sl * 100 + r + 48];
            float v1 = LV[sl * 100 + r], v2 = LV[sl * 100 + r + 48];
            float ur1 = u1 * cc - u2 * ss, ur2 = u2 * cc + u1 * ss;
            float uo1 = u1 * cc + u2 * ss, uo2 = u2 * cc - u1 * ss;
            float vr1 = v1 * cc - v2 * ss, vr2 = v2 * cc + v1 * ss;
            f16 h, l;
            split_f16(ur1, h, l); uhp[rowb + r] = h;      ulp[rowb + r] = l;
            split_f16(ur2, h, l); uhp[rowb + r + 48] = h; ulp[rowb + r + 48] = l;
            split_f16(vr1, h, l); vhp[rowb + r] = h;      vlp[rowb + r] = l;      vt1[ii] = h;
            split_f16(vr2, h, l); vhp[rowb + r + 48] = h; vlp[rowb + r + 48] = l; vt2[ii] = h;
            ot1[ii] = (f16)uo1; ot2[ii] = (f16)uo2;
        }
        f16x4 pv1 = {vt1[0], vt1[1], vt1[2], vt1[3]};
        f16x4 pv2 = {vt2[0], vt2[1], vt2[2], vt2[3]};
        f16x4 po1 = {ot1[0], ot1[1], ot1[2], ot1[3]};
        f16x4 po2 = {ot2[0], ot2[1], ot2[2], ot2[3]};
        *(f16x4*)&vT[tb + (size_t)r * 2048 + s0 + 4 * ty] = pv1;
        *(f16x4*)&vT[tb + (size_t)(r + 48) * 2048 + s0 + 4 * ty] = pv2;
        *(f16x4*)&oT[tb + (size_t)r * 2048 + s0 + 4 * ty] = po1;
        *(f16x4*)&oT[tb + (size_t)(r + 48) * 2048 + s0 + 4 * ty] = po2;
    }
}

// ============================================================
// K2: MFMA row MAX only (L is produced by k3a's ones-column PV).
// Same 36 MFMAs (exact z), but per-tile VALU is a single fmax per
// element — no exp. Final: 16-lane max merge + cross-wave max.
// ============================================================
__global__ __launch_bounds__(256, 2) void k2_stats(const f16* __restrict__ uhp,
                                                   const f16* __restrict__ ulp,
                                                   const f16* __restrict__ vhp,
                                                   const f16* __restrict__ vlp,
                                                   float* __restrict__ Mo) {
    __shared__ f16 Bh[64 * 104];
    __shared__ f16 Bl[64 * 104];
    __shared__ float Mbuf[4][64];
    const int tid = threadIdx.x, w = tid >> 6, lane = tid & 63;
    const int quad = lane >> 4, l15 = lane & 15;
    const int q0 = blockIdx.x * 64, head = blockIdx.y;
    const f16* Ah_g = uhp + (size_t)head * 2048 * 96;
    const f16* Al_g = ulp + (size_t)head * 2048 * 96;
    const f16* Bh_g = vhp + (size_t)head * 2048 * 96;
    const f16* Bl_g = vlp + (size_t)head * 2048 * 96;

    f16x8 Afh[4][3], Afl[4][3];
#pragma unroll
    for (int mt = 0; mt < 4; ++mt)
#pragma unroll
        for (int cc = 0; cc < 3; ++cc) {
            size_t off = (size_t)(q0 + 16 * mt + l15) * 96 + cc * 32 + quad * 8;
            Afh[mt][cc] = *(const f16x8*)(Ah_g + off);
            Afl[mt][cc] = *(const f16x8*)(Al_g + off);
        }

    float m_run[4][4];
#pragma unroll
    for (int mt = 0; mt < 4; ++mt)
#pragma unroll
        for (int r = 0; r < 4; ++r) m_run[mt][r] = -3.0e38f;

    for (int k0 = 0; k0 < 2048; k0 += 64) {
        __syncthreads();
#pragma unroll
        for (int m = 0; m < 3; ++m) {
            int f = tid + 256 * m;
            int row = f / 12, c12 = f % 12;
            *(float4*)&Bh[row * 104 + c12 * 8] =
                *(const float4*)(Bh_g + (size_t)(k0 + row) * 96 + c12 * 8);
            *(float4*)&Bl[row * 104 + c12 * 8] =
                *(const float4*)(Bl_g + (size_t)(k0 + row) * 96 + c12 * 8);
        }
        __syncthreads();
        f32x4 accS[4] = {}, accX[4] = {};
#pragma unroll
        for (int cc = 0; cc < 3; ++cc) {
            f16x8 bh = *(const f16x8*)&Bh[(w * 16 + l15) * 104 + cc * 32 + quad * 8];
            f16x8 bl = *(const f16x8*)&Bl[(w * 16 + l15) * 104 + cc * 32 + quad * 8];
#pragma unroll
            for (int mt = 0; mt < 4; ++mt) {
                accS[mt] = MFMA16(Afh[mt][cc], bh, accS[mt]);
                accX[mt] = MFMA16(Afh[mt][cc], bl, accX[mt]);
                accX[mt] = MFMA16(Afl[mt][cc], bh, accX[mt]);
            }
        }
        // per-lane running max only — no exp work
#pragma unroll
        for (int mt = 0; mt < 4; ++mt)
#pragma unroll
            for (int r = 0; r < 4; ++r) {
                float zl = fmaf(ZC1, accS[mt][r], ZC2 * accX[mt][r]);
                m_run[mt][r] = fmaxf(m_run[mt][r], zl);
            }
    }
    // merge the 16 per-lane column-partitions (max is order-independent)
#pragma unroll
    for (int mt = 0; mt < 4; ++mt)
#pragma unroll
        for (int r = 0; r < 4; ++r) {
            float m = m_run[mt][r];
            m = fmaxf(m, __shfl_xor(m, 1)); m = fmaxf(m, __shfl_xor(m, 2));
            m = fmaxf(m, __shfl_xor(m, 4)); m = fmaxf(m, __shfl_xor(m, 8));
            m_run[mt][r] = m;
        }
    if (l15 == 0) {
#pragma unroll
        for (int mt = 0; mt < 4; ++mt)
#pragma unroll
            for (int r = 0; r < 4; ++r)
                Mbuf[w][16 * mt + 4 * quad + r] = m_run[mt][r];
    }
    __syncthreads();
    if (tid < 64) {
        float M = -3.0e38f;
#pragma unroll
        for (int ww = 0; ww < 4; ++ww) M = fmaxf(M, Mbuf[ww][tid]);
        Mo[head * 2048 + q0 + tid] = M;      // log2-domain exact row max
    }
}

// ============================================================
// K3a: S=ur.vr^T (x3 fp16 emulation, z bitwise == k2), P=exp2(zl-M[q]),
// out=P@vr, row-sums L via ones-column MFMA (nt=6), scale 1/L,
// rope_o -> w1; writes Lo for k3b. Round-2 schedule (3 barriers/tile).
// ============================================================
__global__ __launch_bounds__(256, 2) void k3a(const f16* __restrict__ uhp,
                                              const f16* __restrict__ ulp,
                                              const f16* __restrict__ vhp,
                                              const f16* __restrict__ vlp,
                                              const f16* __restrict__ vT,
                                              const float* __restrict__ Mo,
                                              float* __restrict__ Lo,
                                              const float* __restrict__ cosb,
                                              const float* __restrict__ sinb,
                                              f16* __restrict__ w1) {
    __shared__ f16 Bh[64 * 104];
    __shared__ f16 Bl[64 * 104];
    __shared__ f16 Vt[112 * 72];       // rows 96..111 = ones (row-sum column block)
    __shared__ f16 P[64 * 72];
    const int tid = threadIdx.x, w = tid >> 6, lane = tid & 63;
    const int quad = lane >> 4, l15 = lane & 15;
    const int q0 = blockIdx.x * 64, head = blockIdx.y;
    const f16* Ah_g = uhp + (size_t)head * 2048 * 96;
    const f16* Al_g = ulp + (size_t)head * 2048 * 96;
    const f16* Bh_g = vhp + (size_t)head * 2048 * 96;
    const f16* Bl_g = vlp + (size_t)head * 2048 * 96;
    const f16* Vt_g = vT + (size_t)head * 96 * 2048;

    f16x8 Afh[4][3], Afl[4][3];
#pragma unroll
    for (int mt = 0; mt < 4; ++mt)
#pragma unroll
        for (int cc = 0; cc < 3; ++cc) {
            size_t off = (size_t)(q0 + 16 * mt + l15) * 96 + cc * 32 + quad * 8;
            Afh[mt][cc] = *(const f16x8*)(Ah_g + off);
            Afl[mt][cc] = *(const f16x8*)(Al_g + off);
        }
    float negM[4][4];
#pragma unroll
    for (int mt = 0; mt < 4; ++mt)
#pragma unroll
        for (int r = 0; r < 4; ++r)
            negM[mt][r] = -Mo[head * 2048 + q0 + 16 * mt + 4 * quad + r];

    // ones rows for the row-sum MFMA (written once, never overwritten)
    if (tid < 144) {
        f16x8 ones = {(f16)1, (f16)1, (f16)1, (f16)1,
                      (f16)1, (f16)1, (f16)1, (f16)1};
        *(f16x8*)&Vt[96 * 72 + tid * 8] = ones;
    }

    f32x4 accO[7] = {};

    for (int k0 = 0; k0 < 2048; k0 += 64) {
        __syncthreads();
#pragma unroll
        for (int m = 0; m < 3; ++m) {
            int f = tid + 256 * m;
            int row = f / 12, c12 = f % 12;
            *(float4*)&Bh[row * 104 + c12 * 8] =
                *(const float4*)(Bh_g + (size_t)(k0 + row) * 96 + c12 * 8);
            *(float4*)&Bl[row * 104 + c12 * 8] =
                *(const float4*)(Bl_g + (size_t)(k0 + row) * 96 + c12 * 8);
        }
#pragma unroll
        for (int m = 0; m < 3; ++m) {
            int f = tid + 256 * m;
            int row = f >> 3, c8 = f & 7;
            *(float4*)&Vt[row * 72 + c8 * 8] =
                *(const float4*)(Vt_g + (size_t)row * 2048 + k0 + c8 * 8);
        }
        __syncthreads();
        f32x4 accS[4] = {}, accX[4] = {};
#pragma unroll
        for (int cc = 0; cc < 3; ++cc) {
            f16x8 bh = *(const f16x8*)&Bh[(w * 16 + l15) * 104 + cc * 32 + quad * 8];
            f16x8 bl = *(const f16x8*)&Bl[(w * 16 + l15) * 104 + cc * 32 + quad * 8];
#pragma unroll
            for (int mt = 0; mt < 4; ++mt) {
                accS[mt] = MFMA16(Afh[mt][cc], bh, accS[mt]);
                accX[mt] = MFMA16(Afh[mt][cc], bl, accX[mt]);
                accX[mt] = MFMA16(Afl[mt][cc], bh, accX[mt]);
            }
        }
#pragma unroll
        for (int mt = 0; mt < 4; ++mt)
#pragma unroll
            for (int r = 0; r < 4; ++r) {
                float zl = fmaf(ZC1, accS[mt][r], ZC2 * accX[mt][r]);
                P[(16 * mt + 4 * quad + r) * 72 + w * 16 + l15] =
                    (f16)exp2f(zl + negM[mt][r]);
            }
        __syncthreads();
#pragma unroll
        for (int kc = 0; kc < 2; ++kc) {
            f16x8 ap = *(const f16x8*)&P[(w * 16 + l15) * 72 + kc * 32 + quad * 8];
#pragma unroll
            for (int nt = 0; nt < 7; ++nt) {   // nt=6: ones rows -> row sums (L)
                f16x8 bv = *(const f16x8*)&Vt[(nt * 16 + l15) * 72 + kc * 32 + quad * 8];
                accO[nt] = MFMA16(ap, bv, accO[nt]);
            }
        }
        __syncthreads();
    }
    // L for this wave's q rows comes straight out of the PV (f16-consistent)
    float invL[4];
#pragma unroll
    for (int r = 0; r < 4; ++r) invL[r] = 1.0f / accO[6][r];
    if (l15 == 0) {
#pragma unroll
        for (int r = 0; r < 4; ++r)
            Lo[head * 2048 + q0 + w * 16 + quad * 4 + r] = accO[6][r];
    }

    const int b = head >> 3, c = head & 7;
#pragma unroll
    for (int r = 0; r < 4; ++r) {
        int q = q0 + w * 16 + quad * 4 + r;
        int cbi = (b * 2048 + q) * 96;
        f16* wrow = w1 + (size_t)(b * 2048 + q) * 768 + c * 96;
#pragma unroll
        for (int nt = 0; nt < 3; ++nt) {
            int rr = nt * 16 + l15;
            float cc = cosb[cbi + rr], ss = sinb[cbi + rr];
            float a = accO[nt][r] * invL[r];
            float b2 = accO[nt + 3][r] * invL[r];
            wrow[rr] = (f16)(a * cc + b2 * ss);
            wrow[rr + 48] = (f16)(b2 * cc - a * ss);
        }
    }
}

// ============================================================
// K3b: S2[q][k]=vr_q.ur_k (bitwise == k3a's z transposed),
// P2=exp2(zl-M[k])/L[k], out=P2@uo, rope -> w2. (round-2 version)
// ============================================================
__global__ __launch_bounds__(256, 2) void k3b(const f16* __restrict__ uhp,
                                              const f16* __restrict__ ulp,
                                              const f16* __restrict__ vhp,
                                              const f16* __restrict__ vlp,
                                              const f16* __restrict__ oT,
                                              const float* __restrict__ Mo,
                                              const float* __restrict__ Lo,
                                              const float* __restrict__ cosb,
                                              const float* __restrict__ sinb,
                                              f16* __restrict__ w2) {
    __shared__ f16 Bh[64 * 104];
    __shared__ f16 Bl[64 * 104];
    __shared__ f16 Ot[96 * 72];
    __shared__ f16 P[64 * 72];
    const int tid = threadIdx.x, w = tid >> 6, lane = tid & 63;
    const int quad = lane >> 4, l15 = lane & 15;
    const int q0 = blockIdx.x * 64, head = blockIdx.y;
    const f16* Ah_g = vhp + (size_t)head * 2048 * 96;   // A = vr
    const f16* Al_g = vlp + (size_t)head * 2048 * 96;
    const f16* Bh_g = uhp + (size_t)head * 2048 * 96;   // B = ur
    const f16* Bl_g = ulp + (size_t)head * 2048 * 96;
    const f16* Ot_g = oT + (size_t)head * 96 * 2048;

    f16x8 Afh[4][3], Afl[4][3];
#pragma unroll
    for (int mt = 0; mt < 4; ++mt)
#pragma unroll
        for (int cc = 0; cc < 3; ++cc) {
            size_t off = (size_t)(q0 + 16 * mt + l15) * 96 + cc * 32 + quad * 8;
            Afh[mt][cc] = *(const f16x8*)(Ah_g + off);
            Afl[mt][cc] = *(const f16x8*)(Al_g + off);
        }

    f32x4 accO[6] = {};

    for (int k0 = 0; k0 < 2048; k0 += 64) {
        float negMk = -Mo[head * 2048 + k0 + w * 16 + l15];
        float invLk = 1.0f / Lo[head * 2048 + k0 + w * 16 + l15];
        __syncthreads();
#pragma unroll
        for (int m = 0; m < 3; ++m) {
            int f = tid + 256 * m;
            int row = f / 12, c12 = f % 12;
            *(float4*)&Bh[row * 104 + c12 * 8] =
                *(const float4*)(Bh_g + (size_t)(k0 + row) * 96 + c12 * 8);
            *(float4*)&Bl[row * 104 + c12 * 8] =
                *(const float4*)(Bl_g + (size_t)(k0 + row) * 96 + c12 * 8);
        }
#pragma unroll
        for (int m = 0; m < 3; ++m) {
            int f = tid + 256 * m;
            int row = f >> 3, c8 = f & 7;
            *(float4*)&Ot[row * 72 + c8 * 8] =
                *(const float4*)(Ot_g + (size_t)row * 2048 + k0 + c8 * 8);
        }
        __syncthreads();
        f32x4 accS[4] = {}, accX[4] = {};
#pragma unroll
        for (int cc = 0; cc < 3; ++cc) {
            f16x8 bh = *(const f16x8*)&Bh[(w * 16 + l15) * 104 + cc * 32 + quad * 8];
            f16x8 bl = *(const f16x8*)&Bl[(w * 16 + l15) * 104 + cc * 32 + quad * 8];
#pragma unroll
            for (int mt = 0; mt < 4; ++mt) {
                accS[mt] = MFMA16(Afh[mt][cc], bh, accS[mt]);
                // preserve k2/k3a's cross-product order: (u_hi*v_lo) first, then (u_lo*v_hi)
                accX[mt] = MFMA16(Afl[mt][cc], bh, accX[mt]);   // v_lo * u_hi
                accX[mt] = MFMA16(Afh[mt][cc], bl, accX[mt]);   // v_hi * u_lo
            }
        }
#pragma unroll
        for (int mt = 0; mt < 4; ++mt)
#pragma unroll
            for (int r = 0; r < 4; ++r) {
                float zl = fmaf(ZC1, accS[mt][r], ZC2 * accX[mt][r]);
                P[(16 * mt + 4 * quad + r) * 72 + w * 16 + l15] =
                    (f16)(exp2f(zl + negMk) * invLk);
            }
        __syncthreads();
#pragma unroll
        for (int kc = 0; kc < 2; ++kc) {
            f16x8 ap = *(const f16x8*)&P[(w * 16 + l15) * 72 + kc * 32 + quad * 8];
#pragma unroll
            for (int nt = 0; nt < 6; ++nt) {
                f16x8 bo = *(const f16x8*)&Ot[(nt * 16 + l15) * 72 + kc * 32 + quad * 8];
                accO[nt] = MFMA16(ap, bo, accO[nt]);
            }
        }
        __syncthreads();
    }
    const int b = head >> 3, c = head & 7;
#pragma unroll
    for (int r = 0; r < 4; ++r) {
        int q = q0 + w * 16 + quad * 4 + r;
        int cbi = (b * 2048 + q) * 96;
        f16* wrow = w2 + (size_t)(b * 2048 + q) * 768 + c * 96;
#pragma unroll
        for (int nt = 0; nt < 3; ++nt) {
            int rr = nt * 16 + l15;
            float cc = cosb[cbi + rr], ss = sinb[cbi + rr];
            float a = accO[nt][r];
            float b2 = accO[nt + 3][r];
            wrow[rr] = (f16)(a * cc - b2 * ss);
            wrow[rr + 48] = (f16)(b2 * cc + a * ss);
        }
    }
}

// ============================================================
// K4: G = w1@U + w2@V (fp16 MFMA). grid (32 s-blocks, 12 d-blocks),
// block 256 (4 waves), tile 128s x 64d, wave strip 32s.
// ============================================================
__global__ __launch_bounds__(256, 2) void k4_final(const f16* __restrict__ w1,
                                                   const f16* __restrict__ w2,
                                                   const float* __restrict__ U,
                                                   const float* __restrict__ V,
                                                   float* __restrict__ outp) {
    __shared__ f16 A1[128 * 56];
    __shared__ f16 A2[128 * 56];
    __shared__ f16 B1[64 * 56];
    __shared__ f16 B2[64 * 56];
    const int tid = threadIdx.x, w = tid >> 6, lane = tid & 63;
    const int quad = lane >> 4, l15 = lane & 15;
    const int bs0 = blockIdx.x * 128;
    const int d0 = blockIdx.y * 64;
    f32x4 acc[2][4] = {};

    for (int ec = 0; ec < 24; ++ec) {
        int e0 = ec * 32;
        __syncthreads();
#pragma unroll
        for (int m = 0; m < 2; ++m) {
            int f = tid + 256 * m;
            int row = f >> 2, q = f & 3;
            *(float4*)&A1[row * 56 + q * 8] =
                *(const float4*)(w1 + (size_t)(bs0 + row) * 768 + e0 + q * 8);
            *(float4*)&A2[row * 56 + q * 8] =
                *(const float4*)(w2 + (size_t)(bs0 + row) * 768 + e0 + q * 8);
        }
#pragma unroll
        for (int m2 = 0; m2 < 2; ++m2) {
            int e_r = (tid >> 4) + 16 * m2;
            int dc = tid & 15;
            float4 fu = *(const float4*)(U + (size_t)(e0 + e_r) * 768 + d0 + dc * 4);
            float4 fv = *(const float4*)(V + (size_t)(e0 + e_r) * 768 + d0 + dc * 4);
            B1[(dc * 4 + 0) * 56 + e_r] = (f16)fu.x;
            B1[(dc * 4 + 1) * 56 + e_r] = (f16)fu.y;
            B1[(dc * 4 + 2) * 56 + e_r] = (f16)fu.z;
            B1[(dc * 4 + 3) * 56 + e_r] = (f16)fu.w;
            B2[(dc * 4 + 0) * 56 + e_r] = (f16)fv.x;
            B2[(dc * 4 + 1) * 56 + e_r] = (f16)fv.y;
            B2[(dc * 4 + 2) * 56 + e_r] = (f16)fv.z;
            B2[(dc * 4 + 3) * 56 + e_r] = (f16)fv.w;
        }
        __syncthreads();
        f16x8 a1f[2], a2f[2];
#pragma unroll
        for (int mt = 0; mt < 2; ++mt) {
            a1f[mt] = *(const f16x8*)&A1[(32 * w + 16 * mt + l15) * 56 + quad * 8];
            a2f[mt] = *(const f16x8*)&A2[(32 * w + 16 * mt + l15) * 56 + quad * 8];
        }
#pragma unroll
        for (int nt = 0; nt < 4; ++nt) {
            f16x8 b1f = *(const f16x8*)&B1[(nt * 16 + l15) * 56 + quad * 8];
            f16x8 b2f = *(const f16x8*)&B2[(nt * 16 + l15) * 56 + quad * 8];
#pragma unroll
            for (int mt = 0; mt < 2; ++mt) {
                acc[mt][nt] = MFMA16(a1f[mt], b1f, acc[mt][nt]);
                acc[mt][nt] = MFMA16(a2f[mt], b2f, acc[mt][nt]);
            }
        }
    }
#pragma unroll
    for (int mt = 0; mt < 2; ++mt)
#pragma unroll
        for (int nt = 0; nt < 4; ++nt)
#pragma unroll
            for (int r = 0; r < 4; ++r) {
                int s = bs0 + 32 * w + 16 * mt + 4 * quad + r;
                int d = d0 + 16 * nt + l15;
                outp[(size_t)s * 768 + d] = acc[mt][nt][r];
            }
}

extern "C" void kernel_launch(void* const* d_in, const int* in_sizes, int n_in,
                              void* d_out, int out_size, void* d_ws, size_t ws_size,
                              hipStream_t stream) {
    const float* qz   = (const float*)d_in[0];
    const float* cosb = (const float*)d_in[1];
    const float* sinb = (const float*)d_in[2];
    const float* U    = (const float*)d_in[3];
    const float* V    = (const float*)d_in[4];
    float* outp = (float*)d_out;

    f16* ws16 = (f16*)d_ws;
    f16* uhp = ws16;
    f16* ulp = ws16 + HN;
    f16* vhp = ws16 + 2 * HN;
    f16* vlp = ws16 + 3 * HN;
    f16* vT  = ws16 + 4 * HN;
    f16* oT  = ws16 + 5 * HN;
    f16* w1  = ws16 + 6 * HN;
    f16* w2  = ws16 + 7 * HN;
    float* Mo = (float*)(ws16 + 8 * HN);
    float* Lo = Mo + 16 * 2048;

    // qz hi/lo splits live in the w1/w2 slots (dead until k3a/k3b write them).
    f16* qzh = w1;
    f16* qzl = w2;
    // U/V hi/lo splits live in d_out scratch (overwritten by k4 at the end).
    f16* outw = (f16*)d_out;
    f16* Uh = outw;
    f16* Ul = outw + UVN;
    f16* Vh = outw + 2 * UVN;
    f16* Vl = outw + 3 * UVN;

    k0_split<<<dim3(3072), 256, 0, stream>>>(qz, U, V, qzh, qzl, Uh, Ul, Vh, Vl);
    k1_proj<<<dim3(64, 8), 256, 0, stream>>>(qzh, qzl, Uh, Ul, Vh, Vl, cosb, sinb,
                                             uhp, ulp, vhp, vlp, vT, oT);
    k2_stats<<<dim3(32, 16), 256, 0, stream>>>(uhp, ulp, vhp, vlp, Mo);
    k3a<<<dim3(32, 16), 256, 0, stream>>>(uhp, ulp, vhp, vlp, vT, Mo, Lo, cosb, sinb, w1);
    k3b<<<dim3(32, 16), 256, 0, stream>>>(uhp, ulp, vhp, vlp, oT, Mo, Lo, cosb, sinb, w2);
    k4_final<<<dim3(32, 12), 256, 0, stream>>>(w1, w2, U, V, outp);
}

// Round 6
// 334.325 us; speedup vs baseline: 2.3390x; 1.0165x over previous
//
#include <hip/hip_runtime.h>

typedef _Float16 f16;
typedef _Float16 f16x8 __attribute__((ext_vector_type(8)));
typedef _Float16 f16x4 __attribute__((ext_vector_type(4)));
typedef float f32x4 __attribute__((ext_vector_type(4)));

#define MFMA16(A,B,C) __builtin_amdgcn_mfma_f32_16x16x32_f16(A,B,C,0,0,0)
#define INV2048 4.8828125e-4f
#define HN (16ll*2048*96)
#define UVN 589824   // 768*768
// z in log2 domain: zl = log2(e)*768*accS + log2(e)*768/2048*accX
#define ZC1 1107.98979f
#define ZC2 0.54101064f

__device__ __forceinline__ void split_f16(float x, f16& h, f16& l) {
    h = (f16)x;
    l = (f16)((x - (float)h) * 2048.0f);   // lo pre-scaled by 2^11 (avoids fp16 denorm loss)
}

// ============================================================
// K0: split qz, U, V (fp32) into fp16 hi/lo pairs.
// ============================================================
__global__ __launch_bounds__(256) void k0_split(const float* __restrict__ qz,
                                                const float* __restrict__ U,
                                                const float* __restrict__ V,
                                                f16* __restrict__ qzh, f16* __restrict__ qzl,
                                                f16* __restrict__ Uh, f16* __restrict__ Ul,
                                                f16* __restrict__ Vh, f16* __restrict__ Vl) {
    const int i4 = blockIdx.x * 256 + threadIdx.x;   // float4 index
    {
        float4 x = *(const float4*)(qz + (size_t)i4 * 4);
        f16 h0, l0, h1, l1, h2, l2, h3, l3;
        split_f16(x.x, h0, l0); split_f16(x.y, h1, l1);
        split_f16(x.z, h2, l2); split_f16(x.w, h3, l3);
        f16x4 hv = {h0, h1, h2, h3};
        f16x4 lv = {l0, l1, l2, l3};
        *(f16x4*)(qzh + (size_t)i4 * 4) = hv;
        *(f16x4*)(qzl + (size_t)i4 * 4) = lv;
    }
    if (i4 < UVN / 4) {
        float4 x = *(const float4*)(U + (size_t)i4 * 4);
        f16 h0, l0, h1, l1, h2, l2, h3, l3;
        split_f16(x.x, h0, l0); split_f16(x.y, h1, l1);
        split_f16(x.z, h2, l2); split_f16(x.w, h3, l3);
        f16x4 hv = {h0, h1, h2, h3};
        f16x4 lv = {l0, l1, l2, l3};
        *(f16x4*)(Uh + (size_t)i4 * 4) = hv;
        *(f16x4*)(Ul + (size_t)i4 * 4) = lv;
        float4 y = *(const float4*)(V + (size_t)i4 * 4);
        split_f16(y.x, h0, l0); split_f16(y.y, h1, l1);
        split_f16(y.z, h2, l2); split_f16(y.w, h3, l3);
        f16x4 hv2 = {h0, h1, h2, h3};
        f16x4 lv2 = {l0, l1, l2, l3};
        *(f16x4*)(Vh + (size_t)i4 * 4) = hv2;
        *(f16x4*)(Vl + (size_t)i4 * 4) = lv2;
    }
}

// ============================================================
// K1: dual GEMM qz@U^T, qz@V^T via fp16 MFMA 3-product emulation
// + RoPE; round-2 proven version. (unchanged)
// ============================================================
__global__ __launch_bounds__(256, 2) void k1_proj(const f16* __restrict__ qzh,
                                                  const f16* __restrict__ qzl,
                                                  const f16* __restrict__ Uh,
                                                  const f16* __restrict__ Ul,
                                                  const f16* __restrict__ Vh,
                                                  const f16* __restrict__ Vl,
                                                  const float* __restrict__ cosb,
                                                  const float* __restrict__ sinb,
                                                  f16* __restrict__ uhp, f16* __restrict__ ulp,
                                                  f16* __restrict__ vhp, f16* __restrict__ vlp,
                                                  f16* __restrict__ vT, f16* __restrict__ oT) {
    __shared__ __align__(16) f16 smem[36864];            // 73728 B -> 2 blocks/CU
    f16* sAh  = smem;                                    // [64][72]
    f16* sAl  = smem + 4608;
    f16* sBuh = smem + 9216;                             // [96][72]
    f16* sBul = smem + 9216 + 6912;
    f16* sBvh = smem + 9216 + 2 * 6912;
    f16* sBvl = smem + 9216 + 3 * 6912;

    const int tid = threadIdx.x;
    const int w = tid >> 6, lane = tid & 63;
    const int quad = lane >> 4, l15 = lane & 15;
    const int wr = w >> 1, wc = w & 1;                   // 2x2 wave grid
    const int bs0 = blockIdx.x * 64;
    const int c = blockIdx.y;

    const f16* Ug_h = Uh + (size_t)c * 96 * 768;
    const f16* Ug_l = Ul + (size_t)c * 96 * 768;
    const f16* Vg_h = Vh + (size_t)c * 96 * 768;
    const f16* Vg_l = Vl + (size_t)c * 96 * 768;

    f32x4 aUS[2][3] = {}, aUX[2][3] = {};
    f32x4 aVS[2][3] = {}, aVX[2][3] = {};

    for (int k0 = 0; k0 < 768; k0 += 64) {
        __syncthreads();
#pragma unroll
        for (int m = 0; m < 2; ++m) {
            int f = tid + 256 * m, row = f >> 3, cg = f & 7;
            const size_t go = (size_t)(bs0 + row) * 768 + k0 + cg * 8;
            const int lo = row * 72 + cg * 8;
            *(float4*)&sAh[lo] = *(const float4*)(qzh + go);
            *(float4*)&sAl[lo] = *(const float4*)(qzl + go);
        }
#pragma unroll
        for (int m = 0; m < 3; ++m) {
            int f = tid + 256 * m, row = f >> 3, cg = f & 7;
            const size_t go = (size_t)row * 768 + k0 + cg * 8;
            const int lo = row * 72 + cg * 8;
            *(float4*)&sBuh[lo] = *(const float4*)(Ug_h + go);
            *(float4*)&sBul[lo] = *(const float4*)(Ug_l + go);
            *(float4*)&sBvh[lo] = *(const float4*)(Vg_h + go);
            *(float4*)&sBvl[lo] = *(const float4*)(Vg_l + go);
        }
        __syncthreads();
#pragma unroll
        for (int cc = 0; cc < 2; ++cc) {
            f16x8 ah[2], al[2];
#pragma unroll
            for (int mt = 0; mt < 2; ++mt) {
                const int ar = (32 * wr + 16 * mt + l15) * 72 + cc * 32 + quad * 8;
                ah[mt] = *(const f16x8*)&sAh[ar];
                al[mt] = *(const f16x8*)&sAl[ar];
            }
#pragma unroll
            for (int nt = 0; nt < 3; ++nt) {
                const int br = (48 * wc + 16 * nt + l15) * 72 + cc * 32 + quad * 8;
                f16x8 buh = *(const f16x8*)&sBuh[br];
                f16x8 bul = *(const f16x8*)&sBul[br];
                f16x8 bvh = *(const f16x8*)&sBvh[br];
                f16x8 bvl = *(const f16x8*)&sBvl[br];
#pragma unroll
                for (int mt = 0; mt < 2; ++mt) {
                    aUS[mt][nt] = MFMA16(ah[mt], buh, aUS[mt][nt]);
                    aUX[mt][nt] = MFMA16(ah[mt], bul, aUX[mt][nt]);
                    aUX[mt][nt] = MFMA16(al[mt], buh, aUX[mt][nt]);
                    aVS[mt][nt] = MFMA16(ah[mt], bvh, aVS[mt][nt]);
                    aVX[mt][nt] = MFMA16(ah[mt], bvl, aVX[mt][nt]);
                    aVX[mt][nt] = MFMA16(al[mt], bvh, aVX[mt][nt]);
                }
            }
        }
    }

    __syncthreads();
    float* LU = (float*)smem;          // [64][100] = 25.6 KB
    float* LV = LU + 6400;
#pragma unroll
    for (int mt = 0; mt < 2; ++mt)
#pragma unroll
        for (int nt = 0; nt < 3; ++nt)
#pragma unroll
            for (int r = 0; r < 4; ++r) {
                const int sl = 32 * wr + 16 * mt + 4 * quad + r;
                const int col = 48 * wc + 16 * nt + l15;
                LU[sl * 100 + col] = aUS[mt][nt][r] + aUX[mt][nt][r] * INV2048;
                LV[sl * 100 + col] = aVS[mt][nt][r] + aVX[mt][nt][r] * INV2048;
            }
    __syncthreads();

    const int b = bs0 >> 11;
    const int s0 = bs0 & 2047;
    const int head = b * 8 + c;
    const size_t nb = (size_t)head * 2048 * 96;
    const size_t tb = (size_t)head * 96 * 2048;
    const int ty = tid >> 4, tx = tid & 15;

#pragma unroll
    for (int jj = 0; jj < 3; ++jj) {
        int r = tx + 16 * jj;
        f16 vt1[4], vt2[4], ot1[4], ot2[4];
#pragma unroll
        for (int ii = 0; ii < 4; ++ii) {
            int sl = 4 * ty + ii;
            int s = s0 + sl;
            int cbi = (b * 2048 + s) * 96 + r;
            float cc = cosb[cbi], ss = sinb[cbi];
            size_t rowb = nb + (size_t)s * 96;
            float u1 = LU[sl * 100 + r], u2 = LU[sl * 100 + r + 48];
            float v1 = LV[sl * 100 + r], v2 = LV[sl * 100 + r + 48];
            float ur1 = u1 * cc - u2 * ss, ur2 = u2 * cc + u1 * ss;
            float uo1 = u1 * cc + u2 * ss, uo2 = u2 * cc - u1 * ss;
            float vr1 = v1 * cc - v2 * ss, vr2 = v2 * cc + v1 * ss;
            f16 h, l;
            split_f16(ur1, h, l); uhp[rowb + r] = h;      ulp[rowb + r] = l;
            split_f16(ur2, h, l); uhp[rowb + r + 48] = h; ulp[rowb + r + 48] = l;
            split_f16(vr1, h, l); vhp[rowb + r] = h;      vlp[rowb + r] = l;      vt1[ii] = h;
            split_f16(vr2, h, l); vhp[rowb + r + 48] = h; vlp[rowb + r + 48] = l; vt2[ii] = h;
            ot1[ii] = (f16)uo1; ot2[ii] = (f16)uo2;
        }
        f16x4 pv1 = {vt1[0], vt1[1], vt1[2], vt1[3]};
        f16x4 pv2 = {vt2[0], vt2[1], vt2[2], vt2[3]};
        f16x4 po1 = {ot1[0], ot1[1], ot1[2], ot1[3]};
        f16x4 po2 = {ot2[0], ot2[1], ot2[2], ot2[3]};
        *(f16x4*)&vT[tb + (size_t)r * 2048 + s0 + 4 * ty] = pv1;
        *(f16x4*)&vT[tb + (size_t)(r + 48) * 2048 + s0 + 4 * ty] = pv2;
        *(f16x4*)&oT[tb + (size_t)r * 2048 + s0 + 4 * ty] = po1;
        *(f16x4*)&oT[tb + (size_t)(r + 48) * 2048 + s0 + 4 * ty] = po2;
    }
}

// ============================================================
// K2: MFMA row MAX only. Double-buffered Bh/Bl, 1 barrier/tile;
// next tile's loads issued into NAMED regs at loop top (latency
// hides under 36 MFMAs), ds_write to buf^1 after compute.
// ============================================================
__global__ __launch_bounds__(256, 2) void k2_stats(const f16* __restrict__ uhp,
                                                   const f16* __restrict__ ulp,
                                                   const f16* __restrict__ vhp,
                                                   const f16* __restrict__ vlp,
                                                   float* __restrict__ Mo) {
    __shared__ f16 Bh[2][64 * 104];
    __shared__ f16 Bl[2][64 * 104];
    __shared__ float Mbuf[4][64];
    const int tid = threadIdx.x, w = tid >> 6, lane = tid & 63;
    const int quad = lane >> 4, l15 = lane & 15;
    const int q0 = blockIdx.x * 64, head = blockIdx.y;
    const f16* Ah_g = uhp + (size_t)head * 2048 * 96;
    const f16* Al_g = ulp + (size_t)head * 2048 * 96;
    const f16* Bh_g = vhp + (size_t)head * 2048 * 96;
    const f16* Bl_g = vlp + (size_t)head * 2048 * 96;

    f16x8 Afh[4][3], Afl[4][3];
#pragma unroll
    for (int mt = 0; mt < 4; ++mt)
#pragma unroll
        for (int cc = 0; cc < 3; ++cc) {
            size_t off = (size_t)(q0 + 16 * mt + l15) * 96 + cc * 32 + quad * 8;
            Afh[mt][cc] = *(const f16x8*)(Ah_g + off);
            Afl[mt][cc] = *(const f16x8*)(Al_g + off);
        }

    const int sr0 = tid / 12,         sc0 = (tid % 12) * 8;
    const int sr1 = (tid + 256) / 12, sc1 = ((tid + 256) % 12) * 8;
    const int sr2 = (tid + 512) / 12, sc2 = ((tid + 512) % 12) * 8;

    float4 h0, h1, h2, g0, g1, g2;   // named staging regs (Bh, Bl)

    float m_run[4][4];
#pragma unroll
    for (int mt = 0; mt < 4; ++mt)
#pragma unroll
        for (int r = 0; r < 4; ++r) m_run[mt][r] = -3.0e38f;

    // prologue: tile 0 -> buf 0
    h0 = *(const float4*)(Bh_g + (size_t)sr0 * 96 + sc0);
    h1 = *(const float4*)(Bh_g + (size_t)sr1 * 96 + sc1);
    h2 = *(const float4*)(Bh_g + (size_t)sr2 * 96 + sc2);
    g0 = *(const float4*)(Bl_g + (size_t)sr0 * 96 + sc0);
    g1 = *(const float4*)(Bl_g + (size_t)sr1 * 96 + sc1);
    g2 = *(const float4*)(Bl_g + (size_t)sr2 * 96 + sc2);
    *(float4*)&Bh[0][sr0 * 104 + sc0] = h0;
    *(float4*)&Bh[0][sr1 * 104 + sc1] = h1;
    *(float4*)&Bh[0][sr2 * 104 + sc2] = h2;
    *(float4*)&Bl[0][sr0 * 104 + sc0] = g0;
    *(float4*)&Bl[0][sr1 * 104 + sc1] = g1;
    *(float4*)&Bl[0][sr2 * 104 + sc2] = g2;
    __syncthreads();

    for (int t = 0; t < 32; ++t) {
        const int cur = t & 1;
        if (t < 31) {                 // issue next-tile loads; hide under MFMAs
            const f16* bg = Bh_g + (size_t)(t + 1) * 6144;
            const f16* lg = Bl_g + (size_t)(t + 1) * 6144;
            h0 = *(const float4*)(bg + (size_t)sr0 * 96 + sc0);
            h1 = *(const float4*)(bg + (size_t)sr1 * 96 + sc1);
            h2 = *(const float4*)(bg + (size_t)sr2 * 96 + sc2);
            g0 = *(const float4*)(lg + (size_t)sr0 * 96 + sc0);
            g1 = *(const float4*)(lg + (size_t)sr1 * 96 + sc1);
            g2 = *(const float4*)(lg + (size_t)sr2 * 96 + sc2);
        }
        f32x4 accS[4] = {}, accX[4] = {};
#pragma unroll
        for (int cc = 0; cc < 3; ++cc) {
            f16x8 bh = *(const f16x8*)&Bh[cur][(w * 16 + l15) * 104 + cc * 32 + quad * 8];
            f16x8 bl = *(const f16x8*)&Bl[cur][(w * 16 + l15) * 104 + cc * 32 + quad * 8];
#pragma unroll
            for (int mt = 0; mt < 4; ++mt) {
                accS[mt] = MFMA16(Afh[mt][cc], bh, accS[mt]);
                accX[mt] = MFMA16(Afh[mt][cc], bl, accX[mt]);
                accX[mt] = MFMA16(Afl[mt][cc], bh, accX[mt]);
            }
        }
#pragma unroll
        for (int mt = 0; mt < 4; ++mt)
#pragma unroll
            for (int r = 0; r < 4; ++r) {
                float zl = fmaf(ZC1, accS[mt][r], ZC2 * accX[mt][r]);
                m_run[mt][r] = fmaxf(m_run[mt][r], zl);
            }
        if (t < 31) {                 // write buf^1 (its readers finished at bar(t-1))
            *(float4*)&Bh[cur ^ 1][sr0 * 104 + sc0] = h0;
            *(float4*)&Bh[cur ^ 1][sr1 * 104 + sc1] = h1;
            *(float4*)&Bh[cur ^ 1][sr2 * 104 + sc2] = h2;
            *(float4*)&Bl[cur ^ 1][sr0 * 104 + sc0] = g0;
            *(float4*)&Bl[cur ^ 1][sr1 * 104 + sc1] = g1;
            *(float4*)&Bl[cur ^ 1][sr2 * 104 + sc2] = g2;
        }
        __syncthreads();              // single barrier per tile
    }
#pragma unroll
    for (int mt = 0; mt < 4; ++mt)
#pragma unroll
        for (int r = 0; r < 4; ++r) {
            float m = m_run[mt][r];
            m = fmaxf(m, __shfl_xor(m, 1)); m = fmaxf(m, __shfl_xor(m, 2));
            m = fmaxf(m, __shfl_xor(m, 4)); m = fmaxf(m, __shfl_xor(m, 8));
            m_run[mt][r] = m;
        }
    if (l15 == 0) {
#pragma unroll
        for (int mt = 0; mt < 4; ++mt)
#pragma unroll
            for (int r = 0; r < 4; ++r)
                Mbuf[w][16 * mt + 4 * quad + r] = m_run[mt][r];
    }
    __syncthreads();
    if (tid < 64) {
        float M = -3.0e38f;
#pragma unroll
        for (int ww = 0; ww < 4; ++ww) M = fmaxf(M, Mbuf[ww][tid]);
        Mo[head * 2048 + q0 + tid] = M;      // log2-domain exact row max
    }
}

// ============================================================
// K3a: S=ur.vr^T, P=exp2(zl-M[q]), out=P@vr + ones-column row sums
// (L), /L, rope_o -> w1; writes Lo. 2 barriers/tile: loads for t+1
// issued at S-phase top (named regs); ds_writes after bar_A overlap
// PV. Bh/Bl single-buffered, Vt double-buffered, P single.
// ============================================================
__global__ __launch_bounds__(256, 2) void k3a(const f16* __restrict__ uhp,
                                              const f16* __restrict__ ulp,
                                              const f16* __restrict__ vhp,
                                              const f16* __restrict__ vlp,
                                              const f16* __restrict__ vT,
                                              const float* __restrict__ Mo,
                                              float* __restrict__ Lo,
                                              const float* __restrict__ cosb,
                                              const float* __restrict__ sinb,
                                              f16* __restrict__ w1) {
    __shared__ f16 Bh[64 * 104];
    __shared__ f16 Bl[64 * 104];
    __shared__ f16 Vt[2][112 * 72];    // rows 96..111 = ones in both buffers
    __shared__ f16 P[64 * 72];
    const int tid = threadIdx.x, w = tid >> 6, lane = tid & 63;
    const int quad = lane >> 4, l15 = lane & 15;
    const int q0 = blockIdx.x * 64, head = blockIdx.y;
    const f16* Ah_g = uhp + (size_t)head * 2048 * 96;
    const f16* Al_g = ulp + (size_t)head * 2048 * 96;
    const f16* Bh_g = vhp + (size_t)head * 2048 * 96;
    const f16* Bl_g = vlp + (size_t)head * 2048 * 96;
    const f16* Vt_g = vT + (size_t)head * 96 * 2048;

    f16x8 Afh[4][3], Afl[4][3];
#pragma unroll
    for (int mt = 0; mt < 4; ++mt)
#pragma unroll
        for (int cc = 0; cc < 3; ++cc) {
            size_t off = (size_t)(q0 + 16 * mt + l15) * 96 + cc * 32 + quad * 8;
            Afh[mt][cc] = *(const f16x8*)(Ah_g + off);
            Afl[mt][cc] = *(const f16x8*)(Al_g + off);
        }
    float negM[4][4];
#pragma unroll
    for (int mt = 0; mt < 4; ++mt)
#pragma unroll
        for (int r = 0; r < 4; ++r)
            negM[mt][r] = -Mo[head * 2048 + q0 + 16 * mt + 4 * quad + r];

    const int sr0 = tid / 12,         sc0 = (tid % 12) * 8;
    const int sr1 = (tid + 256) / 12, sc1 = ((tid + 256) % 12) * 8;
    const int sr2 = (tid + 512) / 12, sc2 = ((tid + 512) % 12) * 8;
    const int vr0 = tid >> 3, vcc = (tid & 7) * 8;   // Vt rows vr0, vr0+32, vr0+64

    float4 h0, h1, h2, g0, g1, g2, v0, v1, v2;       // named staging regs

    // ones rows for the row-sum MFMA (both buffers, written once)
    if (tid < 144) {
        f16x8 ones = {(f16)1, (f16)1, (f16)1, (f16)1,
                      (f16)1, (f16)1, (f16)1, (f16)1};
        *(f16x8*)&Vt[0][96 * 72 + tid * 8] = ones;
        *(f16x8*)&Vt[1][96 * 72 + tid * 8] = ones;
    }

    // prologue: tile 0
    h0 = *(const float4*)(Bh_g + (size_t)sr0 * 96 + sc0);
    h1 = *(const float4*)(Bh_g + (size_t)sr1 * 96 + sc1);
    h2 = *(const float4*)(Bh_g + (size_t)sr2 * 96 + sc2);
    g0 = *(const float4*)(Bl_g + (size_t)sr0 * 96 + sc0);
    g1 = *(const float4*)(Bl_g + (size_t)sr1 * 96 + sc1);
    g2 = *(const float4*)(Bl_g + (size_t)sr2 * 96 + sc2);
    v0 = *(const float4*)(Vt_g + (size_t)vr0 * 2048 + vcc);
    v1 = *(const float4*)(Vt_g + (size_t)(vr0 + 32) * 2048 + vcc);
    v2 = *(const float4*)(Vt_g + (size_t)(vr0 + 64) * 2048 + vcc);
    *(float4*)&Bh[sr0 * 104 + sc0] = h0;
    *(float4*)&Bh[sr1 * 104 + sc1] = h1;
    *(float4*)&Bh[sr2 * 104 + sc2] = h2;
    *(float4*)&Bl[sr0 * 104 + sc0] = g0;
    *(float4*)&Bl[sr1 * 104 + sc1] = g1;
    *(float4*)&Bl[sr2 * 104 + sc2] = g2;
    *(float4*)&Vt[0][vr0 * 72 + vcc] = v0;
    *(float4*)&Vt[0][(vr0 + 32) * 72 + vcc] = v1;
    *(float4*)&Vt[0][(vr0 + 64) * 72 + vcc] = v2;
    __syncthreads();

    f32x4 accO[7] = {};
    int pcur = 0;

    for (int t = 0; t < 32; ++t) {
        if (t < 31) {                 // issue t+1 loads; hide under S-MFMA + exp
            const f16* bg = Bh_g + (size_t)(t + 1) * 6144;
            const f16* lg = Bl_g + (size_t)(t + 1) * 6144;
            const int kn = (t + 1) * 64;
            h0 = *(const float4*)(bg + (size_t)sr0 * 96 + sc0);
            h1 = *(const float4*)(bg + (size_t)sr1 * 96 + sc1);
            h2 = *(const float4*)(bg + (size_t)sr2 * 96 + sc2);
            g0 = *(const float4*)(lg + (size_t)sr0 * 96 + sc0);
            g1 = *(const float4*)(lg + (size_t)sr1 * 96 + sc1);
            g2 = *(const float4*)(lg + (size_t)sr2 * 96 + sc2);
            v0 = *(const float4*)(Vt_g + (size_t)vr0 * 2048 + kn + vcc);
            v1 = *(const float4*)(Vt_g + (size_t)(vr0 + 32) * 2048 + kn + vcc);
            v2 = *(const float4*)(Vt_g + (size_t)(vr0 + 64) * 2048 + kn + vcc);
        }
        f32x4 accS[4] = {}, accX[4] = {};
#pragma unroll
        for (int cc = 0; cc < 3; ++cc) {
            f16x8 bh = *(const f16x8*)&Bh[(w * 16 + l15) * 104 + cc * 32 + quad * 8];
            f16x8 bl = *(const f16x8*)&Bl[(w * 16 + l15) * 104 + cc * 32 + quad * 8];
#pragma unroll
            for (int mt = 0; mt < 4; ++mt) {
                accS[mt] = MFMA16(Afh[mt][cc], bh, accS[mt]);
                accX[mt] = MFMA16(Afh[mt][cc], bl, accX[mt]);
                accX[mt] = MFMA16(Afl[mt][cc], bh, accX[mt]);
            }
        }
#pragma unroll
        for (int mt = 0; mt < 4; ++mt)
#pragma unroll
            for (int r = 0; r < 4; ++r) {
                float zl = fmaf(ZC1, accS[mt][r], ZC2 * accX[mt][r]);
                P[(16 * mt + 4 * quad + r) * 72 + w * 16 + l15] =
                    (f16)exp2f(zl + negM[mt][r]);
            }
        __syncthreads();              // bar_A: P visible; S reads of Bh complete
        if (t < 31) {                 // stage t+1 (overlaps PV below)
            *(float4*)&Bh[sr0 * 104 + sc0] = h0;
            *(float4*)&Bh[sr1 * 104 + sc1] = h1;
            *(float4*)&Bh[sr2 * 104 + sc2] = h2;
            *(float4*)&Bl[sr0 * 104 + sc0] = g0;
            *(float4*)&Bl[sr1 * 104 + sc1] = g1;
            *(float4*)&Bl[sr2 * 104 + sc2] = g2;
            *(float4*)&Vt[pcur ^ 1][vr0 * 72 + vcc] = v0;
            *(float4*)&Vt[pcur ^ 1][(vr0 + 32) * 72 + vcc] = v1;
            *(float4*)&Vt[pcur ^ 1][(vr0 + 64) * 72 + vcc] = v2;
        }
#pragma unroll
        for (int kc = 0; kc < 2; ++kc) {
            f16x8 ap = *(const f16x8*)&P[(w * 16 + l15) * 72 + kc * 32 + quad * 8];
#pragma unroll
            for (int nt = 0; nt < 7; ++nt) {   // nt=6: ones rows -> row sums (L)
                f16x8 bv = *(const f16x8*)&Vt[pcur][(nt * 16 + l15) * 72 + kc * 32 + quad * 8];
                accO[nt] = MFMA16(ap, bv, accO[nt]);
            }
        }
        __syncthreads();              // bar_B: staging visible; P/Vt reads done
        pcur ^= 1;
    }
    float invL[4];
#pragma unroll
    for (int r = 0; r < 4; ++r) invL[r] = 1.0f / accO[6][r];
    if (l15 == 0) {
#pragma unroll
        for (int r = 0; r < 4; ++r)
            Lo[head * 2048 + q0 + w * 16 + quad * 4 + r] = accO[6][r];
    }

    const int b = head >> 3, c = head & 7;
#pragma unroll
    for (int r = 0; r < 4; ++r) {
        int q = q0 + w * 16 + quad * 4 + r;
        int cbi = (b * 2048 + q) * 96;
        f16* wrow = w1 + (size_t)(b * 2048 + q) * 768 + c * 96;
#pragma unroll
        for (int nt = 0; nt < 3; ++nt) {
            int rr = nt * 16 + l15;
            float cc = cosb[cbi + rr], ss = sinb[cbi + rr];
            float a = accO[nt][r] * invL[r];
            float b2 = accO[nt + 3][r] * invL[r];
            wrow[rr] = (f16)(a * cc + b2 * ss);
            wrow[rr + 48] = (f16)(b2 * cc - a * ss);
        }
    }
}

// ============================================================
// K3b: S2[q][k]=vr_q.ur_k, P2=exp2(zl-M[k])/L[k], out=P2@uo,
// rope -> w2. Same 2-barrier pipeline as k3a (Ot double-buffered).
// ============================================================
__global__ __launch_bounds__(256, 2) void k3b(const f16* __restrict__ uhp,
                                              const f16* __restrict__ ulp,
                                              const f16* __restrict__ vhp,
                                              const f16* __restrict__ vlp,
                                              const f16* __restrict__ oT,
                                              const float* __restrict__ Mo,
                                              const float* __restrict__ Lo,
                                              const float* __restrict__ cosb,
                                              const float* __restrict__ sinb,
                                              f16* __restrict__ w2) {
    __shared__ f16 Bh[64 * 104];
    __shared__ f16 Bl[64 * 104];
    __shared__ f16 Ot[2][96 * 72];
    __shared__ f16 P[64 * 72];
    const int tid = threadIdx.x, w = tid >> 6, lane = tid & 63;
    const int quad = lane >> 4, l15 = lane & 15;
    const int q0 = blockIdx.x * 64, head = blockIdx.y;
    const f16* Ah_g = vhp + (size_t)head * 2048 * 96;   // A = vr
    const f16* Al_g = vlp + (size_t)head * 2048 * 96;
    const f16* Bh_g = uhp + (size_t)head * 2048 * 96;   // B = ur
    const f16* Bl_g = ulp + (size_t)head * 2048 * 96;
    const f16* Ot_g = oT + (size_t)head * 96 * 2048;

    f16x8 Afh[4][3], Afl[4][3];
#pragma unroll
    for (int mt = 0; mt < 4; ++mt)
#pragma unroll
        for (int cc = 0; cc < 3; ++cc) {
            size_t off = (size_t)(q0 + 16 * mt + l15) * 96 + cc * 32 + quad * 8;
            Afh[mt][cc] = *(const f16x8*)(Ah_g + off);
            Afl[mt][cc] = *(const f16x8*)(Al_g + off);
        }

    const int sr0 = tid / 12,         sc0 = (tid % 12) * 8;
    const int sr1 = (tid + 256) / 12, sc1 = ((tid + 256) % 12) * 8;
    const int sr2 = (tid + 512) / 12, sc2 = ((tid + 512) % 12) * 8;
    const int vr0 = tid >> 3, vcc = (tid & 7) * 8;

    float4 h0, h1, h2, g0, g1, g2, v0, v1, v2;

    // prologue: tile 0
    h0 = *(const float4*)(Bh_g + (size_t)sr0 * 96 + sc0);
    h1 = *(const float4*)(Bh_g + (size_t)sr1 * 96 + sc1);
    h2 = *(const float4*)(Bh_g + (size_t)sr2 * 96 + sc2);
    g0 = *(const float4*)(Bl_g + (size_t)sr0 * 96 + sc0);
    g1 = *(const float4*)(Bl_g + (size_t)sr1 * 96 + sc1);
    g2 = *(const float4*)(Bl_g + (size_t)sr2 * 96 + sc2);
    v0 = *(const float4*)(Ot_g + (size_t)vr0 * 2048 + vcc);
    v1 = *(const float4*)(Ot_g + (size_t)(vr0 + 32) * 2048 + vcc);
    v2 = *(const float4*)(Ot_g + (size_t)(vr0 + 64) * 2048 + vcc);
    *(float4*)&Bh[sr0 * 104 + sc0] = h0;
    *(float4*)&Bh[sr1 * 104 + sc1] = h1;
    *(float4*)&Bh[sr2 * 104 + sc2] = h2;
    *(float4*)&Bl[sr0 * 104 + sc0] = g0;
    *(float4*)&Bl[sr1 * 104 + sc1] = g1;
    *(float4*)&Bl[sr2 * 104 + sc2] = g2;
    *(float4*)&Ot[0][vr0 * 72 + vcc] = v0;
    *(float4*)&Ot[0][(vr0 + 32) * 72 + vcc] = v1;
    *(float4*)&Ot[0][(vr0 + 64) * 72 + vcc] = v2;
    __syncthreads();

    f32x4 accO[6] = {};
    int pcur = 0;

    for (int t = 0; t < 32; ++t) {
        const int k0 = t * 64;
        float negMk = -Mo[head * 2048 + k0 + w * 16 + l15];
        float invLk = 1.0f / Lo[head * 2048 + k0 + w * 16 + l15];
        if (t < 31) {
            const f16* bg = Bh_g + (size_t)(t + 1) * 6144;
            const f16* lg = Bl_g + (size_t)(t + 1) * 6144;
            const int kn = (t + 1) * 64;
            h0 = *(const float4*)(bg + (size_t)sr0 * 96 + sc0);
            h1 = *(const float4*)(bg + (size_t)sr1 * 96 + sc1);
            h2 = *(const float4*)(bg + (size_t)sr2 * 96 + sc2);
            g0 = *(const float4*)(lg + (size_t)sr0 * 96 + sc0);
            g1 = *(const float4*)(lg + (size_t)sr1 * 96 + sc1);
            g2 = *(const float4*)(lg + (size_t)sr2 * 96 + sc2);
            v0 = *(const float4*)(Ot_g + (size_t)vr0 * 2048 + kn + vcc);
            v1 = *(const float4*)(Ot_g + (size_t)(vr0 + 32) * 2048 + kn + vcc);
            v2 = *(const float4*)(Ot_g + (size_t)(vr0 + 64) * 2048 + kn + vcc);
        }
        f32x4 accS[4] = {}, accX[4] = {};
#pragma unroll
        for (int cc = 0; cc < 3; ++cc) {
            f16x8 bh = *(const f16x8*)&Bh[(w * 16 + l15) * 104 + cc * 32 + quad * 8];
            f16x8 bl = *(const f16x8*)&Bl[(w * 16 + l15) * 104 + cc * 32 + quad * 8];
#pragma unroll
            for (int mt = 0; mt < 4; ++mt) {
                accS[mt] = MFMA16(Afh[mt][cc], bh, accS[mt]);
                // preserve k2/k3a's cross-product order: (u_hi*v_lo) first, then (u_lo*v_hi)
                accX[mt] = MFMA16(Afl[mt][cc], bh, accX[mt]);   // v_lo * u_hi
                accX[mt] = MFMA16(Afh[mt][cc], bl, accX[mt]);   // v_hi * u_lo
            }
        }
#pragma unroll
        for (int mt = 0; mt < 4; ++mt)
#pragma unroll
            for (int r = 0; r < 4; ++r) {
                float zl = fmaf(ZC1, accS[mt][r], ZC2 * accX[mt][r]);
                P[(16 * mt + 4 * quad + r) * 72 + w * 16 + l15] =
                    (f16)(exp2f(zl + negMk) * invLk);
            }
        __syncthreads();              // bar_A
        if (t < 31) {
            *(float4*)&Bh[sr0 * 104 + sc0] = h0;
            *(float4*)&Bh[sr1 * 104 + sc1] = h1;
            *(float4*)&Bh[sr2 * 104 + sc2] = h2;
            *(float4*)&Bl[sr0 * 104 + sc0] = g0;
            *(float4*)&Bl[sr1 * 104 + sc1] = g1;
            *(float4*)&Bl[sr2 * 104 + sc2] = g2;
            *(float4*)&Ot[pcur ^ 1][vr0 * 72 + vcc] = v0;
            *(float4*)&Ot[pcur ^ 1][(vr0 + 32) * 72 + vcc] = v1;
            *(float4*)&Ot[pcur ^ 1][(vr0 + 64) * 72 + vcc] = v2;
        }
#pragma unroll
        for (int kc = 0; kc < 2; ++kc) {
            f16x8 ap = *(const f16x8*)&P[(w * 16 + l15) * 72 + kc * 32 + quad * 8];
#pragma unroll
            for (int nt = 0; nt < 6; ++nt) {
                f16x8 bo = *(const f16x8*)&Ot[pcur][(nt * 16 + l15) * 72 + kc * 32 + quad * 8];
                accO[nt] = MFMA16(ap, bo, accO[nt]);
            }
        }
        __syncthreads();              // bar_B
        pcur ^= 1;
    }
    const int b = head >> 3, c = head & 7;
#pragma unroll
    for (int r = 0; r < 4; ++r) {
        int q = q0 + w * 16 + quad * 4 + r;
        int cbi = (b * 2048 + q) * 96;
        f16* wrow = w2 + (size_t)(b * 2048 + q) * 768 + c * 96;
#pragma unroll
        for (int nt = 0; nt < 3; ++nt) {
            int rr = nt * 16 + l15;
            float cc = cosb[cbi + rr], ss = sinb[cbi + rr];
            float a = accO[nt][r];
            float b2 = accO[nt + 3][r];
            wrow[rr] = (f16)(a * cc - b2 * ss);
            wrow[rr + 48] = (f16)(b2 * cc + a * ss);
        }
    }
}

// ============================================================
// K4: G = w1@U + w2@V (fp16 MFMA). (unchanged)
// ============================================================
__global__ __launch_bounds__(256, 2) void k4_final(const f16* __restrict__ w1,
                                                   const f16* __restrict__ w2,
                                                   const float* __restrict__ U,
                                                   const float* __restrict__ V,
                                                   float* __restrict__ outp) {
    __shared__ f16 A1[128 * 56];
    __shared__ f16 A2[128 * 56];
    __shared__ f16 B1[64 * 56];
    __shared__ f16 B2[64 * 56];
    const int tid = threadIdx.x, w = tid >> 6, lane = tid & 63;
    const int quad = lane >> 4, l15 = lane & 15;
    const int bs0 = blockIdx.x * 128;
    const int d0 = blockIdx.y * 64;
    f32x4 acc[2][4] = {};

    for (int ec = 0; ec < 24; ++ec) {
        int e0 = ec * 32;
        __syncthreads();
#pragma unroll
        for (int m = 0; m < 2; ++m) {
            int f = tid + 256 * m;
            int row = f >> 2, q = f & 3;
            *(float4*)&A1[row * 56 + q * 8] =
                *(const float4*)(w1 + (size_t)(bs0 + row) * 768 + e0 + q * 8);
            *(float4*)&A2[row * 56 + q * 8] =
                *(const float4*)(w2 + (size_t)(bs0 + row) * 768 + e0 + q * 8);
        }
#pragma unroll
        for (int m2 = 0; m2 < 2; ++m2) {
            int e_r = (tid >> 4) + 16 * m2;
            int dc = tid & 15;
            float4 fu = *(const float4*)(U + (size_t)(e0 + e_r) * 768 + d0 + dc * 4);
            float4 fv = *(const float4*)(V + (size_t)(e0 + e_r) * 768 + d0 + dc * 4);
            B1[(dc * 4 + 0) * 56 + e_r] = (f16)fu.x;
            B1[(dc * 4 + 1) * 56 + e_r] = (f16)fu.y;
            B1[(dc * 4 + 2) * 56 + e_r] = (f16)fu.z;
            B1[(dc * 4 + 3) * 56 + e_r] = (f16)fu.w;
            B2[(dc * 4 + 0) * 56 + e_r] = (f16)fv.x;
            B2[(dc * 4 + 1) * 56 + e_r] = (f16)fv.y;
            B2[(dc * 4 + 2) * 56 + e_r] = (f16)fv.z;
            B2[(dc * 4 + 3) * 56 + e_r] = (f16)fv.w;
        }
        __syncthreads();
        f16x8 a1f[2], a2f[2];
#pragma unroll
        for (int mt = 0; mt < 2; ++mt) {
            a1f[mt] = *(const f16x8*)&A1[(32 * w + 16 * mt + l15) * 56 + quad * 8];
            a2f[mt] = *(const f16x8*)&A2[(32 * w + 16 * mt + l15) * 56 + quad * 8];
        }
#pragma unroll
        for (int nt = 0; nt < 4; ++nt) {
            f16x8 b1f = *(const f16x8*)&B1[(nt * 16 + l15) * 56 + quad * 8];
            f16x8 b2f = *(const f16x8*)&B2[(nt * 16 + l15) * 56 + quad * 8];
#pragma unroll
            for (int mt = 0; mt < 2; ++mt) {
                acc[mt][nt] = MFMA16(a1f[mt], b1f, acc[mt][nt]);
                acc[mt][nt] = MFMA16(a2f[mt], b2f, acc[mt][nt]);
            }
        }
    }
#pragma unroll
    for (int mt = 0; mt < 2; ++mt)
#pragma unroll
        for (int nt = 0; nt < 4; ++nt)
#pragma unroll
            for (int r = 0; r < 4; ++r) {
                int s = bs0 + 32 * w + 16 * mt + 4 * quad + r;
                int d = d0 + 16 * nt + l15;
                outp[(size_t)s * 768 + d] = acc[mt][nt][r];
            }
}

extern "C" void kernel_launch(void* const* d_in, const int* in_sizes, int n_in,
                              void* d_out, int out_size, void* d_ws, size_t ws_size,
                              hipStream_t stream) {
    const float* qz   = (const float*)d_in[0];
    const float* cosb = (const float*)d_in[1];
    const float* sinb = (const float*)d_in[2];
    const float* U    = (const float*)d_in[3];
    const float* V    = (const float*)d_in[4];
    float* outp = (float*)d_out;

    f16* ws16 = (f16*)d_ws;
    f16* uhp = ws16;
    f16* ulp = ws16 + HN;
    f16* vhp = ws16 + 2 * HN;
    f16* vlp = ws16 + 3 * HN;
    f16* vT  = ws16 + 4 * HN;
    f16* oT  = ws16 + 5 * HN;
    f16* w1  = ws16 + 6 * HN;
    f16* w2  = ws16 + 7 * HN;
    float* Mo = (float*)(ws16 + 8 * HN);
    float* Lo = Mo + 16 * 2048;

    // qz hi/lo splits live in the w1/w2 slots (dead until k3a/k3b write them).
    f16* qzh = w1;
    f16* qzl = w2;
    // U/V hi/lo splits live in d_out scratch (overwritten by k4 at the end).
    f16* outw = (f16*)d_out;
    f16* Uh = outw;
    f16* Ul = outw + UVN;
    f16* Vh = outw + 2 * UVN;
    f16* Vl = outw + 3 * UVN;

    k0_split<<<dim3(3072), 256, 0, stream>>>(qz, U, V, qzh, qzl, Uh, Ul, Vh, Vl);
    k1_proj<<<dim3(64, 8), 256, 0, stream>>>(qzh, qzl, Uh, Ul, Vh, Vl, cosb, sinb,
                                             uhp, ulp, vhp, vlp, vT, oT);
    k2_stats<<<dim3(32, 16), 256, 0, stream>>>(uhp, ulp, vhp, vlp, Mo);
    k3a<<<dim3(32, 16), 256, 0, stream>>>(uhp, ulp, vhp, vlp, vT, Mo, Lo, cosb, sinb, w1);
    k3b<<<dim3(32, 16), 256, 0, stream>>>(uhp, ulp, vhp, vlp, oT, Mo, Lo, cosb, sinb, w2);
    k4_final<<<dim3(32, 12), 256, 0, stream>>>(w1, w2, U, V, outp);
}

// Round 7
// 333.171 us; speedup vs baseline: 2.3471x; 1.0035x over previous
//
#include <hip/hip_runtime.h>

typedef _Float16 f16;
typedef _Float16 f16x8 __attribute__((ext_vector_type(8)));
typedef _Float16 f16x4 __attribute__((ext_vector_type(4)));
typedef float f32x4 __attribute__((ext_vector_type(4)));

#define MFMA16(A,B,C) __builtin_amdgcn_mfma_f32_16x16x32_f16(A,B,C,0,0,0)
#define INV2048 4.8828125e-4f
#define HN (16ll*2048*96)
#define UVN 589824   // 768*768
// z in log2 domain: zl = log2(e)*768*accS + log2(e)*768/2048*accX
#define ZC1 1107.98979f
#define ZC2 0.54101064f

__device__ __forceinline__ void split_f16(float x, f16& h, f16& l) {
    h = (f16)x;
    l = (f16)((x - (float)h) * 2048.0f);   // lo pre-scaled by 2^11 (avoids fp16 denorm loss)
}

// ============================================================
// K0: split qz, U, V (fp32) into fp16 hi/lo pairs.
// ============================================================
__global__ __launch_bounds__(256) void k0_split(const float* __restrict__ qz,
                                                const float* __restrict__ U,
                                                const float* __restrict__ V,
                                                f16* __restrict__ qzh, f16* __restrict__ qzl,
                                                f16* __restrict__ Uh, f16* __restrict__ Ul,
                                                f16* __restrict__ Vh, f16* __restrict__ Vl) {
    const int i4 = blockIdx.x * 256 + threadIdx.x;   // float4 index
    {
        float4 x = *(const float4*)(qz + (size_t)i4 * 4);
        f16 h0, l0, h1, l1, h2, l2, h3, l3;
        split_f16(x.x, h0, l0); split_f16(x.y, h1, l1);
        split_f16(x.z, h2, l2); split_f16(x.w, h3, l3);
        f16x4 hv = {h0, h1, h2, h3};
        f16x4 lv = {l0, l1, l2, l3};
        *(f16x4*)(qzh + (size_t)i4 * 4) = hv;
        *(f16x4*)(qzl + (size_t)i4 * 4) = lv;
    }
    if (i4 < UVN / 4) {
        float4 x = *(const float4*)(U + (size_t)i4 * 4);
        f16 h0, l0, h1, l1, h2, l2, h3, l3;
        split_f16(x.x, h0, l0); split_f16(x.y, h1, l1);
        split_f16(x.z, h2, l2); split_f16(x.w, h3, l3);
        f16x4 hv = {h0, h1, h2, h3};
        f16x4 lv = {l0, l1, l2, l3};
        *(f16x4*)(Uh + (size_t)i4 * 4) = hv;
        *(f16x4*)(Ul + (size_t)i4 * 4) = lv;
        float4 y = *(const float4*)(V + (size_t)i4 * 4);
        split_f16(y.x, h0, l0); split_f16(y.y, h1, l1);
        split_f16(y.z, h2, l2); split_f16(y.w, h3, l3);
        f16x4 hv2 = {h0, h1, h2, h3};
        f16x4 lv2 = {l0, l1, l2, l3};
        *(f16x4*)(Vh + (size_t)i4 * 4) = hv2;
        *(f16x4*)(Vl + (size_t)i4 * 4) = lv2;
    }
}

// ============================================================
// K1: dual GEMM qz@U^T, qz@V^T via fp16 MFMA 3-product emulation
// + RoPE. + XCD-chunked block swizzle (each XCD owns one c-panel).
// ============================================================
__global__ __launch_bounds__(256, 2) void k1_proj(const f16* __restrict__ qzh,
                                                  const f16* __restrict__ qzl,
                                                  const f16* __restrict__ Uh,
                                                  const f16* __restrict__ Ul,
                                                  const f16* __restrict__ Vh,
                                                  const f16* __restrict__ Vl,
                                                  const float* __restrict__ cosb,
                                                  const float* __restrict__ sinb,
                                                  f16* __restrict__ uhp, f16* __restrict__ ulp,
                                                  f16* __restrict__ vhp, f16* __restrict__ vlp,
                                                  f16* __restrict__ vT, f16* __restrict__ oT) {
    __shared__ __align__(16) f16 smem[36864];            // 73728 B -> 2 blocks/CU
    f16* sAh  = smem;                                    // [64][72]
    f16* sAl  = smem + 4608;
    f16* sBuh = smem + 9216;                             // [96][72]
    f16* sBul = smem + 9216 + 6912;
    f16* sBvh = smem + 9216 + 2 * 6912;
    f16* sBvl = smem + 9216 + 3 * 6912;

    const int tid = threadIdx.x;
    const int w = tid >> 6, lane = tid & 63;
    const int quad = lane >> 4, l15 = lane & 15;
    const int wr = w >> 1, wc = w & 1;                   // 2x2 wave grid
    // XCD-chunked bijective swizzle (512 blocks, 8 XCDs)
    const int bid0 = blockIdx.y * 64 + blockIdx.x;
    const int swz  = (bid0 & 7) * 64 + (bid0 >> 3);
    const int bs0 = (swz & 63) * 64;
    const int c = swz >> 6;

    const f16* Ug_h = Uh + (size_t)c * 96 * 768;
    const f16* Ug_l = Ul + (size_t)c * 96 * 768;
    const f16* Vg_h = Vh + (size_t)c * 96 * 768;
    const f16* Vg_l = Vl + (size_t)c * 96 * 768;

    f32x4 aUS[2][3] = {}, aUX[2][3] = {};
    f32x4 aVS[2][3] = {}, aVX[2][3] = {};

    for (int k0 = 0; k0 < 768; k0 += 64) {
        __syncthreads();
#pragma unroll
        for (int m = 0; m < 2; ++m) {
            int f = tid + 256 * m, row = f >> 3, cg = f & 7;
            const size_t go = (size_t)(bs0 + row) * 768 + k0 + cg * 8;
            const int lo = row * 72 + cg * 8;
            *(float4*)&sAh[lo] = *(const float4*)(qzh + go);
            *(float4*)&sAl[lo] = *(const float4*)(qzl + go);
        }
#pragma unroll
        for (int m = 0; m < 3; ++m) {
            int f = tid + 256 * m, row = f >> 3, cg = f & 7;
            const size_t go = (size_t)row * 768 + k0 + cg * 8;
            const int lo = row * 72 + cg * 8;
            *(float4*)&sBuh[lo] = *(const float4*)(Ug_h + go);
            *(float4*)&sBul[lo] = *(const float4*)(Ug_l + go);
            *(float4*)&sBvh[lo] = *(const float4*)(Vg_h + go);
            *(float4*)&sBvl[lo] = *(const float4*)(Vg_l + go);
        }
        __syncthreads();
#pragma unroll
        for (int cc = 0; cc < 2; ++cc) {
            f16x8 ah[2], al[2];
#pragma unroll
            for (int mt = 0; mt < 2; ++mt) {
                const int ar = (32 * wr + 16 * mt + l15) * 72 + cc * 32 + quad * 8;
                ah[mt] = *(const f16x8*)&sAh[ar];
                al[mt] = *(const f16x8*)&sAl[ar];
            }
#pragma unroll
            for (int nt = 0; nt < 3; ++nt) {
                const int br = (48 * wc + 16 * nt + l15) * 72 + cc * 32 + quad * 8;
                f16x8 buh = *(const f16x8*)&sBuh[br];
                f16x8 bul = *(const f16x8*)&sBul[br];
                f16x8 bvh = *(const f16x8*)&sBvh[br];
                f16x8 bvl = *(const f16x8*)&sBvl[br];
#pragma unroll
                for (int mt = 0; mt < 2; ++mt) {
                    aUS[mt][nt] = MFMA16(ah[mt], buh, aUS[mt][nt]);
                    aUX[mt][nt] = MFMA16(ah[mt], bul, aUX[mt][nt]);
                    aUX[mt][nt] = MFMA16(al[mt], buh, aUX[mt][nt]);
                    aVS[mt][nt] = MFMA16(ah[mt], bvh, aVS[mt][nt]);
                    aVX[mt][nt] = MFMA16(ah[mt], bvl, aVX[mt][nt]);
                    aVX[mt][nt] = MFMA16(al[mt], bvh, aVX[mt][nt]);
                }
            }
        }
    }

    __syncthreads();
    float* LU = (float*)smem;          // [64][100] = 25.6 KB
    float* LV = LU + 6400;
#pragma unroll
    for (int mt = 0; mt < 2; ++mt)
#pragma unroll
        for (int nt = 0; nt < 3; ++nt)
#pragma unroll
            for (int r = 0; r < 4; ++r) {
                const int sl = 32 * wr + 16 * mt + 4 * quad + r;
                const int col = 48 * wc + 16 * nt + l15;
                LU[sl * 100 + col] = aUS[mt][nt][r] + aUX[mt][nt][r] * INV2048;
                LV[sl * 100 + col] = aVS[mt][nt][r] + aVX[mt][nt][r] * INV2048;
            }
    __syncthreads();

    const int b = bs0 >> 11;
    const int s0 = bs0 & 2047;
    const int head = b * 8 + c;
    const size_t nb = (size_t)head * 2048 * 96;
    const size_t tb = (size_t)head * 96 * 2048;
    const int ty = tid >> 4, tx = tid & 15;

#pragma unroll
    for (int jj = 0; jj < 3; ++jj) {
        int r = tx + 16 * jj;
        f16 vt1[4], vt2[4], ot1[4], ot2[4];
#pragma unroll
        for (int ii = 0; ii < 4; ++ii) {
            int sl = 4 * ty + ii;
            int s = s0 + sl;
            int cbi = (b * 2048 + s) * 96 + r;
            float cc = cosb[cbi], ss = sinb[cbi];
            size_t rowb = nb + (size_t)s * 96;
            float u1 = LU[sl * 100 + r], u2 = LU[sl * 100 + r + 48];
            float v1 = LV[sl * 100 + r], v2 = LV[sl * 100 + r + 48];
            float ur1 = u1 * cc - u2 * ss, ur2 = u2 * cc + u1 * ss;
            float uo1 = u1 * cc + u2 * ss, uo2 = u2 * cc - u1 * ss;
            float vr1 = v1 * cc - v2 * ss, vr2 = v2 * cc + v1 * ss;
            f16 h, l;
            split_f16(ur1, h, l); uhp[rowb + r] = h;      ulp[rowb + r] = l;
            split_f16(ur2, h, l); uhp[rowb + r + 48] = h; ulp[rowb + r + 48] = l;
            split_f16(vr1, h, l); vhp[rowb + r] = h;      vlp[rowb + r] = l;      vt1[ii] = h;
            split_f16(vr2, h, l); vhp[rowb + r + 48] = h; vlp[rowb + r + 48] = l; vt2[ii] = h;
            ot1[ii] = (f16)uo1; ot2[ii] = (f16)uo2;
        }
        f16x4 pv1 = {vt1[0], vt1[1], vt1[2], vt1[3]};
        f16x4 pv2 = {vt2[0], vt2[1], vt2[2], vt2[3]};
        f16x4 po1 = {ot1[0], ot1[1], ot1[2], ot1[3]};
        f16x4 po2 = {ot2[0], ot2[1], ot2[2], ot2[3]};
        *(f16x4*)&vT[tb + (size_t)r * 2048 + s0 + 4 * ty] = pv1;
        *(f16x4*)&vT[tb + (size_t)(r + 48) * 2048 + s0 + 4 * ty] = pv2;
        *(f16x4*)&oT[tb + (size_t)r * 2048 + s0 + 4 * ty] = po1;
        *(f16x4*)&oT[tb + (size_t)(r + 48) * 2048 + s0 + 4 * ty] = po2;
    }
}

// ============================================================
// K2: MFMA row MAX only. Double-buffered Bh/Bl, 1 barrier/tile,
// named-reg prefetch. + XCD swizzle + setprio around MFMA cluster.
// ============================================================
__global__ __launch_bounds__(256, 2) void k2_stats(const f16* __restrict__ uhp,
                                                   const f16* __restrict__ ulp,
                                                   const f16* __restrict__ vhp,
                                                   const f16* __restrict__ vlp,
                                                   float* __restrict__ Mo) {
    __shared__ f16 Bh[2][64 * 104];
    __shared__ f16 Bl[2][64 * 104];
    __shared__ float Mbuf[4][64];
    const int tid = threadIdx.x, w = tid >> 6, lane = tid & 63;
    const int quad = lane >> 4, l15 = lane & 15;
    const int bid0 = blockIdx.y * 32 + blockIdx.x;
    const int swz  = (bid0 & 7) * 64 + (bid0 >> 3);
    const int q0 = (swz & 31) * 64, head = swz >> 5;
    const f16* Ah_g = uhp + (size_t)head * 2048 * 96;
    const f16* Al_g = ulp + (size_t)head * 2048 * 96;
    const f16* Bh_g = vhp + (size_t)head * 2048 * 96;
    const f16* Bl_g = vlp + (size_t)head * 2048 * 96;

    f16x8 Afh[4][3], Afl[4][3];
#pragma unroll
    for (int mt = 0; mt < 4; ++mt)
#pragma unroll
        for (int cc = 0; cc < 3; ++cc) {
            size_t off = (size_t)(q0 + 16 * mt + l15) * 96 + cc * 32 + quad * 8;
            Afh[mt][cc] = *(const f16x8*)(Ah_g + off);
            Afl[mt][cc] = *(const f16x8*)(Al_g + off);
        }

    const int sr0 = tid / 12,         sc0 = (tid % 12) * 8;
    const int sr1 = (tid + 256) / 12, sc1 = ((tid + 256) % 12) * 8;
    const int sr2 = (tid + 512) / 12, sc2 = ((tid + 512) % 12) * 8;

    float4 h0, h1, h2, g0, g1, g2;   // named staging regs (Bh, Bl)

    float m_run[4][4];
#pragma unroll
    for (int mt = 0; mt < 4; ++mt)
#pragma unroll
        for (int r = 0; r < 4; ++r) m_run[mt][r] = -3.0e38f;

    // prologue: tile 0 -> buf 0
    h0 = *(const float4*)(Bh_g + (size_t)sr0 * 96 + sc0);
    h1 = *(const float4*)(Bh_g + (size_t)sr1 * 96 + sc1);
    h2 = *(const float4*)(Bh_g + (size_t)sr2 * 96 + sc2);
    g0 = *(const float4*)(Bl_g + (size_t)sr0 * 96 + sc0);
    g1 = *(const float4*)(Bl_g + (size_t)sr1 * 96 + sc1);
    g2 = *(const float4*)(Bl_g + (size_t)sr2 * 96 + sc2);
    *(float4*)&Bh[0][sr0 * 104 + sc0] = h0;
    *(float4*)&Bh[0][sr1 * 104 + sc1] = h1;
    *(float4*)&Bh[0][sr2 * 104 + sc2] = h2;
    *(float4*)&Bl[0][sr0 * 104 + sc0] = g0;
    *(float4*)&Bl[0][sr1 * 104 + sc1] = g1;
    *(float4*)&Bl[0][sr2 * 104 + sc2] = g2;
    __syncthreads();

    for (int t = 0; t < 32; ++t) {
        const int cur = t & 1;
        if (t < 31) {                 // issue next-tile loads; hide under MFMAs
            const f16* bg = Bh_g + (size_t)(t + 1) * 6144;
            const f16* lg = Bl_g + (size_t)(t + 1) * 6144;
            h0 = *(const float4*)(bg + (size_t)sr0 * 96 + sc0);
            h1 = *(const float4*)(bg + (size_t)sr1 * 96 + sc1);
            h2 = *(const float4*)(bg + (size_t)sr2 * 96 + sc2);
            g0 = *(const float4*)(lg + (size_t)sr0 * 96 + sc0);
            g1 = *(const float4*)(lg + (size_t)sr1 * 96 + sc1);
            g2 = *(const float4*)(lg + (size_t)sr2 * 96 + sc2);
        }
        f32x4 accS[4] = {}, accX[4] = {};
        __builtin_amdgcn_s_setprio(1);
#pragma unroll
        for (int cc = 0; cc < 3; ++cc) {
            f16x8 bh = *(const f16x8*)&Bh[cur][(w * 16 + l15) * 104 + cc * 32 + quad * 8];
            f16x8 bl = *(const f16x8*)&Bl[cur][(w * 16 + l15) * 104 + cc * 32 + quad * 8];
#pragma unroll
            for (int mt = 0; mt < 4; ++mt) {
                accS[mt] = MFMA16(Afh[mt][cc], bh, accS[mt]);
                accX[mt] = MFMA16(Afh[mt][cc], bl, accX[mt]);
                accX[mt] = MFMA16(Afl[mt][cc], bh, accX[mt]);
            }
        }
        __builtin_amdgcn_s_setprio(0);
#pragma unroll
        for (int mt = 0; mt < 4; ++mt)
#pragma unroll
            for (int r = 0; r < 4; ++r) {
                float zl = fmaf(ZC1, accS[mt][r], ZC2 * accX[mt][r]);
                m_run[mt][r] = fmaxf(m_run[mt][r], zl);
            }
        if (t < 31) {                 // write buf^1 (its readers finished at bar(t-1))
            *(float4*)&Bh[cur ^ 1][sr0 * 104 + sc0] = h0;
            *(float4*)&Bh[cur ^ 1][sr1 * 104 + sc1] = h1;
            *(float4*)&Bh[cur ^ 1][sr2 * 104 + sc2] = h2;
            *(float4*)&Bl[cur ^ 1][sr0 * 104 + sc0] = g0;
            *(float4*)&Bl[cur ^ 1][sr1 * 104 + sc1] = g1;
            *(float4*)&Bl[cur ^ 1][sr2 * 104 + sc2] = g2;
        }
        __syncthreads();              // single barrier per tile
    }
#pragma unroll
    for (int mt = 0; mt < 4; ++mt)
#pragma unroll
        for (int r = 0; r < 4; ++r) {
            float m = m_run[mt][r];
            m = fmaxf(m, __shfl_xor(m, 1)); m = fmaxf(m, __shfl_xor(m, 2));
            m = fmaxf(m, __shfl_xor(m, 4)); m = fmaxf(m, __shfl_xor(m, 8));
            m_run[mt][r] = m;
        }
    if (l15 == 0) {
#pragma unroll
        for (int mt = 0; mt < 4; ++mt)
#pragma unroll
            for (int r = 0; r < 4; ++r)
                Mbuf[w][16 * mt + 4 * quad + r] = m_run[mt][r];
    }
    __syncthreads();
    if (tid < 64) {
        float M = -3.0e38f;
#pragma unroll
        for (int ww = 0; ww < 4; ++ww) M = fmaxf(M, Mbuf[ww][tid]);
        Mo[head * 2048 + q0 + tid] = M;      // log2-domain exact row max
    }
}

// ============================================================
// K3a: S=ur.vr^T, P=exp2(zl-M[q]), out=P@vr + ones-column row sums
// (L), /L, rope_o -> w1; writes Lo. 2 barriers/tile, named-reg
// prefetch. + P XOR-swizzle (col ^= 32 when q-row bit3 set: breaks
// the 4-way store conflict, reads stay uniform) + XCD swizzle +
// setprio around both MFMA clusters.
// ============================================================
__global__ __launch_bounds__(256, 2) void k3a(const f16* __restrict__ uhp,
                                              const f16* __restrict__ ulp,
                                              const f16* __restrict__ vhp,
                                              const f16* __restrict__ vlp,
                                              const f16* __restrict__ vT,
                                              const float* __restrict__ Mo,
                                              float* __restrict__ Lo,
                                              const float* __restrict__ cosb,
                                              const float* __restrict__ sinb,
                                              f16* __restrict__ w1) {
    __shared__ f16 Bh[64 * 104];
    __shared__ f16 Bl[64 * 104];
    __shared__ f16 Vt[2][112 * 72];    // rows 96..111 = ones in both buffers
    __shared__ f16 P[64 * 72];
    const int tid = threadIdx.x, w = tid >> 6, lane = tid & 63;
    const int quad = lane >> 4, l15 = lane & 15;
    const int bid0 = blockIdx.y * 32 + blockIdx.x;
    const int swz  = (bid0 & 7) * 64 + (bid0 >> 3);
    const int q0 = (swz & 31) * 64, head = swz >> 5;
    const f16* Ah_g = uhp + (size_t)head * 2048 * 96;
    const f16* Al_g = ulp + (size_t)head * 2048 * 96;
    const f16* Bh_g = vhp + (size_t)head * 2048 * 96;
    const f16* Bl_g = vlp + (size_t)head * 2048 * 96;
    const f16* Vt_g = vT + (size_t)head * 96 * 2048;

    f16x8 Afh[4][3], Afl[4][3];
#pragma unroll
    for (int mt = 0; mt < 4; ++mt)
#pragma unroll
        for (int cc = 0; cc < 3; ++cc) {
            size_t off = (size_t)(q0 + 16 * mt + l15) * 96 + cc * 32 + quad * 8;
            Afh[mt][cc] = *(const f16x8*)(Ah_g + off);
            Afl[mt][cc] = *(const f16x8*)(Al_g + off);
        }
    float negM[4][4];
#pragma unroll
    for (int mt = 0; mt < 4; ++mt)
#pragma unroll
        for (int r = 0; r < 4; ++r)
            negM[mt][r] = -Mo[head * 2048 + q0 + 16 * mt + 4 * quad + r];

    const int sr0 = tid / 12,         sc0 = (tid % 12) * 8;
    const int sr1 = (tid + 256) / 12, sc1 = ((tid + 256) % 12) * 8;
    const int sr2 = (tid + 512) / 12, sc2 = ((tid + 512) % 12) * 8;
    const int vr0 = tid >> 3, vcc = (tid & 7) * 8;   // Vt rows vr0, vr0+32, vr0+64

    // P swizzle constants: write col ^= 32 when q-row bit3 (quad>=2);
    // read chunk ^= 32 when q-row bit3 (l15>=8)
    const int pwsw = (quad & 2) << 4;
    const int prsw = (l15 & 8) << 2;

    float4 h0, h1, h2, g0, g1, g2, v0, v1, v2;       // named staging regs

    if (tid < 144) {
        f16x8 ones = {(f16)1, (f16)1, (f16)1, (f16)1,
                      (f16)1, (f16)1, (f16)1, (f16)1};
        *(f16x8*)&Vt[0][96 * 72 + tid * 8] = ones;
        *(f16x8*)&Vt[1][96 * 72 + tid * 8] = ones;
    }

    // prologue: tile 0
    h0 = *(const float4*)(Bh_g + (size_t)sr0 * 96 + sc0);
    h1 = *(const float4*)(Bh_g + (size_t)sr1 * 96 + sc1);
    h2 = *(const float4*)(Bh_g + (size_t)sr2 * 96 + sc2);
    g0 = *(const float4*)(Bl_g + (size_t)sr0 * 96 + sc0);
    g1 = *(const float4*)(Bl_g + (size_t)sr1 * 96 + sc1);
    g2 = *(const float4*)(Bl_g + (size_t)sr2 * 96 + sc2);
    v0 = *(const float4*)(Vt_g + (size_t)vr0 * 2048 + vcc);
    v1 = *(const float4*)(Vt_g + (size_t)(vr0 + 32) * 2048 + vcc);
    v2 = *(const float4*)(Vt_g + (size_t)(vr0 + 64) * 2048 + vcc);
    *(float4*)&Bh[sr0 * 104 + sc0] = h0;
    *(float4*)&Bh[sr1 * 104 + sc1] = h1;
    *(float4*)&Bh[sr2 * 104 + sc2] = h2;
    *(float4*)&Bl[sr0 * 104 + sc0] = g0;
    *(float4*)&Bl[sr1 * 104 + sc1] = g1;
    *(float4*)&Bl[sr2 * 104 + sc2] = g2;
    *(float4*)&Vt[0][vr0 * 72 + vcc] = v0;
    *(float4*)&Vt[0][(vr0 + 32) * 72 + vcc] = v1;
    *(float4*)&Vt[0][(vr0 + 64) * 72 + vcc] = v2;
    __syncthreads();

    f32x4 accO[7] = {};
    int pcur = 0;

    for (int t = 0; t < 32; ++t) {
        if (t < 31) {                 // issue t+1 loads; hide under S-MFMA + exp
            const f16* bg = Bh_g + (size_t)(t + 1) * 6144;
            const f16* lg = Bl_g + (size_t)(t + 1) * 6144;
            const int kn = (t + 1) * 64;
            h0 = *(const float4*)(bg + (size_t)sr0 * 96 + sc0);
            h1 = *(const float4*)(bg + (size_t)sr1 * 96 + sc1);
            h2 = *(const float4*)(bg + (size_t)sr2 * 96 + sc2);
            g0 = *(const float4*)(lg + (size_t)sr0 * 96 + sc0);
            g1 = *(const float4*)(lg + (size_t)sr1 * 96 + sc1);
            g2 = *(const float4*)(lg + (size_t)sr2 * 96 + sc2);
            v0 = *(const float4*)(Vt_g + (size_t)vr0 * 2048 + kn + vcc);
            v1 = *(const float4*)(Vt_g + (size_t)(vr0 + 32) * 2048 + kn + vcc);
            v2 = *(const float4*)(Vt_g + (size_t)(vr0 + 64) * 2048 + kn + vcc);
        }
        f32x4 accS[4] = {}, accX[4] = {};
        __builtin_amdgcn_s_setprio(1);
#pragma unroll
        for (int cc = 0; cc < 3; ++cc) {
            f16x8 bh = *(const f16x8*)&Bh[(w * 16 + l15) * 104 + cc * 32 + quad * 8];
            f16x8 bl = *(const f16x8*)&Bl[(w * 16 + l15) * 104 + cc * 32 + quad * 8];
#pragma unroll
            for (int mt = 0; mt < 4; ++mt) {
                accS[mt] = MFMA16(Afh[mt][cc], bh, accS[mt]);
                accX[mt] = MFMA16(Afh[mt][cc], bl, accX[mt]);
                accX[mt] = MFMA16(Afl[mt][cc], bh, accX[mt]);
            }
        }
        __builtin_amdgcn_s_setprio(0);
#pragma unroll
        for (int mt = 0; mt < 4; ++mt)
#pragma unroll
            for (int r = 0; r < 4; ++r) {
                float zl = fmaf(ZC1, accS[mt][r], ZC2 * accX[mt][r]);
                P[(16 * mt + 4 * quad + r) * 72 + ((w * 16 + l15) ^ pwsw)] =
                    (f16)exp2f(zl + negM[mt][r]);
            }
        __syncthreads();              // bar_A: P visible; S reads of Bh complete
        if (t < 31) {                 // stage t+1 (overlaps PV below)
            *(float4*)&Bh[sr0 * 104 + sc0] = h0;
            *(float4*)&Bh[sr1 * 104 + sc1] = h1;
            *(float4*)&Bh[sr2 * 104 + sc2] = h2;
            *(float4*)&Bl[sr0 * 104 + sc0] = g0;
            *(float4*)&Bl[sr1 * 104 + sc1] = g1;
            *(float4*)&Bl[sr2 * 104 + sc2] = g2;
            *(float4*)&Vt[pcur ^ 1][vr0 * 72 + vcc] = v0;
            *(float4*)&Vt[pcur ^ 1][(vr0 + 32) * 72 + vcc] = v1;
            *(float4*)&Vt[pcur ^ 1][(vr0 + 64) * 72 + vcc] = v2;
        }
        __builtin_amdgcn_s_setprio(1);
#pragma unroll
        for (int kc = 0; kc < 2; ++kc) {
            f16x8 ap = *(const f16x8*)&P[(w * 16 + l15) * 72 +
                                         ((kc * 32 + quad * 8) ^ prsw)];
#pragma unroll
            for (int nt = 0; nt < 7; ++nt) {   // nt=6: ones rows -> row sums (L)
                f16x8 bv = *(const f16x8*)&Vt[pcur][(nt * 16 + l15) * 72 + kc * 32 + quad * 8];
                accO[nt] = MFMA16(ap, bv, accO[nt]);
            }
        }
        __builtin_amdgcn_s_setprio(0);
        __syncthreads();              // bar_B: staging visible; P/Vt reads done
        pcur ^= 1;
    }
    float invL[4];
#pragma unroll
    for (int r = 0; r < 4; ++r) invL[r] = 1.0f / accO[6][r];
    if (l15 == 0) {
#pragma unroll
        for (int r = 0; r < 4; ++r)
            Lo[head * 2048 + q0 + w * 16 + quad * 4 + r] = accO[6][r];
    }

    const int b = head >> 3, c = head & 7;
#pragma unroll
    for (int r = 0; r < 4; ++r) {
        int q = q0 + w * 16 + quad * 4 + r;
        int cbi = (b * 2048 + q) * 96;
        f16* wrow = w1 + (size_t)(b * 2048 + q) * 768 + c * 96;
#pragma unroll
        for (int nt = 0; nt < 3; ++nt) {
            int rr = nt * 16 + l15;
            float cc = cosb[cbi + rr], ss = sinb[cbi + rr];
            float a = accO[nt][r] * invL[r];
            float b2 = accO[nt + 3][r] * invL[r];
            wrow[rr] = (f16)(a * cc + b2 * ss);
            wrow[rr + 48] = (f16)(b2 * cc - a * ss);
        }
    }
}

// ============================================================
// K3b: S2[q][k]=vr_q.ur_k, P2=exp2(zl-M[k])/L[k], out=P2@uo,
// rope -> w2. Same pipeline + swizzles + setprio as k3a.
// ============================================================
__global__ __launch_bounds__(256, 2) void k3b(const f16* __restrict__ uhp,
                                              const f16* __restrict__ ulp,
                                              const f16* __restrict__ vhp,
                                              const f16* __restrict__ vlp,
                                              const f16* __restrict__ oT,
                                              const float* __restrict__ Mo,
                                              const float* __restrict__ Lo,
                                              const float* __restrict__ cosb,
                                              const float* __restrict__ sinb,
                                              f16* __restrict__ w2) {
    __shared__ f16 Bh[64 * 104];
    __shared__ f16 Bl[64 * 104];
    __shared__ f16 Ot[2][96 * 72];
    __shared__ f16 P[64 * 72];
    const int tid = threadIdx.x, w = tid >> 6, lane = tid & 63;
    const int quad = lane >> 4, l15 = lane & 15;
    const int bid0 = blockIdx.y * 32 + blockIdx.x;
    const int swz  = (bid0 & 7) * 64 + (bid0 >> 3);
    const int q0 = (swz & 31) * 64, head = swz >> 5;
    const f16* Ah_g = vhp + (size_t)head * 2048 * 96;   // A = vr
    const f16* Al_g = vlp + (size_t)head * 2048 * 96;
    const f16* Bh_g = uhp + (size_t)head * 2048 * 96;   // B = ur
    const f16* Bl_g = ulp + (size_t)head * 2048 * 96;
    const f16* Ot_g = oT + (size_t)head * 96 * 2048;

    f16x8 Afh[4][3], Afl[4][3];
#pragma unroll
    for (int mt = 0; mt < 4; ++mt)
#pragma unroll
        for (int cc = 0; cc < 3; ++cc) {
            size_t off = (size_t)(q0 + 16 * mt + l15) * 96 + cc * 32 + quad * 8;
            Afh[mt][cc] = *(const f16x8*)(Ah_g + off);
            Afl[mt][cc] = *(const f16x8*)(Al_g + off);
        }

    const int sr0 = tid / 12,         sc0 = (tid % 12) * 8;
    const int sr1 = (tid + 256) / 12, sc1 = ((tid + 256) % 12) * 8;
    const int sr2 = (tid + 512) / 12, sc2 = ((tid + 512) % 12) * 8;
    const int vr0 = tid >> 3, vcc = (tid & 7) * 8;

    const int pwsw = (quad & 2) << 4;
    const int prsw = (l15 & 8) << 2;

    float4 h0, h1, h2, g0, g1, g2, v0, v1, v2;

    // prologue: tile 0
    h0 = *(const float4*)(Bh_g + (size_t)sr0 * 96 + sc0);
    h1 = *(const float4*)(Bh_g + (size_t)sr1 * 96 + sc1);
    h2 = *(const float4*)(Bh_g + (size_t)sr2 * 96 + sc2);
    g0 = *(const float4*)(Bl_g + (size_t)sr0 * 96 + sc0);
    g1 = *(const float4*)(Bl_g + (size_t)sr1 * 96 + sc1);
    g2 = *(const float4*)(Bl_g + (size_t)sr2 * 96 + sc2);
    v0 = *(const float4*)(Ot_g + (size_t)vr0 * 2048 + vcc);
    v1 = *(const float4*)(Ot_g + (size_t)(vr0 + 32) * 2048 + vcc);
    v2 = *(const float4*)(Ot_g + (size_t)(vr0 + 64) * 2048 + vcc);
    *(float4*)&Bh[sr0 * 104 + sc0] = h0;
    *(float4*)&Bh[sr1 * 104 + sc1] = h1;
    *(float4*)&Bh[sr2 * 104 + sc2] = h2;
    *(float4*)&Bl[sr0 * 104 + sc0] = g0;
    *(float4*)&Bl[sr1 * 104 + sc1] = g1;
    *(float4*)&Bl[sr2 * 104 + sc2] = g2;
    *(float4*)&Ot[0][vr0 * 72 + vcc] = v0;
    *(float4*)&Ot[0][(vr0 + 32) * 72 + vcc] = v1;
    *(float4*)&Ot[0][(vr0 + 64) * 72 + vcc] = v2;
    __syncthreads();

    f32x4 accO[6] = {};
    int pcur = 0;

    for (int t = 0; t < 32; ++t) {
        const int k0 = t * 64;
        float negMk = -Mo[head * 2048 + k0 + w * 16 + l15];
        float invLk = 1.0f / Lo[head * 2048 + k0 + w * 16 + l15];
        if (t < 31) {
            const f16* bg = Bh_g + (size_t)(t + 1) * 6144;
            const f16* lg = Bl_g + (size_t)(t + 1) * 6144;
            const int kn = (t + 1) * 64;
            h0 = *(const float4*)(bg + (size_t)sr0 * 96 + sc0);
            h1 = *(const float4*)(bg + (size_t)sr1 * 96 + sc1);
            h2 = *(const float4*)(bg + (size_t)sr2 * 96 + sc2);
            g0 = *(const float4*)(lg + (size_t)sr0 * 96 + sc0);
            g1 = *(const float4*)(lg + (size_t)sr1 * 96 + sc1);
            g2 = *(const float4*)(lg + (size_t)sr2 * 96 + sc2);
            v0 = *(const float4*)(Ot_g + (size_t)vr0 * 2048 + kn + vcc);
            v1 = *(const float4*)(Ot_g + (size_t)(vr0 + 32) * 2048 + kn + vcc);
            v2 = *(const float4*)(Ot_g + (size_t)(vr0 + 64) * 2048 + kn + vcc);
        }
        f32x4 accS[4] = {}, accX[4] = {};
        __builtin_amdgcn_s_setprio(1);
#pragma unroll
        for (int cc = 0; cc < 3; ++cc) {
            f16x8 bh = *(const f16x8*)&Bh[(w * 16 + l15) * 104 + cc * 32 + quad * 8];
            f16x8 bl = *(const f16x8*)&Bl[(w * 16 + l15) * 104 + cc * 32 + quad * 8];
#pragma unroll
            for (int mt = 0; mt < 4; ++mt) {
                accS[mt] = MFMA16(Afh[mt][cc], bh, accS[mt]);
                // preserve k2/k3a's cross-product order: (u_hi*v_lo) first, then (u_lo*v_hi)
                accX[mt] = MFMA16(Afl[mt][cc], bh, accX[mt]);   // v_lo * u_hi
                accX[mt] = MFMA16(Afh[mt][cc], bl, accX[mt]);   // v_hi * u_lo
            }
        }
        __builtin_amdgcn_s_setprio(0);
#pragma unroll
        for (int mt = 0; mt < 4; ++mt)
#pragma unroll
            for (int r = 0; r < 4; ++r) {
                float zl = fmaf(ZC1, accS[mt][r], ZC2 * accX[mt][r]);
                P[(16 * mt + 4 * quad + r) * 72 + ((w * 16 + l15) ^ pwsw)] =
                    (f16)(exp2f(zl + negMk) * invLk);
            }
        __syncthreads();              // bar_A
        if (t < 31) {
            *(float4*)&Bh[sr0 * 104 + sc0] = h0;
            *(float4*)&Bh[sr1 * 104 + sc1] = h1;
            *(float4*)&Bh[sr2 * 104 + sc2] = h2;
            *(float4*)&Bl[sr0 * 104 + sc0] = g0;
            *(float4*)&Bl[sr1 * 104 + sc1] = g1;
            *(float4*)&Bl[sr2 * 104 + sc2] = g2;
            *(float4*)&Ot[pcur ^ 1][vr0 * 72 + vcc] = v0;
            *(float4*)&Ot[pcur ^ 1][(vr0 + 32) * 72 + vcc] = v1;
            *(float4*)&Ot[pcur ^ 1][(vr0 + 64) * 72 + vcc] = v2;
        }
        __builtin_amdgcn_s_setprio(1);
#pragma unroll
        for (int kc = 0; kc < 2; ++kc) {
            f16x8 ap = *(const f16x8*)&P[(w * 16 + l15) * 72 +
                                         ((kc * 32 + quad * 8) ^ prsw)];
#pragma unroll
            for (int nt = 0; nt < 6; ++nt) {
                f16x8 bo = *(const f16x8*)&Ot[pcur][(nt * 16 + l15) * 72 + kc * 32 + quad * 8];
                accO[nt] = MFMA16(ap, bo, accO[nt]);
            }
        }
        __builtin_amdgcn_s_setprio(0);
        __syncthreads();              // bar_B
        pcur ^= 1;
    }
    const int b = head >> 3, c = head & 7;
#pragma unroll
    for (int r = 0; r < 4; ++r) {
        int q = q0 + w * 16 + quad * 4 + r;
        int cbi = (b * 2048 + q) * 96;
        f16* wrow = w2 + (size_t)(b * 2048 + q) * 768 + c * 96;
#pragma unroll
        for (int nt = 0; nt < 3; ++nt) {
            int rr = nt * 16 + l15;
            float cc = cosb[cbi + rr], ss = sinb[cbi + rr];
            float a = accO[nt][r];
            float b2 = accO[nt + 3][r];
            wrow[rr] = (f16)(a * cc - b2 * ss);
            wrow[rr + 48] = (f16)(b2 * cc + a * ss);
        }
    }
}

// ============================================================
// K4: G = w1@U + w2@V (fp16 MFMA). (unchanged)
// ============================================================
__global__ __launch_bounds__(256, 2) void k4_final(const f16* __restrict__ w1,
                                                   const f16* __restrict__ w2,
                                                   const float* __restrict__ U,
                                                   const float* __restrict__ V,
                                                   float* __restrict__ outp) {
    __shared__ f16 A1[128 * 56];
    __shared__ f16 A2[128 * 56];
    __shared__ f16 B1[64 * 56];
    __shared__ f16 B2[64 * 56];
    const int tid = threadIdx.x, w = tid >> 6, lane = tid & 63;
    const int quad = lane >> 4, l15 = lane & 15;
    const int bs0 = blockIdx.x * 128;
    const int d0 = blockIdx.y * 64;
    f32x4 acc[2][4] = {};

    for (int ec = 0; ec < 24; ++ec) {
        int e0 = ec * 32;
        __syncthreads();
#pragma unroll
        for (int m = 0; m < 2; ++m) {
            int f = tid + 256 * m;
            int row = f >> 2, q = f & 3;
            *(float4*)&A1[row * 56 + q * 8] =
                *(const float4*)(w1 + (size_t)(bs0 + row) * 768 + e0 + q * 8);
            *(float4*)&A2[row * 56 + q * 8] =
                *(const float4*)(w2 + (size_t)(bs0 + row) * 768 + e0 + q * 8);
        }
#pragma unroll
        for (int m2 = 0; m2 < 2; ++m2) {
            int e_r = (tid >> 4) + 16 * m2;
            int dc = tid & 15;
            float4 fu = *(const float4*)(U + (size_t)(e0 + e_r) * 768 + d0 + dc * 4);
            float4 fv = *(const float4*)(V + (size_t)(e0 + e_r) * 768 + d0 + dc * 4);
            B1[(dc * 4 + 0) * 56 + e_r] = (f16)fu.x;
            B1[(dc * 4 + 1) * 56 + e_r] = (f16)fu.y;
            B1[(dc * 4 + 2) * 56 + e_r] = (f16)fu.z;
            B1[(dc * 4 + 3) * 56 + e_r] = (f16)fu.w;
            B2[(dc * 4 + 0) * 56 + e_r] = (f16)fv.x;
            B2[(dc * 4 + 1) * 56 + e_r] = (f16)fv.y;
            B2[(dc * 4 + 2) * 56 + e_r] = (f16)fv.z;
            B2[(dc * 4 + 3) * 56 + e_r] = (f16)fv.w;
        }
        __syncthreads();
        f16x8 a1f[2], a2f[2];
#pragma unroll
        for (int mt = 0; mt < 2; ++mt) {
            a1f[mt] = *(const f16x8*)&A1[(32 * w + 16 * mt + l15) * 56 + quad * 8];
            a2f[mt] = *(const f16x8*)&A2[(32 * w + 16 * mt + l15) * 56 + quad * 8];
        }
#pragma unroll
        for (int nt = 0; nt < 4; ++nt) {
            f16x8 b1f = *(const f16x8*)&B1[(nt * 16 + l15) * 56 + quad * 8];
            f16x8 b2f = *(const f16x8*)&B2[(nt * 16 + l15) * 56 + quad * 8];
#pragma unroll
            for (int mt = 0; mt < 2; ++mt) {
                acc[mt][nt] = MFMA16(a1f[mt], b1f, acc[mt][nt]);
                acc[mt][nt] = MFMA16(a2f[mt], b2f, acc[mt][nt]);
            }
        }
    }
#pragma unroll
    for (int mt = 0; mt < 2; ++mt)
#pragma unroll
        for (int nt = 0; nt < 4; ++nt)
#pragma unroll
            for (int r = 0; r < 4; ++r) {
                int s = bs0 + 32 * w + 16 * mt + 4 * quad + r;
                int d = d0 + 16 * nt + l15;
                outp[(size_t)s * 768 + d] = acc[mt][nt][r];
            }
}

extern "C" void kernel_launch(void* const* d_in, const int* in_sizes, int n_in,
                              void* d_out, int out_size, void* d_ws, size_t ws_size,
                              hipStream_t stream) {
    const float* qz   = (const float*)d_in[0];
    const float* cosb = (const float*)d_in[1];
    const float* sinb = (const float*)d_in[2];
    const float* U    = (const float*)d_in[3];
    const float* V    = (const float*)d_in[4];
    float* outp = (float*)d_out;

    f16* ws16 = (f16*)d_ws;
    f16* uhp = ws16;
    f16* ulp = ws16 + HN;
    f16* vhp = ws16 + 2 * HN;
    f16* vlp = ws16 + 3 * HN;
    f16* vT  = ws16 + 4 * HN;
    f16* oT  = ws16 + 5 * HN;
    f16* w1  = ws16 + 6 * HN;
    f16* w2  = ws16 + 7 * HN;
    float* Mo = (float*)(ws16 + 8 * HN);
    float* Lo = Mo + 16 * 2048;

    // qz hi/lo splits live in the w1/w2 slots (dead until k3a/k3b write them).
    f16* qzh = w1;
    f16* qzl = w2;
    // U/V hi/lo splits live in d_out scratch (overwritten by k4 at the end).
    f16* outw = (f16*)d_out;
    f16* Uh = outw;
    f16* Ul = outw + UVN;
    f16* Vh = outw + 2 * UVN;
    f16* Vl = outw + 3 * UVN;

    k0_split<<<dim3(3072), 256, 0, stream>>>(qz, U, V, qzh, qzl, Uh, Ul, Vh, Vl);
    k1_proj<<<dim3(64, 8), 256, 0, stream>>>(qzh, qzl, Uh, Ul, Vh, Vl, cosb, sinb,
                                             uhp, ulp, vhp, vlp, vT, oT);
    k2_stats<<<dim3(32, 16), 256, 0, stream>>>(uhp, ulp, vhp, vlp, Mo);
    k3a<<<dim3(32, 16), 256, 0, stream>>>(uhp, ulp, vhp, vlp, vT, Mo, Lo, cosb, sinb, w1);
    k3b<<<dim3(32, 16), 256, 0, stream>>>(uhp, ulp, vhp, vlp, oT, Mo, Lo, cosb, sinb, w2);
    k4_final<<<dim3(32, 12), 256, 0, stream>>>(w1, w2, U, V, outp);
}

// Round 8
// 326.274 us; speedup vs baseline: 2.3967x; 1.0211x over previous
//
#include <hip/hip_runtime.h>

typedef _Float16 f16;
typedef _Float16 f16x8 __attribute__((ext_vector_type(8)));
typedef _Float16 f16x4 __attribute__((ext_vector_type(4)));
typedef float f32x4 __attribute__((ext_vector_type(4)));

#define MFMA16(A,B,C) __builtin_amdgcn_mfma_f32_16x16x32_f16(A,B,C,0,0,0)
#define INV2048 4.8828125e-4f
#define HN (16ll*2048*96)
#define UVN 589824   // 768*768
// z in log2 domain: zl = log2(e)*768*accS + log2(e)*768/2048*accX
#define ZC1 1107.98979f
#define ZC2 0.54101064f

__device__ __forceinline__ void split_f16(float x, f16& h, f16& l) {
    h = (f16)x;
    l = (f16)((x - (float)h) * 2048.0f);   // lo pre-scaled by 2^11 (avoids fp16 denorm loss)
}

// ============================================================
// K0: split qz, U, V (fp32) into fp16 hi/lo pairs.
// ============================================================
__global__ __launch_bounds__(256) void k0_split(const float* __restrict__ qz,
                                                const float* __restrict__ U,
                                                const float* __restrict__ V,
                                                f16* __restrict__ qzh, f16* __restrict__ qzl,
                                                f16* __restrict__ Uh, f16* __restrict__ Ul,
                                                f16* __restrict__ Vh, f16* __restrict__ Vl) {
    const int i4 = blockIdx.x * 256 + threadIdx.x;   // float4 index
    {
        float4 x = *(const float4*)(qz + (size_t)i4 * 4);
        f16 h0, l0, h1, l1, h2, l2, h3, l3;
        split_f16(x.x, h0, l0); split_f16(x.y, h1, l1);
        split_f16(x.z, h2, l2); split_f16(x.w, h3, l3);
        f16x4 hv = {h0, h1, h2, h3};
        f16x4 lv = {l0, l1, l2, l3};
        *(f16x4*)(qzh + (size_t)i4 * 4) = hv;
        *(f16x4*)(qzl + (size_t)i4 * 4) = lv;
    }
    if (i4 < UVN / 4) {
        float4 x = *(const float4*)(U + (size_t)i4 * 4);
        f16 h0, l0, h1, l1, h2, l2, h3, l3;
        split_f16(x.x, h0, l0); split_f16(x.y, h1, l1);
        split_f16(x.z, h2, l2); split_f16(x.w, h3, l3);
        f16x4 hv = {h0, h1, h2, h3};
        f16x4 lv = {l0, l1, l2, l3};
        *(f16x4*)(Uh + (size_t)i4 * 4) = hv;
        *(f16x4*)(Ul + (size_t)i4 * 4) = lv;
        float4 y = *(const float4*)(V + (size_t)i4 * 4);
        split_f16(y.x, h0, l0); split_f16(y.y, h1, l1);
        split_f16(y.z, h2, l2); split_f16(y.w, h3, l3);
        f16x4 hv2 = {h0, h1, h2, h3};
        f16x4 lv2 = {l0, l1, l2, l3};
        *(f16x4*)(Vh + (size_t)i4 * 4) = hv2;
        *(f16x4*)(Vl + (size_t)i4 * 4) = lv2;
    }
}

// ============================================================
// K1: dual GEMM qz@U^T, qz@V^T via fp16 MFMA 3-product emulation
// + RoPE. + XCD-chunked block swizzle. (unchanged from round 7)
// ============================================================
__global__ __launch_bounds__(256, 2) void k1_proj(const f16* __restrict__ qzh,
                                                  const f16* __restrict__ qzl,
                                                  const f16* __restrict__ Uh,
                                                  const f16* __restrict__ Ul,
                                                  const f16* __restrict__ Vh,
                                                  const f16* __restrict__ Vl,
                                                  const float* __restrict__ cosb,
                                                  const float* __restrict__ sinb,
                                                  f16* __restrict__ uhp, f16* __restrict__ ulp,
                                                  f16* __restrict__ vhp, f16* __restrict__ vlp,
                                                  f16* __restrict__ vT, f16* __restrict__ oT) {
    __shared__ __align__(16) f16 smem[36864];            // 73728 B -> 2 blocks/CU
    f16* sAh  = smem;                                    // [64][72]
    f16* sAl  = smem + 4608;
    f16* sBuh = smem + 9216;                             // [96][72]
    f16* sBul = smem + 9216 + 6912;
    f16* sBvh = smem + 9216 + 2 * 6912;
    f16* sBvl = smem + 9216 + 3 * 6912;

    const int tid = threadIdx.x;
    const int w = tid >> 6, lane = tid & 63;
    const int quad = lane >> 4, l15 = lane & 15;
    const int wr = w >> 1, wc = w & 1;                   // 2x2 wave grid
    const int bid0 = blockIdx.y * 64 + blockIdx.x;
    const int swz  = (bid0 & 7) * 64 + (bid0 >> 3);
    const int bs0 = (swz & 63) * 64;
    const int c = swz >> 6;

    const f16* Ug_h = Uh + (size_t)c * 96 * 768;
    const f16* Ug_l = Ul + (size_t)c * 96 * 768;
    const f16* Vg_h = Vh + (size_t)c * 96 * 768;
    const f16* Vg_l = Vl + (size_t)c * 96 * 768;

    f32x4 aUS[2][3] = {}, aUX[2][3] = {};
    f32x4 aVS[2][3] = {}, aVX[2][3] = {};

    for (int k0 = 0; k0 < 768; k0 += 64) {
        __syncthreads();
#pragma unroll
        for (int m = 0; m < 2; ++m) {
            int f = tid + 256 * m, row = f >> 3, cg = f & 7;
            const size_t go = (size_t)(bs0 + row) * 768 + k0 + cg * 8;
            const int lo = row * 72 + cg * 8;
            *(float4*)&sAh[lo] = *(const float4*)(qzh + go);
            *(float4*)&sAl[lo] = *(const float4*)(qzl + go);
        }
#pragma unroll
        for (int m = 0; m < 3; ++m) {
            int f = tid + 256 * m, row = f >> 3, cg = f & 7;
            const size_t go = (size_t)row * 768 + k0 + cg * 8;
            const int lo = row * 72 + cg * 8;
            *(float4*)&sBuh[lo] = *(const float4*)(Ug_h + go);
            *(float4*)&sBul[lo] = *(const float4*)(Ug_l + go);
            *(float4*)&sBvh[lo] = *(const float4*)(Vg_h + go);
            *(float4*)&sBvl[lo] = *(const float4*)(Vg_l + go);
        }
        __syncthreads();
#pragma unroll
        for (int cc = 0; cc < 2; ++cc) {
            f16x8 ah[2], al[2];
#pragma unroll
            for (int mt = 0; mt < 2; ++mt) {
                const int ar = (32 * wr + 16 * mt + l15) * 72 + cc * 32 + quad * 8;
                ah[mt] = *(const f16x8*)&sAh[ar];
                al[mt] = *(const f16x8*)&sAl[ar];
            }
#pragma unroll
            for (int nt = 0; nt < 3; ++nt) {
                const int br = (48 * wc + 16 * nt + l15) * 72 + cc * 32 + quad * 8;
                f16x8 buh = *(const f16x8*)&sBuh[br];
                f16x8 bul = *(const f16x8*)&sBul[br];
                f16x8 bvh = *(const f16x8*)&sBvh[br];
                f16x8 bvl = *(const f16x8*)&sBvl[br];
#pragma unroll
                for (int mt = 0; mt < 2; ++mt) {
                    aUS[mt][nt] = MFMA16(ah[mt], buh, aUS[mt][nt]);
                    aUX[mt][nt] = MFMA16(ah[mt], bul, aUX[mt][nt]);
                    aUX[mt][nt] = MFMA16(al[mt], buh, aUX[mt][nt]);
                    aVS[mt][nt] = MFMA16(ah[mt], bvh, aVS[mt][nt]);
                    aVX[mt][nt] = MFMA16(ah[mt], bvl, aVX[mt][nt]);
                    aVX[mt][nt] = MFMA16(al[mt], bvh, aVX[mt][nt]);
                }
            }
        }
    }

    __syncthreads();
    float* LU = (float*)smem;          // [64][100] = 25.6 KB
    float* LV = LU + 6400;
#pragma unroll
    for (int mt = 0; mt < 2; ++mt)
#pragma unroll
        for (int nt = 0; nt < 3; ++nt)
#pragma unroll
            for (int r = 0; r < 4; ++r) {
                const int sl = 32 * wr + 16 * mt + 4 * quad + r;
                const int col = 48 * wc + 16 * nt + l15;
                LU[sl * 100 + col] = aUS[mt][nt][r] + aUX[mt][nt][r] * INV2048;
                LV[sl * 100 + col] = aVS[mt][nt][r] + aVX[mt][nt][r] * INV2048;
            }
    __syncthreads();

    const int b = bs0 >> 11;
    const int s0 = bs0 & 2047;
    const int head = b * 8 + c;
    const size_t nb = (size_t)head * 2048 * 96;
    const size_t tb = (size_t)head * 96 * 2048;
    const int ty = tid >> 4, tx = tid & 15;

#pragma unroll
    for (int jj = 0; jj < 3; ++jj) {
        int r = tx + 16 * jj;
        f16 vt1[4], vt2[4], ot1[4], ot2[4];
#pragma unroll
        for (int ii = 0; ii < 4; ++ii) {
            int sl = 4 * ty + ii;
            int s = s0 + sl;
            int cbi = (b * 2048 + s) * 96 + r;
            float cc = cosb[cbi], ss = sinb[cbi];
            size_t rowb = nb + (size_t)s * 96;
            float u1 = LU[sl * 100 + r], u2 = LU[sl * 100 + r + 48];
            float v1 = LV[sl * 100 + r], v2 = LV[sl * 100 + r + 48];
            float ur1 = u1 * cc - u2 * ss, ur2 = u2 * cc + u1 * ss;
            float uo1 = u1 * cc + u2 * ss, uo2 = u2 * cc - u1 * ss;
            float vr1 = v1 * cc - v2 * ss, vr2 = v2 * cc + v1 * ss;
            f16 h, l;
            split_f16(ur1, h, l); uhp[rowb + r] = h;      ulp[rowb + r] = l;
            split_f16(ur2, h, l); uhp[rowb + r + 48] = h; ulp[rowb + r + 48] = l;
            split_f16(vr1, h, l); vhp[rowb + r] = h;      vlp[rowb + r] = l;      vt1[ii] = h;
            split_f16(vr2, h, l); vhp[rowb + r + 48] = h; vlp[rowb + r + 48] = l; vt2[ii] = h;
            ot1[ii] = (f16)uo1; ot2[ii] = (f16)uo2;
        }
        f16x4 pv1 = {vt1[0], vt1[1], vt1[2], vt1[3]};
        f16x4 pv2 = {vt2[0], vt2[1], vt2[2], vt2[3]};
        f16x4 po1 = {ot1[0], ot1[1], ot1[2], ot1[3]};
        f16x4 po2 = {ot2[0], ot2[1], ot2[2], ot2[3]};
        *(f16x4*)&vT[tb + (size_t)r * 2048 + s0 + 4 * ty] = pv1;
        *(f16x4*)&vT[tb + (size_t)(r + 48) * 2048 + s0 + 4 * ty] = pv2;
        *(f16x4*)&oT[tb + (size_t)r * 2048 + s0 + 4 * ty] = po1;
        *(f16x4*)&oT[tb + (size_t)(r + 48) * 2048 + s0 + 4 * ty] = po2;
    }
}

// ============================================================
// K2: MFMA row MAX only. B-fragments loaded DIRECT global->regs
// (each (k,col) consumed by exactly one lane) with 1-tile-ahead
// prefetch into the h^1 register set. NO LDS, NO barriers in loop.
// ============================================================
__global__ __launch_bounds__(256, 2) void k2_stats(const f16* __restrict__ uhp,
                                                   const f16* __restrict__ ulp,
                                                   const f16* __restrict__ vhp,
                                                   const f16* __restrict__ vlp,
                                                   float* __restrict__ Mo) {
    __shared__ float Mbuf[4][64];
    const int tid = threadIdx.x, w = tid >> 6, lane = tid & 63;
    const int quad = lane >> 4, l15 = lane & 15;
    const int bid0 = blockIdx.y * 32 + blockIdx.x;
    const int swz  = (bid0 & 7) * 64 + (bid0 >> 3);
    const int q0 = (swz & 31) * 64, head = swz >> 5;
    const f16* Ah_g = uhp + (size_t)head * 2048 * 96;
    const f16* Al_g = ulp + (size_t)head * 2048 * 96;

    f16x8 Afh[4][3], Afl[4][3];
#pragma unroll
    for (int mt = 0; mt < 4; ++mt)
#pragma unroll
        for (int cc = 0; cc < 3; ++cc) {
            size_t off = (size_t)(q0 + 16 * mt + l15) * 96 + cc * 32 + quad * 8;
            Afh[mt][cc] = *(const f16x8*)(Ah_g + off);
            Afl[mt][cc] = *(const f16x8*)(Al_g + off);
        }

    // direct B-frag pointers: this lane owns row (w*16+l15), cols quad*8+cc*32
    const f16* Bh_p = vhp + (size_t)head * 2048 * 96 + (size_t)(w * 16 + l15) * 96 + quad * 8;
    const f16* Bl_p = vlp + (size_t)head * 2048 * 96 + (size_t)(w * 16 + l15) * 96 + quad * 8;

    f16x8 Bch[2][3], Bcl[2][3];
#pragma unroll
    for (int cc = 0; cc < 3; ++cc) {
        Bch[0][cc] = *(const f16x8*)(Bh_p + cc * 32);
        Bcl[0][cc] = *(const f16x8*)(Bl_p + cc * 32);
    }

    float m_run[4][4];
#pragma unroll
    for (int mt = 0; mt < 4; ++mt)
#pragma unroll
        for (int r = 0; r < 4; ++r) m_run[mt][r] = -3.0e38f;

    for (int tp = 0; tp < 16; ++tp) {
#pragma unroll
        for (int h = 0; h < 2; ++h) {
            const int t = 2 * tp + h;
            if (t < 31) {
                const f16* bh = Bh_p + (size_t)(t + 1) * 6144;
                const f16* bl = Bl_p + (size_t)(t + 1) * 6144;
#pragma unroll
                for (int cc = 0; cc < 3; ++cc) {
                    Bch[h ^ 1][cc] = *(const f16x8*)(bh + cc * 32);
                    Bcl[h ^ 1][cc] = *(const f16x8*)(bl + cc * 32);
                }
            }
            f32x4 accS[4] = {}, accX[4] = {};
            __builtin_amdgcn_s_setprio(1);
#pragma unroll
            for (int cc = 0; cc < 3; ++cc)
#pragma unroll
                for (int mt = 0; mt < 4; ++mt) {
                    accS[mt] = MFMA16(Afh[mt][cc], Bch[h][cc], accS[mt]);
                    accX[mt] = MFMA16(Afh[mt][cc], Bcl[h][cc], accX[mt]);
                    accX[mt] = MFMA16(Afl[mt][cc], Bch[h][cc], accX[mt]);
                }
            __builtin_amdgcn_s_setprio(0);
#pragma unroll
            for (int mt = 0; mt < 4; ++mt)
#pragma unroll
                for (int r = 0; r < 4; ++r) {
                    float zl = fmaf(ZC1, accS[mt][r], ZC2 * accX[mt][r]);
                    m_run[mt][r] = fmaxf(m_run[mt][r], zl);
                }
        }
    }
#pragma unroll
    for (int mt = 0; mt < 4; ++mt)
#pragma unroll
        for (int r = 0; r < 4; ++r) {
            float m = m_run[mt][r];
            m = fmaxf(m, __shfl_xor(m, 1)); m = fmaxf(m, __shfl_xor(m, 2));
            m = fmaxf(m, __shfl_xor(m, 4)); m = fmaxf(m, __shfl_xor(m, 8));
            m_run[mt][r] = m;
        }
    if (l15 == 0) {
#pragma unroll
        for (int mt = 0; mt < 4; ++mt)
#pragma unroll
            for (int r = 0; r < 4; ++r)
                Mbuf[w][16 * mt + 4 * quad + r] = m_run[mt][r];
    }
    __syncthreads();
    if (tid < 64) {
        float M = -3.0e38f;
#pragma unroll
        for (int ww = 0; ww < 4; ++ww) M = fmaxf(M, Mbuf[ww][tid]);
        Mo[head * 2048 + q0 + tid] = M;      // log2-domain exact row max
    }
}

// ============================================================
// K3a: S=ur.vr^T, P=exp2(zl-M[q]), out=P@vr + ones-column row sums
// (L), /L, rope_o -> w1; writes Lo.
// B-frags DIRECT global->regs (1-tile-ahead prefetch); P and Vt
// double-buffered in LDS -> ONE barrier per tile. P stored with
// rotation col'=(col+16*quad)&63: quads land on disjoint 8-bank
// groups (write 2-way same-dword = free; read exactly 8 dw/bank).
// ============================================================
__global__ __launch_bounds__(256, 2) void k3a(const f16* __restrict__ uhp,
                                              const f16* __restrict__ ulp,
                                              const f16* __restrict__ vhp,
                                              const f16* __restrict__ vlp,
                                              const f16* __restrict__ vT,
                                              const float* __restrict__ Mo,
                                              float* __restrict__ Lo,
                                              const float* __restrict__ cosb,
                                              const float* __restrict__ sinb,
                                              f16* __restrict__ w1) {
    __shared__ f16 Vt[2][112 * 72];    // rows 96..111 = ones (row-sum block)
    __shared__ f16 P[2][64 * 72];
    const int tid = threadIdx.x, w = tid >> 6, lane = tid & 63;
    const int quad = lane >> 4, l15 = lane & 15;
    const int bid0 = blockIdx.y * 32 + blockIdx.x;
    const int swz  = (bid0 & 7) * 64 + (bid0 >> 3);
    const int q0 = (swz & 31) * 64, head = swz >> 5;
    const f16* Ah_g = uhp + (size_t)head * 2048 * 96;
    const f16* Al_g = ulp + (size_t)head * 2048 * 96;
    const f16* Vt_g = vT + (size_t)head * 96 * 2048;

    f16x8 Afh[4][3], Afl[4][3];
#pragma unroll
    for (int mt = 0; mt < 4; ++mt)
#pragma unroll
        for (int cc = 0; cc < 3; ++cc) {
            size_t off = (size_t)(q0 + 16 * mt + l15) * 96 + cc * 32 + quad * 8;
            Afh[mt][cc] = *(const f16x8*)(Ah_g + off);
            Afl[mt][cc] = *(const f16x8*)(Al_g + off);
        }
    float negM[4][4];
#pragma unroll
    for (int mt = 0; mt < 4; ++mt)
#pragma unroll
        for (int r = 0; r < 4; ++r)
            negM[mt][r] = -Mo[head * 2048 + q0 + 16 * mt + 4 * quad + r];

    const f16* Bh_p = vhp + (size_t)head * 2048 * 96 + (size_t)(w * 16 + l15) * 96 + quad * 8;
    const f16* Bl_p = vlp + (size_t)head * 2048 * 96 + (size_t)(w * 16 + l15) * 96 + quad * 8;
    const int vr0 = tid >> 3, vc8 = (tid & 7) * 8;       // Vt rows vr0,+32,+64
    const int pwc = (w * 16 + l15 + 16 * quad) & 63;     // P write col (rotated)
    const int prr = 16 * (l15 >> 2);                     // P read rotation

    // ones rows for the row-sum MFMA (both buffers, written once)
    if (tid < 144) {
        f16x8 ones = {(f16)1, (f16)1, (f16)1, (f16)1,
                      (f16)1, (f16)1, (f16)1, (f16)1};
        *(f16x8*)&Vt[0][96 * 72 + tid * 8] = ones;
        *(f16x8*)&Vt[1][96 * 72 + tid * 8] = ones;
    }

    f16x8 Bch[2][3], Bcl[2][3];
    float4 v0, v1, v2;
    // prologue: tile 0
#pragma unroll
    for (int cc = 0; cc < 3; ++cc) {
        Bch[0][cc] = *(const f16x8*)(Bh_p + cc * 32);
        Bcl[0][cc] = *(const f16x8*)(Bl_p + cc * 32);
    }
    v0 = *(const float4*)(Vt_g + (size_t)vr0 * 2048 + vc8);
    v1 = *(const float4*)(Vt_g + (size_t)(vr0 + 32) * 2048 + vc8);
    v2 = *(const float4*)(Vt_g + (size_t)(vr0 + 64) * 2048 + vc8);
    *(float4*)&Vt[0][vr0 * 72 + vc8] = v0;
    *(float4*)&Vt[0][(vr0 + 32) * 72 + vc8] = v1;
    *(float4*)&Vt[0][(vr0 + 64) * 72 + vc8] = v2;
    // (no prologue barrier needed: first in-loop barrier covers visibility)

    f32x4 accO[7] = {};

    for (int tp = 0; tp < 16; ++tp) {
#pragma unroll
        for (int h = 0; h < 2; ++h) {
            const int t = 2 * tp + h;
            if (t < 31) {             // prefetch tile t+1 (hides under S-MFMA)
                const f16* bh = Bh_p + (size_t)(t + 1) * 6144;
                const f16* bl = Bl_p + (size_t)(t + 1) * 6144;
                const int kn = (t + 1) * 64;
#pragma unroll
                for (int cc = 0; cc < 3; ++cc) {
                    Bch[h ^ 1][cc] = *(const f16x8*)(bh + cc * 32);
                    Bcl[h ^ 1][cc] = *(const f16x8*)(bl + cc * 32);
                }
                v0 = *(const float4*)(Vt_g + (size_t)vr0 * 2048 + kn + vc8);
                v1 = *(const float4*)(Vt_g + (size_t)(vr0 + 32) * 2048 + kn + vc8);
                v2 = *(const float4*)(Vt_g + (size_t)(vr0 + 64) * 2048 + kn + vc8);
            }
            f32x4 accS[4] = {}, accX[4] = {};
            __builtin_amdgcn_s_setprio(1);
#pragma unroll
            for (int cc = 0; cc < 3; ++cc)
#pragma unroll
                for (int mt = 0; mt < 4; ++mt) {
                    accS[mt] = MFMA16(Afh[mt][cc], Bch[h][cc], accS[mt]);
                    accX[mt] = MFMA16(Afh[mt][cc], Bcl[h][cc], accX[mt]);
                    accX[mt] = MFMA16(Afl[mt][cc], Bch[h][cc], accX[mt]);
                }
            __builtin_amdgcn_s_setprio(0);
#pragma unroll
            for (int mt = 0; mt < 4; ++mt)
#pragma unroll
                for (int r = 0; r < 4; ++r) {
                    float zl = fmaf(ZC1, accS[mt][r], ZC2 * accX[mt][r]);
                    P[h][(16 * mt + 4 * quad + r) * 72 + pwc] =
                        (f16)exp2f(zl + negM[mt][r]);
                }
            __syncthreads();          // the single per-tile barrier
            __builtin_amdgcn_s_setprio(1);
#pragma unroll
            for (int kc = 0; kc < 2; ++kc) {
                f16x8 ap = *(const f16x8*)&P[h][(w * 16 + l15) * 72 +
                                               ((kc * 32 + quad * 8 + prr) & 63)];
#pragma unroll
                for (int nt = 0; nt < 7; ++nt) {   // nt=6: ones rows -> L
                    f16x8 bv = *(const f16x8*)&Vt[h][(nt * 16 + l15) * 72 + kc * 32 + quad * 8];
                    accO[nt] = MFMA16(ap, bv, accO[nt]);
                }
            }
            __builtin_amdgcn_s_setprio(0);
            if (t < 31) {             // stage Vt(t+1) into the other buffer
                *(float4*)&Vt[h ^ 1][vr0 * 72 + vc8] = v0;
                *(float4*)&Vt[h ^ 1][(vr0 + 32) * 72 + vc8] = v1;
                *(float4*)&Vt[h ^ 1][(vr0 + 64) * 72 + vc8] = v2;
            }
        }
    }
    float invL[4];
#pragma unroll
    for (int r = 0; r < 4; ++r) invL[r] = 1.0f / accO[6][r];
    if (l15 == 0) {
#pragma unroll
        for (int r = 0; r < 4; ++r)
            Lo[head * 2048 + q0 + w * 16 + quad * 4 + r] = accO[6][r];
    }

    const int b = head >> 3, c = head & 7;
#pragma unroll
    for (int r = 0; r < 4; ++r) {
        int q = q0 + w * 16 + quad * 4 + r;
        int cbi = (b * 2048 + q) * 96;
        f16* wrow = w1 + (size_t)(b * 2048 + q) * 768 + c * 96;
#pragma unroll
        for (int nt = 0; nt < 3; ++nt) {
            int rr = nt * 16 + l15;
            float cc = cosb[cbi + rr], ss = sinb[cbi + rr];
            float a = accO[nt][r] * invL[r];
            float b2 = accO[nt + 3][r] * invL[r];
            wrow[rr] = (f16)(a * cc + b2 * ss);
            wrow[rr + 48] = (f16)(b2 * cc - a * ss);
        }
    }
}

// ============================================================
// K3b: S2[q][k]=vr_q.ur_k, P2=exp2(zl-M[k])/L[k], out=P2@uo,
// rope -> w2. Same 1-barrier direct-B pipeline as k3a.
// ============================================================
__global__ __launch_bounds__(256, 2) void k3b(const f16* __restrict__ uhp,
                                              const f16* __restrict__ ulp,
                                              const f16* __restrict__ vhp,
                                              const f16* __restrict__ vlp,
                                              const f16* __restrict__ oT,
                                              const float* __restrict__ Mo,
                                              const float* __restrict__ Lo,
                                              const float* __restrict__ cosb,
                                              const float* __restrict__ sinb,
                                              f16* __restrict__ w2) {
    __shared__ f16 Ot[2][96 * 72];
    __shared__ f16 P[2][64 * 72];
    const int tid = threadIdx.x, w = tid >> 6, lane = tid & 63;
    const int quad = lane >> 4, l15 = lane & 15;
    const int bid0 = blockIdx.y * 32 + blockIdx.x;
    const int swz  = (bid0 & 7) * 64 + (bid0 >> 3);
    const int q0 = (swz & 31) * 64, head = swz >> 5;
    const f16* Ah_g = vhp + (size_t)head * 2048 * 96;   // A = vr
    const f16* Al_g = vlp + (size_t)head * 2048 * 96;
    const f16* Ot_g = oT + (size_t)head * 96 * 2048;

    f16x8 Afh[4][3], Afl[4][3];
#pragma unroll
    for (int mt = 0; mt < 4; ++mt)
#pragma unroll
        for (int cc = 0; cc < 3; ++cc) {
            size_t off = (size_t)(q0 + 16 * mt + l15) * 96 + cc * 32 + quad * 8;
            Afh[mt][cc] = *(const f16x8*)(Ah_g + off);
            Afl[mt][cc] = *(const f16x8*)(Al_g + off);
        }

    const f16* Bh_p = uhp + (size_t)head * 2048 * 96 + (size_t)(w * 16 + l15) * 96 + quad * 8;
    const f16* Bl_p = ulp + (size_t)head * 2048 * 96 + (size_t)(w * 16 + l15) * 96 + quad * 8;
    const int vr0 = tid >> 3, vc8 = (tid & 7) * 8;
    const int pwc = (w * 16 + l15 + 16 * quad) & 63;
    const int prr = 16 * (l15 >> 2);

    f16x8 Bch[2][3], Bcl[2][3];
    float4 v0, v1, v2;
#pragma unroll
    for (int cc = 0; cc < 3; ++cc) {
        Bch[0][cc] = *(const f16x8*)(Bh_p + cc * 32);
        Bcl[0][cc] = *(const f16x8*)(Bl_p + cc * 32);
    }
    v0 = *(const float4*)(Ot_g + (size_t)vr0 * 2048 + vc8);
    v1 = *(const float4*)(Ot_g + (size_t)(vr0 + 32) * 2048 + vc8);
    v2 = *(const float4*)(Ot_g + (size_t)(vr0 + 64) * 2048 + vc8);
    *(float4*)&Ot[0][vr0 * 72 + vc8] = v0;
    *(float4*)&Ot[0][(vr0 + 32) * 72 + vc8] = v1;
    *(float4*)&Ot[0][(vr0 + 64) * 72 + vc8] = v2;

    f32x4 accO[6] = {};

    for (int tp = 0; tp < 16; ++tp) {
#pragma unroll
        for (int h = 0; h < 2; ++h) {
            const int t = 2 * tp + h;
            const int k0 = t * 64;
            float negMk = -Mo[head * 2048 + k0 + w * 16 + l15];
            float invLk = 1.0f / Lo[head * 2048 + k0 + w * 16 + l15];
            if (t < 31) {
                const f16* bh = Bh_p + (size_t)(t + 1) * 6144;
                const f16* bl = Bl_p + (size_t)(t + 1) * 6144;
                const int kn = (t + 1) * 64;
#pragma unroll
                for (int cc = 0; cc < 3; ++cc) {
                    Bch[h ^ 1][cc] = *(const f16x8*)(bh + cc * 32);
                    Bcl[h ^ 1][cc] = *(const f16x8*)(bl + cc * 32);
                }
                v0 = *(const float4*)(Ot_g + (size_t)vr0 * 2048 + kn + vc8);
                v1 = *(const float4*)(Ot_g + (size_t)(vr0 + 32) * 2048 + kn + vc8);
                v2 = *(const float4*)(Ot_g + (size_t)(vr0 + 64) * 2048 + kn + vc8);
            }
            f32x4 accS[4] = {}, accX[4] = {};
            __builtin_amdgcn_s_setprio(1);
#pragma unroll
            for (int cc = 0; cc < 3; ++cc)
#pragma unroll
                for (int mt = 0; mt < 4; ++mt) {
                    accS[mt] = MFMA16(Afh[mt][cc], Bch[h][cc], accS[mt]);
                    // preserve cross-product order: (u_hi*v_lo) first, then (u_lo*v_hi)
                    accX[mt] = MFMA16(Afl[mt][cc], Bch[h][cc], accX[mt]);   // v_lo * u_hi
                    accX[mt] = MFMA16(Afh[mt][cc], Bcl[h][cc], accX[mt]);   // v_hi * u_lo
                }
            __builtin_amdgcn_s_setprio(0);
#pragma unroll
            for (int mt = 0; mt < 4; ++mt)
#pragma unroll
                for (int r = 0; r < 4; ++r) {
                    float zl = fmaf(ZC1, accS[mt][r], ZC2 * accX[mt][r]);
                    P[h][(16 * mt + 4 * quad + r) * 72 + pwc] =
                        (f16)(exp2f(zl + negMk) * invLk);
                }
            __syncthreads();
            __builtin_amdgcn_s_setprio(1);
#pragma unroll
            for (int kc = 0; kc < 2; ++kc) {
                f16x8 ap = *(const f16x8*)&P[h][(w * 16 + l15) * 72 +
                                               ((kc * 32 + quad * 8 + prr) & 63)];
#pragma unroll
                for (int nt = 0; nt < 6; ++nt) {
                    f16x8 bo = *(const f16x8*)&Ot[h][(nt * 16 + l15) * 72 + kc * 32 + quad * 8];
                    accO[nt] = MFMA16(ap, bo, accO[nt]);
                }
            }
            __builtin_amdgcn_s_setprio(0);
            if (t < 31) {
                *(float4*)&Ot[h ^ 1][vr0 * 72 + vc8] = v0;
                *(float4*)&Ot[h ^ 1][(vr0 + 32) * 72 + vc8] = v1;
                *(float4*)&Ot[h ^ 1][(vr0 + 64) * 72 + vc8] = v2;
            }
        }
    }
    const int b = head >> 3, c = head & 7;
#pragma unroll
    for (int r = 0; r < 4; ++r) {
        int q = q0 + w * 16 + quad * 4 + r;
        int cbi = (b * 2048 + q) * 96;
        f16* wrow = w2 + (size_t)(b * 2048 + q) * 768 + c * 96;
#pragma unroll
        for (int nt = 0; nt < 3; ++nt) {
            int rr = nt * 16 + l15;
            float cc = cosb[cbi + rr], ss = sinb[cbi + rr];
            float a = accO[nt][r];
            float b2 = accO[nt + 3][r];
            wrow[rr] = (f16)(a * cc - b2 * ss);
            wrow[rr + 48] = (f16)(b2 * cc + a * ss);
        }
    }
}

// ============================================================
// K4: G = w1@U + w2@V (fp16 MFMA). (unchanged)
// ============================================================
__global__ __launch_bounds__(256, 2) void k4_final(const f16* __restrict__ w1,
                                                   const f16* __restrict__ w2,
                                                   const float* __restrict__ U,
                                                   const float* __restrict__ V,
                                                   float* __restrict__ outp) {
    __shared__ f16 A1[128 * 56];
    __shared__ f16 A2[128 * 56];
    __shared__ f16 B1[64 * 56];
    __shared__ f16 B2[64 * 56];
    const int tid = threadIdx.x, w = tid >> 6, lane = tid & 63;
    const int quad = lane >> 4, l15 = lane & 15;
    const int bs0 = blockIdx.x * 128;
    const int d0 = blockIdx.y * 64;
    f32x4 acc[2][4] = {};

    for (int ec = 0; ec < 24; ++ec) {
        int e0 = ec * 32;
        __syncthreads();
#pragma unroll
        for (int m = 0; m < 2; ++m) {
            int f = tid + 256 * m;
            int row = f >> 2, q = f & 3;
            *(float4*)&A1[row * 56 + q * 8] =
                *(const float4*)(w1 + (size_t)(bs0 + row) * 768 + e0 + q * 8);
            *(float4*)&A2[row * 56 + q * 8] =
                *(const float4*)(w2 + (size_t)(bs0 + row) * 768 + e0 + q * 8);
        }
#pragma unroll
        for (int m2 = 0; m2 < 2; ++m2) {
            int e_r = (tid >> 4) + 16 * m2;
            int dc = tid & 15;
            float4 fu = *(const float4*)(U + (size_t)(e0 + e_r) * 768 + d0 + dc * 4);
            float4 fv = *(const float4*)(V + (size_t)(e0 + e_r) * 768 + d0 + dc * 4);
            B1[(dc * 4 + 0) * 56 + e_r] = (f16)fu.x;
            B1[(dc * 4 + 1) * 56 + e_r] = (f16)fu.y;
            B1[(dc * 4 + 2) * 56 + e_r] = (f16)fu.z;
            B1[(dc * 4 + 3) * 56 + e_r] = (f16)fu.w;
            B2[(dc * 4 + 0) * 56 + e_r] = (f16)fv.x;
            B2[(dc * 4 + 1) * 56 + e_r] = (f16)fv.y;
            B2[(dc * 4 + 2) * 56 + e_r] = (f16)fv.z;
            B2[(dc * 4 + 3) * 56 + e_r] = (f16)fv.w;
        }
        __syncthreads();
        f16x8 a1f[2], a2f[2];
#pragma unroll
        for (int mt = 0; mt < 2; ++mt) {
            a1f[mt] = *(const f16x8*)&A1[(32 * w + 16 * mt + l15) * 56 + quad * 8];
            a2f[mt] = *(const f16x8*)&A2[(32 * w + 16 * mt + l15) * 56 + quad * 8];
        }
#pragma unroll
        for (int nt = 0; nt < 4; ++nt) {
            f16x8 b1f = *(const f16x8*)&B1[(nt * 16 + l15) * 56 + quad * 8];
            f16x8 b2f = *(const f16x8*)&B2[(nt * 16 + l15) * 56 + quad * 8];
#pragma unroll
            for (int mt = 0; mt < 2; ++mt) {
                acc[mt][nt] = MFMA16(a1f[mt], b1f, acc[mt][nt]);
                acc[mt][nt] = MFMA16(a2f[mt], b2f, acc[mt][nt]);
            }
        }
    }
#pragma unroll
    for (int mt = 0; mt < 2; ++mt)
#pragma unroll
        for (int nt = 0; nt < 4; ++nt)
#pragma unroll
            for (int r = 0; r < 4; ++r) {
                int s = bs0 + 32 * w + 16 * mt + 4 * quad + r;
                int d = d0 + 16 * nt + l15;
                outp[(size_t)s * 768 + d] = acc[mt][nt][r];
            }
}

extern "C" void kernel_launch(void* const* d_in, const int* in_sizes, int n_in,
                              void* d_out, int out_size, void* d_ws, size_t ws_size,
                              hipStream_t stream) {
    const float* qz   = (const float*)d_in[0];
    const float* cosb = (const float*)d_in[1];
    const float* sinb = (const float*)d_in[2];
    const float* U    = (const float*)d_in[3];
    const float* V    = (const float*)d_in[4];
    float* outp = (float*)d_out;

    f16* ws16 = (f16*)d_ws;
    f16* uhp = ws16;
    f16* ulp = ws16 + HN;
    f16* vhp = ws16 + 2 * HN;
    f16* vlp = ws16 + 3 * HN;
    f16* vT  = ws16 + 4 * HN;
    f16* oT  = ws16 + 5 * HN;
    f16* w1  = ws16 + 6 * HN;
    f16* w2  = ws16 + 7 * HN;
    float* Mo = (float*)(ws16 + 8 * HN);
    float* Lo = Mo + 16 * 2048;

    // qz hi/lo splits live in the w1/w2 slots (dead until k3a/k3b write them).
    f16* qzh = w1;
    f16* qzl = w2;
    // U/V hi/lo splits live in d_out scratch (overwritten by k4 at the end).
    f16* outw = (f16*)d_out;
    f16* Uh = outw;
    f16* Ul = outw + UVN;
    f16* Vh = outw + 2 * UVN;
    f16* Vl = outw + 3 * UVN;

    k0_split<<<dim3(3072), 256, 0, stream>>>(qz, U, V, qzh, qzl, Uh, Ul, Vh, Vl);
    k1_proj<<<dim3(64, 8), 256, 0, stream>>>(qzh, qzl, Uh, Ul, Vh, Vl, cosb, sinb,
                                             uhp, ulp, vhp, vlp, vT, oT);
    k2_stats<<<dim3(32, 16), 256, 0, stream>>>(uhp, ulp, vhp, vlp, Mo);
    k3a<<<dim3(32, 16), 256, 0, stream>>>(uhp, ulp, vhp, vlp, vT, Mo, Lo, cosb, sinb, w1);
    k3b<<<dim3(32, 16), 256, 0, stream>>>(uhp, ulp, vhp, vlp, oT, Mo, Lo, cosb, sinb, w2);
    k4_final<<<dim3(32, 12), 256, 0, stream>>>(w1, w2, U, V, outp);
}